// Round 1
// baseline (1892.809 us; speedup 1.0000x reference)
//
#include <hip/hip_runtime.h>
#include <hip/hip_bf16.h>
#include <cstdint>

#define HID 128

// ---------------------------------------------------------------- utilities
__device__ __forceinline__ int lower_bound_i(const int* a, int n, int v) {
    int lo = 0, hi = n;
    while (lo < hi) { int m = (lo + hi) >> 1; if (a[m] < v) lo = m + 1; else hi = m; }
    return lo;
}

// ---------------------------------------------------------------- mean of edge_attr
__global__ __launch_bounds__(256) void mean_kernel(const float* __restrict__ eattr,
                                                   float* __restrict__ meansum, int E) {
    float sx = 0.f, sy = 0.f;
    for (int i = blockIdx.x * 256 + threadIdx.x; i < E; i += gridDim.x * 256) {
        float2 v = *(const float2*)(eattr + 2 * (size_t)i);
        sx += v.x; sy += v.y;
    }
    for (int d = 1; d < 64; d <<= 1) { sx += __shfl_xor(sx, d); sy += __shfl_xor(sy, d); }
    if ((threadIdx.x & 63) == 0) { atomicAdd(&meansum[0], sx); atomicAdd(&meansum[1], sy); }
}

// ---------------------------------------------------------------- CSR build
__global__ __launch_bounds__(256) void deg_kernel(const int* __restrict__ ei,
                                                  int* __restrict__ deg, int E, int ET) {
    int e = blockIdx.x * 256 + threadIdx.x;
    if (e >= ET) return;
    int dst = (e < E) ? ei[E + e] : (e - E);
    atomicAdd(&deg[dst], 1);
}

__global__ __launch_bounds__(1024) void scan_kernel(const int* __restrict__ deg,
                                                    int* __restrict__ row_ptr,
                                                    int* __restrict__ cursor, int N) {
    __shared__ int partial[1024];
    int t = threadIdx.x;
    int chunk = (N + 1023) / 1024;
    int lo = t * chunk, hi = min(lo + chunk, N);
    int s = 0;
    for (int i = lo; i < hi; i++) s += deg[i];
    partial[t] = s;
    __syncthreads();
    for (int d = 1; d < 1024; d <<= 1) {
        int v = (t >= d) ? partial[t - d] : 0;
        __syncthreads();
        partial[t] += v;
        __syncthreads();
    }
    int pre = partial[t] - s;   // exclusive prefix of this chunk
    for (int i = lo; i < hi; i++) {
        row_ptr[i] = pre; cursor[i] = pre;
        pre += deg[i];
    }
    if (t == 1023) row_ptr[N] = partial[1023];
}

__global__ __launch_bounds__(256) void fill_kernel(const int* __restrict__ ei,
                                                   const float* __restrict__ eattr,
                                                   const float* __restrict__ meansum,
                                                   int* __restrict__ cursor,
                                                   int* __restrict__ csr_src,
                                                   float2* __restrict__ csr_ea,
                                                   int E, int ET) {
    int e = blockIdx.x * 256 + threadIdx.x;
    if (e >= ET) return;
    int src, dst; float2 ea;
    if (e < E) {
        src = ei[e]; dst = ei[E + e];
        ea = *(const float2*)(eattr + 2 * (size_t)e);
    } else {
        src = dst = e - E;
        float inv = 1.0f / (float)E;
        ea.x = meansum[0] * inv; ea.y = meansum[1] * inv;
    }
    int pos = atomicAdd(&cursor[dst], 1);
    csr_src[pos] = src;
    csr_ea[pos] = ea;
}

// ---------------------------------------------------------------- f32 GEMM tile (32 rows x 128 cols)
// computes out = Hin @ W + bias for two (W,bias,out) triples selected by blockIdx.z
template <int K>
__global__ __launch_bounds__(256) void transform_kernel(
    const float* __restrict__ Hin,
    const float* __restrict__ W0, const float* __restrict__ b0, float* __restrict__ o0,
    const float* __restrict__ W1, const float* __restrict__ b1, float* __restrict__ o1,
    int N) {
    constexpr int KC = (K > 64) ? 64 : K;
    __shared__ float Ws[KC][HID];
    __shared__ float Hs[32][K + 4];

    const float* W; const float* bias; float* out;
    if (blockIdx.z == 0) { W = W0; bias = b0; out = o0; }
    else                 { W = W1; bias = b1; out = o1; }

    int row0 = blockIdx.x * 32;
    int tid = threadIdx.x;
    int tx = tid & 15, ty = tid >> 4;

    // stage H tile
    for (int i = tid; i < 32 * (K / 4); i += 256) {
        int r = i / (K / 4), kq = i % (K / 4);
        int row = row0 + r;
        float4 v = make_float4(0.f, 0.f, 0.f, 0.f);
        if (row < N) v = *(const float4*)(Hin + (size_t)row * K + kq * 4);
        *(float4*)&Hs[r][kq * 4] = v;
    }

    float acc[2][8];
    #pragma unroll
    for (int i = 0; i < 2; i++)
        #pragma unroll
        for (int j = 0; j < 8; j++) acc[i][j] = 0.f;

    int r0 = ty * 2, r1 = ty * 2 + 1;

    for (int kc = 0; kc < K; kc += KC) {
        __syncthreads();
        for (int i = tid; i < KC * 32; i += 256) {
            int k = i >> 5, cq = i & 31;
            *(float4*)&Ws[k][cq * 4] = *(const float4*)(W + (size_t)(kc + k) * HID + cq * 4);
        }
        __syncthreads();
        #pragma unroll 8
        for (int k = 0; k < KC; k++) {
            float a0 = Hs[r0][kc + k];
            float a1 = Hs[r1][kc + k];
            float4 w0 = *(float4*)&Ws[k][tx * 4];
            float4 w1 = *(float4*)&Ws[k][64 + tx * 4];
            acc[0][0] += a0 * w0.x; acc[0][1] += a0 * w0.y; acc[0][2] += a0 * w0.z; acc[0][3] += a0 * w0.w;
            acc[0][4] += a0 * w1.x; acc[0][5] += a0 * w1.y; acc[0][6] += a0 * w1.z; acc[0][7] += a0 * w1.w;
            acc[1][0] += a1 * w0.x; acc[1][1] += a1 * w0.y; acc[1][2] += a1 * w0.z; acc[1][3] += a1 * w0.w;
            acc[1][4] += a1 * w1.x; acc[1][5] += a1 * w1.y; acc[1][6] += a1 * w1.z; acc[1][7] += a1 * w1.w;
        }
    }

    float4 bb0 = *(const float4*)(bias + tx * 4);
    float4 bb1 = *(const float4*)(bias + 64 + tx * 4);
    #pragma unroll
    for (int i = 0; i < 2; i++) {
        int row = row0 + ty * 2 + i;
        if (row < N) {
            float4 v0 = make_float4(acc[i][0] + bb0.x, acc[i][1] + bb0.y, acc[i][2] + bb0.z, acc[i][3] + bb0.w);
            float4 v1 = make_float4(acc[i][4] + bb1.x, acc[i][5] + bb1.y, acc[i][6] + bb1.z, acc[i][7] + bb1.w);
            *(float4*)(out + (size_t)row * HID + tx * 4) = v0;
            *(float4*)(out + (size_t)row * HID + 64 + tx * 4) = v1;
        }
    }
}

// ---------------------------------------------------------------- combine: Hnext = elu(Hnext + Hin@W + b)
template <int K>
__global__ __launch_bounds__(256) void combine_kernel(
    const float* __restrict__ Hin,
    const float* __restrict__ W, const float* __restrict__ bias,
    float* __restrict__ Hio, int N) {
    constexpr int KC = (K > 64) ? 64 : K;
    __shared__ float Ws[KC][HID];
    __shared__ float Hs[32][K + 4];

    int row0 = blockIdx.x * 32;
    int tid = threadIdx.x;
    int tx = tid & 15, ty = tid >> 4;

    for (int i = tid; i < 32 * (K / 4); i += 256) {
        int r = i / (K / 4), kq = i % (K / 4);
        int row = row0 + r;
        float4 v = make_float4(0.f, 0.f, 0.f, 0.f);
        if (row < N) v = *(const float4*)(Hin + (size_t)row * K + kq * 4);
        *(float4*)&Hs[r][kq * 4] = v;
    }

    float acc[2][8];
    #pragma unroll
    for (int i = 0; i < 2; i++)
        #pragma unroll
        for (int j = 0; j < 8; j++) acc[i][j] = 0.f;

    int r0 = ty * 2, r1 = ty * 2 + 1;

    for (int kc = 0; kc < K; kc += KC) {
        __syncthreads();
        for (int i = tid; i < KC * 32; i += 256) {
            int k = i >> 5, cq = i & 31;
            *(float4*)&Ws[k][cq * 4] = *(const float4*)(W + (size_t)(kc + k) * HID + cq * 4);
        }
        __syncthreads();
        #pragma unroll 8
        for (int k = 0; k < KC; k++) {
            float a0 = Hs[r0][kc + k];
            float a1 = Hs[r1][kc + k];
            float4 w0 = *(float4*)&Ws[k][tx * 4];
            float4 w1 = *(float4*)&Ws[k][64 + tx * 4];
            acc[0][0] += a0 * w0.x; acc[0][1] += a0 * w0.y; acc[0][2] += a0 * w0.z; acc[0][3] += a0 * w0.w;
            acc[0][4] += a0 * w1.x; acc[0][5] += a0 * w1.y; acc[0][6] += a0 * w1.z; acc[0][7] += a0 * w1.w;
            acc[1][0] += a1 * w0.x; acc[1][1] += a1 * w0.y; acc[1][2] += a1 * w0.z; acc[1][3] += a1 * w0.w;
            acc[1][4] += a1 * w1.x; acc[1][5] += a1 * w1.y; acc[1][6] += a1 * w1.z; acc[1][7] += a1 * w1.w;
        }
    }

    float4 bb0 = *(const float4*)(bias + tx * 4);
    float4 bb1 = *(const float4*)(bias + 64 + tx * 4);
    #pragma unroll
    for (int i = 0; i < 2; i++) {
        int row = row0 + ty * 2 + i;
        if (row < N) {
            float* p0 = Hio + (size_t)row * HID + tx * 4;
            float* p1 = p0 + 64;
            float4 g0 = *(float4*)p0;
            float4 g1 = *(float4*)p1;
            float v[8];
            v[0] = g0.x + acc[i][0] + bb0.x; v[1] = g0.y + acc[i][1] + bb0.y;
            v[2] = g0.z + acc[i][2] + bb0.z; v[3] = g0.w + acc[i][3] + bb0.w;
            v[4] = g1.x + acc[i][4] + bb1.x; v[5] = g1.y + acc[i][5] + bb1.y;
            v[6] = g1.z + acc[i][6] + bb1.z; v[7] = g1.w + acc[i][7] + bb1.w;
            #pragma unroll
            for (int j = 0; j < 8; j++) v[j] = (v[j] > 0.f) ? v[j] : (__expf(v[j]) - 1.f);
            *(float4*)p0 = make_float4(v[0], v[1], v[2], v[3]);
            *(float4*)p1 = make_float4(v[4], v[5], v[6], v[7]);
        }
    }
}

// ---------------------------------------------------------------- edge/attention kernel: one wave per dst node
__global__ __launch_bounds__(256) void edge_kernel(
    const float* __restrict__ XL, const float* __restrict__ XR,
    const int* __restrict__ row_ptr, const int* __restrict__ csr_src,
    const float2* __restrict__ csr_ea,
    const float* __restrict__ att,    // 128 = H*C flattened
    const float* __restrict__ We,     // 2 x 128
    const float* __restrict__ gbias,  // 128
    float* __restrict__ out, int N) {
    int n = (blockIdx.x * 256 + threadIdx.x) >> 6;
    int lane = threadIdx.x & 63;
    if (n >= N) return;

    int c0 = lane * 2;
    float2 xr = *(const float2*)(XR + (size_t)n * HID + c0);
    float2 av = *(const float2*)(att + c0);
    float2 we0 = *(const float2*)(We + c0);
    float2 we1 = *(const float2*)(We + HID + c0);

    int eb = row_ptr[n], eend = row_ptr[n + 1];

    float m_run = -INFINITY, l_run = 0.f, acc0 = 0.f, acc1 = 0.f;
    for (int e = eb; e < eend; e++) {
        int s = csr_src[e];
        float2 ea = csr_ea[e];
        float2 xl = *(const float2*)(XL + (size_t)s * HID + c0);
        float m0 = xl.x + xr.x + ea.x * we0.x + ea.y * we1.x;
        float m1 = xl.y + xr.y + ea.x * we0.y + ea.y * we1.y;
        m0 = (m0 > 0.f) ? m0 : 0.2f * m0;
        m1 = (m1 > 0.f) ? m1 : 0.2f * m1;
        float part = m0 * av.x + m1 * av.y;
        part += __shfl_xor(part, 1);
        part += __shfl_xor(part, 2);
        part += __shfl_xor(part, 4);     // lanes 8h..8h+7 now hold head-h logit
        float m_new = fmaxf(m_run, part);
        float scale = (m_run == -INFINITY) ? 0.f : __expf(m_run - m_new);
        float p = __expf(part - m_new);
        l_run = l_run * scale + p;
        acc0 = acc0 * scale + p * xl.x;
        acc1 = acc1 * scale + p * xl.y;
        m_run = m_new;
    }
    float inv = 1.f / fmaxf(l_run, 1e-16f);
    float2 o;
    o.x = acc0 * inv + gbias[c0];
    o.y = acc1 * inv + gbias[c0 + 1];
    *(float2*)(out + (size_t)n * HID + c0) = o;
}

// ---------------------------------------------------------------- mean pool per graph
__global__ __launch_bounds__(128) void pool_kernel(const float* __restrict__ h,
                                                   const int* __restrict__ batch,
                                                   float* __restrict__ g, int N) {
    int gid = blockIdx.x;
    int lo = lower_bound_i(batch, N, gid);
    int hi = lower_bound_i(batch, N, gid + 1);
    int c = threadIdx.x;
    float s = 0.f;
    for (int i = lo; i < hi; i++) s += h[(size_t)i * HID + c];
    g[gid * HID + c] = s / fmaxf((float)(hi - lo), 1.0f);
}

// ---------------------------------------------------------------- readout GEMM 500x128 @ 128x1000
__global__ __launch_bounds__(256) void readout_kernel(const float* __restrict__ g,
                                                      const float* __restrict__ W,
                                                      const float* __restrict__ b,
                                                      float* __restrict__ out, int S) {
    __shared__ float gs[HID];
    int gid = blockIdx.y;
    if (threadIdx.x < HID) gs[threadIdx.x] = g[gid * HID + threadIdx.x];
    __syncthreads();
    int c = blockIdx.x * 256 + threadIdx.x;
    if (c < S) {
        float acc = b[c];
        #pragma unroll 8
        for (int k = 0; k < HID; k++) acc += gs[k] * W[(size_t)k * S + c];
        out[(size_t)gid * S + c] = acc;
    }
}

// ---------------------------------------------------------------- launcher
extern "C" void kernel_launch(void* const* d_in, const int* in_sizes, int n_in,
                              void* d_out, int out_size, void* d_ws, size_t ws_size,
                              hipStream_t stream) {
    const float* x      = (const float*)d_in[0];
    const int*   ei     = (const int*)d_in[1];
    const float* eattr  = (const float*)d_in[2];
    const int*   batch  = (const int*)d_in[3];
    const float* at1_Wl = (const float*)d_in[4];
    const float* at1_bl = (const float*)d_in[5];
    const float* at1_Wr = (const float*)d_in[6];
    const float* at1_br = (const float*)d_in[7];
    const float* at1_We = (const float*)d_in[8];
    const float* at1_att= (const float*)d_in[9];
    const float* at1_b  = (const float*)d_in[10];
    const float* l1_W   = (const float*)d_in[11];
    const float* l1_b   = (const float*)d_in[12];
    const float* atk_Wl = (const float*)d_in[13];
    const float* atk_bl = (const float*)d_in[14];
    const float* atk_Wr = (const float*)d_in[15];
    const float* atk_br = (const float*)d_in[16];
    const float* atk_We = (const float*)d_in[17];
    const float* atk_att= (const float*)d_in[18];
    const float* atk_b  = (const float*)d_in[19];
    const float* lk_W   = (const float*)d_in[20];
    const float* lk_b   = (const float*)d_in[21];
    const float* lin_W  = (const float*)d_in[22];
    const float* lin_b  = (const float*)d_in[23];
    float* out = (float*)d_out;

    const int N  = in_sizes[0] / 16;     // 50000
    const int E  = in_sizes[1] / 2;      // 400000
    const int ET = E + N;                // + self loops
    const int S  = 1000;
    const int G  = out_size / S;         // 500

    char* w = (char*)d_ws;
    auto alloc = [&](size_t bytes) -> char* {
        char* p = w; w += (bytes + 255) & ~(size_t)255; return p;
    };
    float*  XL      = (float*)alloc((size_t)N * HID * 4);
    float*  XR      = (float*)alloc((size_t)N * HID * 4);
    float*  HA      = (float*)alloc((size_t)N * HID * 4);
    float*  HB      = (float*)alloc((size_t)N * HID * 4);
    int*    deg     = (int*)alloc((size_t)N * 4);
    int*    row_ptr = (int*)alloc((size_t)(N + 1) * 4);
    int*    cursor  = (int*)alloc((size_t)N * 4);
    int*    csr_src = (int*)alloc((size_t)ET * 4);
    float2* csr_ea  = (float2*)alloc((size_t)ET * 8);
    float*  meansum = (float*)alloc(8);
    float*  gpool   = (float*)alloc((size_t)G * HID * 4);
    (void)ws_size; (void)n_in;

    hipMemsetAsync(deg, 0, (size_t)N * 4, stream);
    hipMemsetAsync(meansum, 0, 8, stream);

    mean_kernel<<<256, 256, 0, stream>>>(eattr, meansum, E);
    deg_kernel<<<(ET + 255) / 256, 256, 0, stream>>>(ei, deg, E, ET);
    scan_kernel<<<1, 1024, 0, stream>>>(deg, row_ptr, cursor, N);
    fill_kernel<<<(ET + 255) / 256, 256, 0, stream>>>(ei, eattr, meansum, cursor, csr_src, csr_ea, E, ET);

    const int gx = (N + 31) / 32;
    const int ge = (N * 64 + 255) / 256;

    // ---- layer 1 (K = 16)
    transform_kernel<16><<<dim3(gx, 1, 2), 256, 0, stream>>>(x, at1_Wl, at1_bl, XL, at1_Wr, at1_br, XR, N);
    edge_kernel<<<ge, 256, 0, stream>>>(XL, XR, row_ptr, csr_src, csr_ea, at1_att, at1_We, at1_b, HB, N);
    combine_kernel<16><<<gx, 256, 0, stream>>>(x, l1_W, l1_b, HB, N);

    float* hc = HB;
    float* hn = HA;
    // ---- layers 2..10 (K = 128)
    for (int i = 0; i < 9; i++) {
        const float* Wl = atk_Wl + (size_t)i * HID * HID;
        const float* bl = atk_bl + (size_t)i * HID;
        const float* Wr = atk_Wr + (size_t)i * HID * HID;
        const float* br = atk_br + (size_t)i * HID;
        const float* We = atk_We + (size_t)i * 2 * HID;
        const float* at = atk_att + (size_t)i * HID;
        const float* ab = atk_b  + (size_t)i * HID;
        const float* Wk = lk_W   + (size_t)i * HID * HID;
        const float* bk = lk_b   + (size_t)i * HID;

        transform_kernel<128><<<dim3(gx, 1, 2), 256, 0, stream>>>(hc, Wl, bl, XL, Wr, br, XR, N);
        edge_kernel<<<ge, 256, 0, stream>>>(XL, XR, row_ptr, csr_src, csr_ea, at, We, ab, hn, N);
        combine_kernel<128><<<gx, 256, 0, stream>>>(hc, Wk, bk, hn, N);
        float* t = hc; hc = hn; hn = t;
    }

    pool_kernel<<<G, 128, 0, stream>>>(hc, batch, gpool, N);
    readout_kernel<<<dim3((S + 255) / 256, G), 256, 0, stream>>>(gpool, lin_W, lin_b, out, S);
}

// Round 2
// 1503.459 us; speedup vs baseline: 1.2590x; 1.2590x over previous
//
#include <hip/hip_runtime.h>
#include <hip/hip_bf16.h>
#include <cstdint>

#define HID 128

typedef __attribute__((ext_vector_type(8))) short bf16x8;
typedef __attribute__((ext_vector_type(4))) float f32x4;

__device__ __forceinline__ unsigned short f2bf(float x) {
    __hip_bfloat16 h = __float2bfloat16(x);
    return __builtin_bit_cast(unsigned short, h);
}
__device__ __forceinline__ float bf2f(unsigned short u) {
    return __bfloat162float(__builtin_bit_cast(__hip_bfloat16, u));
}
__device__ __forceinline__ int lower_bound_i(const int* a, int n, int v) {
    int lo = 0, hi = n;
    while (lo < hi) { int m = (lo + hi) >> 1; if (a[m] < v) lo = m + 1; else hi = m; }
    return lo;
}

// ---------------------------------------------------------------- mean of edge_attr
__global__ __launch_bounds__(256) void mean_kernel(const float* __restrict__ eattr,
                                                   float* __restrict__ meansum, int E) {
    float sx = 0.f, sy = 0.f;
    for (int i = blockIdx.x * 256 + threadIdx.x; i < E; i += gridDim.x * 256) {
        float2 v = *(const float2*)(eattr + 2 * (size_t)i);
        sx += v.x; sy += v.y;
    }
    for (int d = 1; d < 64; d <<= 1) { sx += __shfl_xor(sx, d); sy += __shfl_xor(sy, d); }
    if ((threadIdx.x & 63) == 0) { atomicAdd(&meansum[0], sx); atomicAdd(&meansum[1], sy); }
}

// ---------------------------------------------------------------- CSR build
__global__ __launch_bounds__(256) void deg_kernel(const int* __restrict__ ei,
                                                  int* __restrict__ deg, int E, int ET) {
    int e = blockIdx.x * 256 + threadIdx.x;
    if (e >= ET) return;
    int dst = (e < E) ? ei[E + e] : (e - E);
    atomicAdd(&deg[dst], 1);
}

__global__ __launch_bounds__(256) void scanA_kernel(const int* __restrict__ deg,
                                                    int* __restrict__ bsum, int N) {
    __shared__ int ws[4];
    int t = threadIdx.x;
    int base = blockIdx.x * 1024 + t * 4;
    int s = 0;
    #pragma unroll
    for (int j = 0; j < 4; j++) { int idx = base + j; if (idx < N) s += deg[idx]; }
    for (int d = 1; d < 64; d <<= 1) s += __shfl_xor(s, d);
    if ((t & 63) == 0) ws[t >> 6] = s;
    __syncthreads();
    if (t == 0) bsum[blockIdx.x] = ws[0] + ws[1] + ws[2] + ws[3];
}

__global__ __launch_bounds__(64) void scanB_kernel(const int* __restrict__ bsum,
                                                   int* __restrict__ boff,
                                                   int* __restrict__ row_ptr, int NB, int N) {
    int t = threadIdx.x;
    int v = (t < NB) ? bsum[t] : 0;
    int inc = v;
    #pragma unroll
    for (int d = 1; d < 64; d <<= 1) { int u = __shfl_up(inc, d); if (t >= d) inc += u; }
    if (t < NB) boff[t] = inc - v;
    if (t == 63) row_ptr[N] = inc;
}

__global__ __launch_bounds__(256) void scanC_kernel(const int* __restrict__ deg,
                                                    const int* __restrict__ boff,
                                                    int* __restrict__ row_ptr,
                                                    int* __restrict__ cursor, int N) {
    __shared__ int wsum[4];
    int t = threadIdx.x;
    int lane = t & 63, wid = t >> 6;
    int base = blockIdx.x * 1024 + t * 4;
    int v[4]; int s = 0;
    #pragma unroll
    for (int j = 0; j < 4; j++) { int idx = base + j; v[j] = (idx < N) ? deg[idx] : 0; s += v[j]; }
    int inc = s;
    #pragma unroll
    for (int d = 1; d < 64; d <<= 1) { int u = __shfl_up(inc, d); if (lane >= d) inc += u; }
    if (lane == 63) wsum[wid] = inc;
    __syncthreads();
    int woff = 0;
    for (int ww = 0; ww < wid; ww++) woff += wsum[ww];
    int excl = boff[blockIdx.x] + woff + inc - s;
    #pragma unroll
    for (int j = 0; j < 4; j++) {
        int idx = base + j;
        if (idx < N) { row_ptr[idx] = excl; cursor[idx] = excl; }
        excl += v[j];
    }
}

__global__ __launch_bounds__(256) void fill_kernel(const int* __restrict__ ei,
                                                   const float* __restrict__ eattr,
                                                   const float* __restrict__ meansum,
                                                   int* __restrict__ cursor,
                                                   int* __restrict__ csr_src,
                                                   float2* __restrict__ csr_ea,
                                                   int E, int ET) {
    int e = blockIdx.x * 256 + threadIdx.x;
    if (e >= ET) return;
    int src, dst; float2 ea;
    if (e < E) {
        src = ei[e]; dst = ei[E + e];
        ea = *(const float2*)(eattr + 2 * (size_t)e);
    } else {
        src = dst = e - E;
        float inv = 1.0f / (float)E;
        ea.x = meansum[0] * inv; ea.y = meansum[1] * inv;
    }
    int pos = atomicAdd(&cursor[dst], 1);
    csr_src[pos] = src;
    csr_ea[pos] = ea;
}

// ---------------------------------------------------------------- weight prep: transpose + bf16 hi/lo split
__global__ __launch_bounds__(256) void wprep_kernel(const float* __restrict__ src,
                                                    unsigned short* __restrict__ hi,
                                                    unsigned short* __restrict__ lo, int total) {
    int idx = blockIdx.x * 256 + threadIdx.x;
    if (idx >= total) return;
    int layer = idx >> 14;
    int rem = idx & 16383;
    int n = rem >> 7, k = rem & 127;
    float w = src[(layer << 14) | (k << 7) | n];
    unsigned short h = f2bf(w);
    hi[idx] = h;
    lo[idx] = f2bf(w - bf2f(h));
}

// ---------------------------------------------------------------- fused 3-GEMM, bf16x3-split MFMA, K=128, no LDS
__global__ __launch_bounds__(256) void gemm3_kernel(
    const unsigned short* __restrict__ Ahi, const unsigned short* __restrict__ Alo,
    const unsigned short* __restrict__ W0h, const unsigned short* __restrict__ W0l,
    const float* __restrict__ b0, float* __restrict__ o0,
    const unsigned short* __restrict__ W1h, const unsigned short* __restrict__ W1l,
    const float* __restrict__ b1, float* __restrict__ o1,
    const unsigned short* __restrict__ W2h, const unsigned short* __restrict__ W2l,
    const float* __restrict__ b2, float* __restrict__ o2, int N) {
    int tid = threadIdx.x;
    int wid = tid >> 6, lane = tid & 63;
    int row0 = blockIdx.x * 128 + wid * 32;
    if (row0 >= N) return;
    int lr = lane & 15;
    int kb = (lane >> 4) * 8;

    const unsigned short* Wh[3] = {W0h, W1h, W2h};
    const unsigned short* Wlo_[3] = {W0l, W1l, W2l};
    const float* Bs[3] = {b0, b1, b2};
    float* Os[3] = {o0, o1, o2};

    bf16x8 ah[2][4], al[2][4];
    #pragma unroll
    for (int mf = 0; mf < 2; mf++) {
        int row = row0 + mf * 16 + lr;
        int rowc = (row < N) ? row : (N - 1);   // clamped: OOB rows never stored
        const unsigned short* pa = Ahi + (size_t)rowc * HID + kb;
        const unsigned short* pl = Alo + (size_t)rowc * HID + kb;
        #pragma unroll
        for (int kf = 0; kf < 4; kf++) {
            ah[mf][kf] = *(const bf16x8*)(pa + kf * 32);
            al[mf][kf] = *(const bf16x8*)(pl + kf * 32);
        }
    }

    #pragma unroll
    for (int w = 0; w < 3; w++) {
        const unsigned short* wh = Wh[w];
        const unsigned short* wlp = Wlo_[w];
        const float* bias = Bs[w];
        float* outp = Os[w];
        #pragma unroll 2
        for (int nf = 0; nf < 8; nf++) {
            int col = nf * 16 + lr;
            const unsigned short* pb = wh + (size_t)col * HID + kb;
            const unsigned short* pbl = wlp + (size_t)col * HID + kb;
            bf16x8 bh[4], bl4[4];
            #pragma unroll
            for (int kf = 0; kf < 4; kf++) {
                bh[kf] = *(const bf16x8*)(pb + kf * 32);
                bl4[kf] = *(const bf16x8*)(pbl + kf * 32);
            }
            f32x4 acc0 = {0.f, 0.f, 0.f, 0.f};
            f32x4 acc1 = {0.f, 0.f, 0.f, 0.f};
            #pragma unroll
            for (int kf = 0; kf < 4; kf++) {
                acc0 = __builtin_amdgcn_mfma_f32_16x16x32_bf16(al[0][kf], bh[kf], acc0, 0, 0, 0);
                acc0 = __builtin_amdgcn_mfma_f32_16x16x32_bf16(ah[0][kf], bl4[kf], acc0, 0, 0, 0);
                acc0 = __builtin_amdgcn_mfma_f32_16x16x32_bf16(ah[0][kf], bh[kf], acc0, 0, 0, 0);
                acc1 = __builtin_amdgcn_mfma_f32_16x16x32_bf16(al[1][kf], bh[kf], acc1, 0, 0, 0);
                acc1 = __builtin_amdgcn_mfma_f32_16x16x32_bf16(ah[1][kf], bl4[kf], acc1, 0, 0, 0);
                acc1 = __builtin_amdgcn_mfma_f32_16x16x32_bf16(ah[1][kf], bh[kf], acc1, 0, 0, 0);
            }
            float bv = bias[col];
            int rb = (lane >> 4) * 4;
            #pragma unroll
            for (int r = 0; r < 4; r++) {
                int row = row0 + rb + r;
                if (row < N) outp[(size_t)row * HID + col] = acc0[r] + bv;
            }
            #pragma unroll
            for (int r = 0; r < 4; r++) {
                int row = row0 + 16 + rb + r;
                if (row < N) outp[(size_t)row * HID + col] = acc1[r] + bv;
            }
        }
    }
}

// ---------------------------------------------------------------- layer-1 f32 transform (K=16)
__global__ __launch_bounds__(256) void transform16_kernel(
    const float* __restrict__ Hin,
    const float* __restrict__ W0, const float* __restrict__ b0, float* __restrict__ o0,
    const float* __restrict__ W1, const float* __restrict__ b1, float* __restrict__ o1,
    int N) {
    constexpr int K = 16;
    __shared__ float Ws[K][HID];
    __shared__ float Hs[32][K + 4];

    const float* W; const float* bias; float* outp;
    if (blockIdx.z == 0) { W = W0; bias = b0; outp = o0; }
    else                 { W = W1; bias = b1; outp = o1; }

    int row0 = blockIdx.x * 32;
    int tid = threadIdx.x;
    int tx = tid & 15, ty = tid >> 4;

    for (int i = tid; i < 32 * (K / 4); i += 256) {
        int r = i / (K / 4), kq = i % (K / 4);
        int row = row0 + r;
        float4 v = make_float4(0.f, 0.f, 0.f, 0.f);
        if (row < N) v = *(const float4*)(Hin + (size_t)row * K + kq * 4);
        *(float4*)&Hs[r][kq * 4] = v;
    }
    for (int i = tid; i < K * 32; i += 256) {
        int k = i >> 5, cq = i & 31;
        *(float4*)&Ws[k][cq * 4] = *(const float4*)(W + (size_t)k * HID + cq * 4);
    }
    __syncthreads();

    float acc[2][8];
    #pragma unroll
    for (int i = 0; i < 2; i++)
        #pragma unroll
        for (int j = 0; j < 8; j++) acc[i][j] = 0.f;

    int r0 = ty * 2, r1 = ty * 2 + 1;
    #pragma unroll
    for (int k = 0; k < K; k++) {
        float a0 = Hs[r0][k];
        float a1 = Hs[r1][k];
        float4 w0 = *(float4*)&Ws[k][tx * 4];
        float4 w1 = *(float4*)&Ws[k][64 + tx * 4];
        acc[0][0] += a0 * w0.x; acc[0][1] += a0 * w0.y; acc[0][2] += a0 * w0.z; acc[0][3] += a0 * w0.w;
        acc[0][4] += a0 * w1.x; acc[0][5] += a0 * w1.y; acc[0][6] += a0 * w1.z; acc[0][7] += a0 * w1.w;
        acc[1][0] += a1 * w0.x; acc[1][1] += a1 * w0.y; acc[1][2] += a1 * w0.z; acc[1][3] += a1 * w0.w;
        acc[1][4] += a1 * w1.x; acc[1][5] += a1 * w1.y; acc[1][6] += a1 * w1.z; acc[1][7] += a1 * w1.w;
    }

    float4 bb0 = *(const float4*)(bias + tx * 4);
    float4 bb1 = *(const float4*)(bias + 64 + tx * 4);
    #pragma unroll
    for (int i = 0; i < 2; i++) {
        int row = row0 + ty * 2 + i;
        if (row < N) {
            float4 v0 = make_float4(acc[i][0] + bb0.x, acc[i][1] + bb0.y, acc[i][2] + bb0.z, acc[i][3] + bb0.w);
            float4 v1 = make_float4(acc[i][4] + bb1.x, acc[i][5] + bb1.y, acc[i][6] + bb1.z, acc[i][7] + bb1.w);
            *(float4*)(outp + (size_t)row * HID + tx * 4) = v0;
            *(float4*)(outp + (size_t)row * HID + 64 + tx * 4) = v1;
        }
    }
}

// ---------------------------------------------------------------- layer-1 combine + bf16 split emit
__global__ __launch_bounds__(256) void combine16_kernel(
    const float* __restrict__ Hin,
    const float* __restrict__ W, const float* __restrict__ bias,
    float* __restrict__ Hio, unsigned short* __restrict__ Hhi, unsigned short* __restrict__ Hlo,
    int N) {
    constexpr int K = 16;
    __shared__ float Ws[K][HID];
    __shared__ float Hs[32][K + 4];

    int row0 = blockIdx.x * 32;
    int tid = threadIdx.x;
    int tx = tid & 15, ty = tid >> 4;

    for (int i = tid; i < 32 * (K / 4); i += 256) {
        int r = i / (K / 4), kq = i % (K / 4);
        int row = row0 + r;
        float4 v = make_float4(0.f, 0.f, 0.f, 0.f);
        if (row < N) v = *(const float4*)(Hin + (size_t)row * K + kq * 4);
        *(float4*)&Hs[r][kq * 4] = v;
    }
    for (int i = tid; i < K * 32; i += 256) {
        int k = i >> 5, cq = i & 31;
        *(float4*)&Ws[k][cq * 4] = *(const float4*)(W + (size_t)k * HID + cq * 4);
    }
    __syncthreads();

    float acc[2][8];
    #pragma unroll
    for (int i = 0; i < 2; i++)
        #pragma unroll
        for (int j = 0; j < 8; j++) acc[i][j] = 0.f;

    int r0 = ty * 2, r1 = ty * 2 + 1;
    #pragma unroll
    for (int k = 0; k < K; k++) {
        float a0 = Hs[r0][k];
        float a1 = Hs[r1][k];
        float4 w0 = *(float4*)&Ws[k][tx * 4];
        float4 w1 = *(float4*)&Ws[k][64 + tx * 4];
        acc[0][0] += a0 * w0.x; acc[0][1] += a0 * w0.y; acc[0][2] += a0 * w0.z; acc[0][3] += a0 * w0.w;
        acc[0][4] += a0 * w1.x; acc[0][5] += a0 * w1.y; acc[0][6] += a0 * w1.z; acc[0][7] += a0 * w1.w;
        acc[1][0] += a1 * w0.x; acc[1][1] += a1 * w0.y; acc[1][2] += a1 * w0.z; acc[1][3] += a1 * w0.w;
        acc[1][4] += a1 * w1.x; acc[1][5] += a1 * w1.y; acc[1][6] += a1 * w1.z; acc[1][7] += a1 * w1.w;
    }

    float4 bb0 = *(const float4*)(bias + tx * 4);
    float4 bb1 = *(const float4*)(bias + 64 + tx * 4);
    #pragma unroll
    for (int i = 0; i < 2; i++) {
        int row = row0 + ty * 2 + i;
        if (row < N) {
            float* p0 = Hio + (size_t)row * HID + tx * 4;
            float* p1 = p0 + 64;
            float4 g0 = *(float4*)p0;
            float4 g1 = *(float4*)p1;
            float v[8];
            v[0] = g0.x + acc[i][0] + bb0.x; v[1] = g0.y + acc[i][1] + bb0.y;
            v[2] = g0.z + acc[i][2] + bb0.z; v[3] = g0.w + acc[i][3] + bb0.w;
            v[4] = g1.x + acc[i][4] + bb1.x; v[5] = g1.y + acc[i][5] + bb1.y;
            v[6] = g1.z + acc[i][6] + bb1.z; v[7] = g1.w + acc[i][7] + bb1.w;
            #pragma unroll
            for (int j = 0; j < 8; j++) v[j] = (v[j] > 0.f) ? v[j] : (__expf(v[j]) - 1.f);
            *(float4*)p0 = make_float4(v[0], v[1], v[2], v[3]);
            *(float4*)p1 = make_float4(v[4], v[5], v[6], v[7]);
            ushort4 h0, h1, l0, l1;
            h0.x = f2bf(v[0]); h0.y = f2bf(v[1]); h0.z = f2bf(v[2]); h0.w = f2bf(v[3]);
            h1.x = f2bf(v[4]); h1.y = f2bf(v[5]); h1.z = f2bf(v[6]); h1.w = f2bf(v[7]);
            l0.x = f2bf(v[0] - bf2f(h0.x)); l0.y = f2bf(v[1] - bf2f(h0.y));
            l0.z = f2bf(v[2] - bf2f(h0.z)); l0.w = f2bf(v[3] - bf2f(h0.w));
            l1.x = f2bf(v[4] - bf2f(h1.x)); l1.y = f2bf(v[5] - bf2f(h1.y));
            l1.z = f2bf(v[6] - bf2f(h1.z)); l1.w = f2bf(v[7] - bf2f(h1.w));
            *(ushort4*)(Hhi + (size_t)row * HID + tx * 4) = h0;
            *(ushort4*)(Hhi + (size_t)row * HID + 64 + tx * 4) = h1;
            *(ushort4*)(Hlo + (size_t)row * HID + tx * 4) = l0;
            *(ushort4*)(Hlo + (size_t)row * HID + 64 + tx * 4) = l1;
        }
    }
}

// ---------------------------------------------------------------- edge/attention: one wave per dst, online softmax
template <int FUSE>
__global__ __launch_bounds__(256) void edge_kernel(
    const float* __restrict__ XL, const float* __restrict__ XR,
    const int* __restrict__ row_ptr, const int* __restrict__ csr_src,
    const float2* __restrict__ csr_ea,
    const float* __restrict__ att,
    const float* __restrict__ We,
    const float* __restrict__ gbias,
    const float* __restrict__ lin,
    float* __restrict__ hf, unsigned short* __restrict__ hhi, unsigned short* __restrict__ hlo,
    int N) {
    int n = (blockIdx.x * 256 + threadIdx.x) >> 6;
    int lane = threadIdx.x & 63;
    if (n >= N) return;

    int c0 = lane * 2;
    float2 xr = *(const float2*)(XR + (size_t)n * HID + c0);
    float2 av = *(const float2*)(att + c0);
    float2 we0 = *(const float2*)(We + c0);
    float2 we1 = *(const float2*)(We + HID + c0);

    int eb = row_ptr[n], eend = row_ptr[n + 1];

    float m_run = -INFINITY, l_run = 0.f, acc0 = 0.f, acc1 = 0.f;
    for (int e = eb; e < eend; e++) {
        int s = csr_src[e];
        float2 ea = csr_ea[e];
        float2 xl = *(const float2*)(XL + (size_t)s * HID + c0);
        float m0 = xl.x + xr.x + ea.x * we0.x + ea.y * we1.x;
        float m1 = xl.y + xr.y + ea.x * we0.y + ea.y * we1.y;
        m0 = (m0 > 0.f) ? m0 : 0.2f * m0;
        m1 = (m1 > 0.f) ? m1 : 0.2f * m1;
        float part = m0 * av.x + m1 * av.y;
        part += __shfl_xor(part, 1);
        part += __shfl_xor(part, 2);
        part += __shfl_xor(part, 4);
        float m_new = fmaxf(m_run, part);
        float scale = (m_run == -INFINITY) ? 0.f : __expf(m_run - m_new);
        float p = __expf(part - m_new);
        l_run = l_run * scale + p;
        acc0 = acc0 * scale + p * xl.x;
        acc1 = acc1 * scale + p * xl.y;
        m_run = m_new;
    }
    float inv = 1.f / fmaxf(l_run, 1e-16f);
    float v0 = acc0 * inv + gbias[c0];
    float v1 = acc1 * inv + gbias[c0 + 1];
    if constexpr (FUSE) {
        float2 lv = *(const float2*)(lin + (size_t)n * HID + c0);
        v0 += lv.x; v1 += lv.y;
        v0 = (v0 > 0.f) ? v0 : (__expf(v0) - 1.f);
        v1 = (v1 > 0.f) ? v1 : (__expf(v1) - 1.f);
        *(float2*)(hf + (size_t)n * HID + c0) = make_float2(v0, v1);
        unsigned short h0 = f2bf(v0), h1 = f2bf(v1);
        ushort2 hh; hh.x = h0; hh.y = h1;
        ushort2 ll; ll.x = f2bf(v0 - bf2f(h0)); ll.y = f2bf(v1 - bf2f(h1));
        *(ushort2*)(hhi + (size_t)n * HID + c0) = hh;
        *(ushort2*)(hlo + (size_t)n * HID + c0) = ll;
    } else {
        *(float2*)(hf + (size_t)n * HID + c0) = make_float2(v0, v1);
    }
}

// ---------------------------------------------------------------- mean pool per graph
__global__ __launch_bounds__(128) void pool_kernel(const float* __restrict__ h,
                                                   const int* __restrict__ batch,
                                                   float* __restrict__ g, int N) {
    int gid = blockIdx.x;
    int lo = lower_bound_i(batch, N, gid);
    int hi = lower_bound_i(batch, N, gid + 1);
    int c = threadIdx.x;
    float s = 0.f;
    for (int i = lo; i < hi; i++) s += h[(size_t)i * HID + c];
    g[gid * HID + c] = s / fmaxf((float)(hi - lo), 1.0f);
}

// ---------------------------------------------------------------- readout GEMM
__global__ __launch_bounds__(256) void readout_kernel(const float* __restrict__ g,
                                                      const float* __restrict__ W,
                                                      const float* __restrict__ b,
                                                      float* __restrict__ out, int S) {
    __shared__ float gs[HID];
    int gid = blockIdx.y;
    if (threadIdx.x < HID) gs[threadIdx.x] = g[gid * HID + threadIdx.x];
    __syncthreads();
    int c = blockIdx.x * 256 + threadIdx.x;
    if (c < S) {
        float acc = b[c];
        #pragma unroll 8
        for (int k = 0; k < HID; k++) acc += gs[k] * W[(size_t)k * S + c];
        out[(size_t)gid * S + c] = acc;
    }
}

// ---------------------------------------------------------------- launcher
extern "C" void kernel_launch(void* const* d_in, const int* in_sizes, int n_in,
                              void* d_out, int out_size, void* d_ws, size_t ws_size,
                              hipStream_t stream) {
    const float* x      = (const float*)d_in[0];
    const int*   ei     = (const int*)d_in[1];
    const float* eattr  = (const float*)d_in[2];
    const int*   batch  = (const int*)d_in[3];
    const float* at1_Wl = (const float*)d_in[4];
    const float* at1_bl = (const float*)d_in[5];
    const float* at1_Wr = (const float*)d_in[6];
    const float* at1_br = (const float*)d_in[7];
    const float* at1_We = (const float*)d_in[8];
    const float* at1_att= (const float*)d_in[9];
    const float* at1_b  = (const float*)d_in[10];
    const float* l1_W   = (const float*)d_in[11];
    const float* l1_b   = (const float*)d_in[12];
    const float* atk_Wl = (const float*)d_in[13];
    const float* atk_bl = (const float*)d_in[14];
    const float* atk_Wr = (const float*)d_in[15];
    const float* atk_br = (const float*)d_in[16];
    const float* atk_We = (const float*)d_in[17];
    const float* atk_att= (const float*)d_in[18];
    const float* atk_b  = (const float*)d_in[19];
    const float* lk_W   = (const float*)d_in[20];
    const float* lk_b   = (const float*)d_in[21];
    const float* lin_W  = (const float*)d_in[22];
    const float* lin_b  = (const float*)d_in[23];
    float* out = (float*)d_out;

    const int N  = in_sizes[0] / 16;
    const int E  = in_sizes[1] / 2;
    const int ET = E + N;
    const int S  = 1000;
    const int G  = out_size / S;

    char* w = (char*)d_ws;
    auto alloc = [&](size_t bytes) -> char* {
        char* p = w; w += (bytes + 255) & ~(size_t)255; return p;
    };
    float*  XL      = (float*)alloc((size_t)N * HID * 4);
    float*  XR      = (float*)alloc((size_t)N * HID * 4);
    float*  Lin     = (float*)alloc((size_t)N * HID * 4);
    float*  Hf      = (float*)alloc((size_t)N * HID * 4);
    unsigned short* Hhi = (unsigned short*)alloc((size_t)N * HID * 2);
    unsigned short* Hlo = (unsigned short*)alloc((size_t)N * HID * 2);
    int*    deg     = (int*)alloc((size_t)N * 4);
    int*    row_ptr = (int*)alloc((size_t)(N + 1) * 4);
    int*    cursor  = (int*)alloc((size_t)N * 4);
    int*    csr_src = (int*)alloc((size_t)ET * 4);
    float2* csr_ea  = (float2*)alloc((size_t)ET * 8);
    float*  meansum = (float*)alloc(8);
    int*    bsum    = (int*)alloc(256);
    int*    boff    = (int*)alloc(256);
    unsigned short* WlTh = (unsigned short*)alloc((size_t)9 * 16384 * 2);
    unsigned short* WlTl = (unsigned short*)alloc((size_t)9 * 16384 * 2);
    unsigned short* WrTh = (unsigned short*)alloc((size_t)9 * 16384 * 2);
    unsigned short* WrTl = (unsigned short*)alloc((size_t)9 * 16384 * 2);
    unsigned short* WkTh = (unsigned short*)alloc((size_t)9 * 16384 * 2);
    unsigned short* WkTl = (unsigned short*)alloc((size_t)9 * 16384 * 2);
    float*  gpool   = (float*)alloc((size_t)G * HID * 4);
    (void)ws_size; (void)n_in;

    hipMemsetAsync(deg, 0, (size_t)N * 4, stream);
    hipMemsetAsync(meansum, 0, 8, stream);

    const int wtot = 9 * 16384;
    wprep_kernel<<<(wtot + 255) / 256, 256, 0, stream>>>(atk_Wl, WlTh, WlTl, wtot);
    wprep_kernel<<<(wtot + 255) / 256, 256, 0, stream>>>(atk_Wr, WrTh, WrTl, wtot);
    wprep_kernel<<<(wtot + 255) / 256, 256, 0, stream>>>(lk_W,   WkTh, WkTl, wtot);

    mean_kernel<<<256, 256, 0, stream>>>(eattr, meansum, E);
    deg_kernel<<<(ET + 255) / 256, 256, 0, stream>>>(ei, deg, E, ET);
    const int NB = (N + 1023) / 1024;
    scanA_kernel<<<NB, 256, 0, stream>>>(deg, bsum, N);
    scanB_kernel<<<1, 64, 0, stream>>>(bsum, boff, row_ptr, NB, N);
    scanC_kernel<<<NB, 256, 0, stream>>>(deg, boff, row_ptr, cursor, N);
    fill_kernel<<<(ET + 255) / 256, 256, 0, stream>>>(ei, eattr, meansum, cursor, csr_src, csr_ea, E, ET);

    const int gx16 = (N + 31) / 32;
    const int ge   = (N * 64 + 255) / 256;
    const int gx3  = (N + 127) / 128;

    transform16_kernel<<<dim3(gx16, 1, 2), 256, 0, stream>>>(x, at1_Wl, at1_bl, XL, at1_Wr, at1_br, XR, N);
    edge_kernel<0><<<ge, 256, 0, stream>>>(XL, XR, row_ptr, csr_src, csr_ea, at1_att, at1_We, at1_b,
                                           nullptr, Hf, nullptr, nullptr, N);
    combine16_kernel<<<gx16, 256, 0, stream>>>(x, l1_W, l1_b, Hf, Hhi, Hlo, N);

    for (int i = 0; i < 9; i++) {
        const unsigned short* wlh = WlTh + (size_t)i * 16384;
        const unsigned short* wll = WlTl + (size_t)i * 16384;
        const unsigned short* wrh = WrTh + (size_t)i * 16384;
        const unsigned short* wrl = WrTl + (size_t)i * 16384;
        const unsigned short* wkh = WkTh + (size_t)i * 16384;
        const unsigned short* wkl = WkTl + (size_t)i * 16384;
        const float* bl = atk_bl + (size_t)i * HID;
        const float* br = atk_br + (size_t)i * HID;
        const float* bk = lk_b   + (size_t)i * HID;
        const float* Wep = atk_We + (size_t)i * 2 * HID;
        const float* at = atk_att + (size_t)i * HID;
        const float* ab = atk_b  + (size_t)i * HID;

        gemm3_kernel<<<gx3, 256, 0, stream>>>(Hhi, Hlo,
                                              wlh, wll, bl, XL,
                                              wrh, wrl, br, XR,
                                              wkh, wkl, bk, Lin, N);
        edge_kernel<1><<<ge, 256, 0, stream>>>(XL, XR, row_ptr, csr_src, csr_ea, at, Wep, ab,
                                               Lin, Hf, Hhi, Hlo, N);
    }

    pool_kernel<<<G, 128, 0, stream>>>(Hf, batch, gpool, N);
    readout_kernel<<<dim3((S + 255) / 256, G), 256, 0, stream>>>(gpool, lin_W, lin_b, out, S);
}

// Round 5
// 1165.650 us; speedup vs baseline: 1.6238x; 1.2898x over previous
//
#include <hip/hip_runtime.h>
#include <hip/hip_bf16.h>
#include <cstdint>

#define HID 128

typedef __attribute__((ext_vector_type(8))) short bf16x8;
typedef __attribute__((ext_vector_type(4))) float f32x4;

__device__ __forceinline__ unsigned short f2bf(float x) {
    __hip_bfloat16 h = __float2bfloat16(x);
    return __builtin_bit_cast(unsigned short, h);
}
__device__ __forceinline__ float bf2f(unsigned short u) {
    return __bfloat162float(__builtin_bit_cast(__hip_bfloat16, u));
}
__device__ __forceinline__ float bflo(unsigned u) {
    return __builtin_bit_cast(float, u << 16);
}
__device__ __forceinline__ float bfhi(unsigned u) {
    return __builtin_bit_cast(float, u & 0xffff0000u);
}
__device__ __forceinline__ int lower_bound_i(const int* a, int n, int v) {
    int lo = 0, hi = n;
    while (lo < hi) { int m = (lo + hi) >> 1; if (a[m] < v) lo = m + 1; else hi = m; }
    return lo;
}

// ---------------------------------------------------------------- mean of edge_attr
__global__ __launch_bounds__(256) void mean_kernel(const float* __restrict__ eattr,
                                                   float* __restrict__ meansum, int E) {
    float sx = 0.f, sy = 0.f;
    for (int i = blockIdx.x * 256 + threadIdx.x; i < E; i += gridDim.x * 256) {
        float2 v = *(const float2*)(eattr + 2 * (size_t)i);
        sx += v.x; sy += v.y;
    }
    for (int d = 1; d < 64; d <<= 1) { sx += __shfl_xor(sx, d); sy += __shfl_xor(sy, d); }
    if ((threadIdx.x & 63) == 0) { atomicAdd(&meansum[0], sx); atomicAdd(&meansum[1], sy); }
}

// ---------------------------------------------------------------- CSR build
__global__ __launch_bounds__(256) void deg_kernel(const int* __restrict__ ei,
                                                  int* __restrict__ deg, int E, int ET) {
    int e = blockIdx.x * 256 + threadIdx.x;
    if (e >= ET) return;
    int dst = (e < E) ? ei[E + e] : (e - E);
    atomicAdd(&deg[dst], 1);
}

__global__ __launch_bounds__(256) void scanA_kernel(const int* __restrict__ deg,
                                                    int* __restrict__ bsum, int N) {
    __shared__ int ws[4];
    int t = threadIdx.x;
    int base = blockIdx.x * 1024 + t * 4;
    int s = 0;
    #pragma unroll
    for (int j = 0; j < 4; j++) { int idx = base + j; if (idx < N) s += deg[idx]; }
    for (int d = 1; d < 64; d <<= 1) s += __shfl_xor(s, d);
    if ((t & 63) == 0) ws[t >> 6] = s;
    __syncthreads();
    if (t == 0) bsum[blockIdx.x] = ws[0] + ws[1] + ws[2] + ws[3];
}

__global__ __launch_bounds__(64) void scanB_kernel(const int* __restrict__ bsum,
                                                   int* __restrict__ boff,
                                                   int* __restrict__ row_ptr, int NB, int N) {
    int t = threadIdx.x;
    int v = (t < NB) ? bsum[t] : 0;
    int inc = v;
    #pragma unroll
    for (int d = 1; d < 64; d <<= 1) { int u = __shfl_up(inc, d); if (t >= d) inc += u; }
    if (t < NB) boff[t] = inc - v;
    if (t == 63) row_ptr[N] = inc;
}

__global__ __launch_bounds__(256) void scanC_kernel(const int* __restrict__ deg,
                                                    const int* __restrict__ boff,
                                                    int* __restrict__ row_ptr,
                                                    int* __restrict__ cursor, int N) {
    __shared__ int wsum[4];
    int t = threadIdx.x;
    int lane = t & 63, wid = t >> 6;
    int base = blockIdx.x * 1024 + t * 4;
    int v[4]; int s = 0;
    #pragma unroll
    for (int j = 0; j < 4; j++) { int idx = base + j; v[j] = (idx < N) ? deg[idx] : 0; s += v[j]; }
    int inc = s;
    #pragma unroll
    for (int d = 1; d < 64; d <<= 1) { int u = __shfl_up(inc, d); if (lane >= d) inc += u; }
    if (lane == 63) wsum[wid] = inc;
    __syncthreads();
    int woff = 0;
    for (int ww = 0; ww < wid; ww++) woff += wsum[ww];
    int excl = boff[blockIdx.x] + woff + inc - s;
    #pragma unroll
    for (int j = 0; j < 4; j++) {
        int idx = base + j;
        if (idx < N) { row_ptr[idx] = excl; cursor[idx] = excl; }
        excl += v[j];
    }
}

__global__ __launch_bounds__(256) void fill_kernel(const int* __restrict__ ei,
                                                   const float* __restrict__ eattr,
                                                   const float* __restrict__ meansum,
                                                   int* __restrict__ cursor,
                                                   int* __restrict__ csr_src,
                                                   unsigned int* __restrict__ csr_eap,
                                                   int E, int ET) {
    int e = blockIdx.x * 256 + threadIdx.x;
    if (e >= ET) return;
    int src, dst; float2 ea;
    if (e < E) {
        src = ei[e]; dst = ei[E + e];
        ea = *(const float2*)(eattr + 2 * (size_t)e);
    } else {
        src = dst = e - E;
        float inv = 1.0f / (float)E;
        ea.x = meansum[0] * inv; ea.y = meansum[1] * inv;
    }
    unsigned pea = (unsigned)f2bf(ea.x) | ((unsigned)f2bf(ea.y) << 16);
    int pos = atomicAdd(&cursor[dst], 1);
    csr_src[pos] = src;
    csr_eap[pos] = pea;
}

// ---------------------------------------------------------------- weight prep: transpose + bf16 hi/lo split
__global__ __launch_bounds__(256) void wprep_kernel(const float* __restrict__ src,
                                                    unsigned short* __restrict__ hi,
                                                    unsigned short* __restrict__ lo, int total) {
    int idx = blockIdx.x * 256 + threadIdx.x;
    if (idx >= total) return;
    int layer = idx >> 14;
    int rem = idx & 16383;
    int n = rem >> 7, k = rem & 127;
    float w = src[(layer << 14) | (k << 7) | n];
    unsigned short h = f2bf(w);
    hi[idx] = h;
    lo[idx] = f2bf(w - bf2f(h));
}

// ---------------------------------------------------------------- 3-GEMM, bf16x3-split MFMA, blockIdx.y selects W
__global__ __launch_bounds__(256) void gemm3_kernel(
    const unsigned short* __restrict__ Ahi, const unsigned short* __restrict__ Alo,
    const unsigned short* __restrict__ W0h, const unsigned short* __restrict__ W0l,
    const float* __restrict__ b0, float* __restrict__ o0,
    const unsigned short* __restrict__ W1h, const unsigned short* __restrict__ W1l,
    const float* __restrict__ b1, float* __restrict__ o1,
    const unsigned short* __restrict__ W2h, const unsigned short* __restrict__ W2l,
    const float* __restrict__ b2, float* __restrict__ o2, int N) {
    int y = blockIdx.y;
    const unsigned short* wh  = (y == 0) ? W0h : (y == 1) ? W1h : W2h;
    const unsigned short* wlp = (y == 0) ? W0l : (y == 1) ? W1l : W2l;
    const float* bias = (y == 0) ? b0 : (y == 1) ? b1 : b2;
    float* outp = (y == 0) ? o0 : (y == 1) ? o1 : o2;

    int tid = threadIdx.x;
    int wid = tid >> 6, lane = tid & 63;
    int row0 = blockIdx.x * 128 + wid * 32;
    if (row0 >= N) return;
    int lr = lane & 15;
    int kb = (lane >> 4) * 8;

    bf16x8 ah[2][4], al[2][4];
    #pragma unroll
    for (int mf = 0; mf < 2; mf++) {
        int row = row0 + mf * 16 + lr;
        int rowc = (row < N) ? row : (N - 1);   // clamped: OOB rows never stored
        const unsigned short* pa = Ahi + (size_t)rowc * HID + kb;
        const unsigned short* pl = Alo + (size_t)rowc * HID + kb;
        #pragma unroll
        for (int kf = 0; kf < 4; kf++) {
            ah[mf][kf] = *(const bf16x8*)(pa + kf * 32);
            al[mf][kf] = *(const bf16x8*)(pl + kf * 32);
        }
    }

    #pragma unroll 2
    for (int nf = 0; nf < 8; nf++) {
        int col = nf * 16 + lr;
        const unsigned short* pb = wh + (size_t)col * HID + kb;
        const unsigned short* pbl = wlp + (size_t)col * HID + kb;
        bf16x8 bh[4], bl4[4];
        #pragma unroll
        for (int kf = 0; kf < 4; kf++) {
            bh[kf] = *(const bf16x8*)(pb + kf * 32);
            bl4[kf] = *(const bf16x8*)(pbl + kf * 32);
        }
        // 6 independent 4-deep MFMA chains for ILP
        f32x4 hh0 = {0.f,0.f,0.f,0.f}, hl0 = {0.f,0.f,0.f,0.f}, lh0 = {0.f,0.f,0.f,0.f};
        f32x4 hh1 = {0.f,0.f,0.f,0.f}, hl1 = {0.f,0.f,0.f,0.f}, lh1 = {0.f,0.f,0.f,0.f};
        #pragma unroll
        for (int kf = 0; kf < 4; kf++) {
            hh0 = __builtin_amdgcn_mfma_f32_16x16x32_bf16(ah[0][kf], bh[kf], hh0, 0, 0, 0);
            hl0 = __builtin_amdgcn_mfma_f32_16x16x32_bf16(ah[0][kf], bl4[kf], hl0, 0, 0, 0);
            lh0 = __builtin_amdgcn_mfma_f32_16x16x32_bf16(al[0][kf], bh[kf], lh0, 0, 0, 0);
            hh1 = __builtin_amdgcn_mfma_f32_16x16x32_bf16(ah[1][kf], bh[kf], hh1, 0, 0, 0);
            hl1 = __builtin_amdgcn_mfma_f32_16x16x32_bf16(ah[1][kf], bl4[kf], hl1, 0, 0, 0);
            lh1 = __builtin_amdgcn_mfma_f32_16x16x32_bf16(al[1][kf], bh[kf], lh1, 0, 0, 0);
        }
        f32x4 acc0 = hh0 + hl0 + lh0;
        f32x4 acc1 = hh1 + hl1 + lh1;
        float bv = bias[col];
        int rb = (lane >> 4) * 4;
        #pragma unroll
        for (int r = 0; r < 4; r++) {
            int row = row0 + rb + r;
            if (row < N) outp[(size_t)row * HID + col] = acc0[r] + bv;
        }
        #pragma unroll
        for (int r = 0; r < 4; r++) {
            int row = row0 + 16 + rb + r;
            if (row < N) outp[(size_t)row * HID + col] = acc1[r] + bv;
        }
    }
}

// ---------------------------------------------------------------- layer-1 f32 transform (K=16)
__global__ __launch_bounds__(256) void transform16_kernel(
    const float* __restrict__ Hin,
    const float* __restrict__ W0, const float* __restrict__ b0, float* __restrict__ o0,
    const float* __restrict__ W1, const float* __restrict__ b1, float* __restrict__ o1,
    int N) {
    constexpr int K = 16;
    __shared__ float Ws[K][HID];
    __shared__ float Hs[32][K + 4];

    const float* W; const float* bias; float* outp;
    if (blockIdx.z == 0) { W = W0; bias = b0; outp = o0; }
    else                 { W = W1; bias = b1; outp = o1; }

    int row0 = blockIdx.x * 32;
    int tid = threadIdx.x;
    int tx = tid & 15, ty = tid >> 4;

    for (int i = tid; i < 32 * (K / 4); i += 256) {
        int r = i / (K / 4), kq = i % (K / 4);
        int row = row0 + r;
        float4 v = make_float4(0.f, 0.f, 0.f, 0.f);
        if (row < N) v = *(const float4*)(Hin + (size_t)row * K + kq * 4);
        *(float4*)&Hs[r][kq * 4] = v;
    }
    for (int i = tid; i < K * 32; i += 256) {
        int k = i >> 5, cq = i & 31;
        *(float4*)&Ws[k][cq * 4] = *(const float4*)(W + (size_t)k * HID + cq * 4);
    }
    __syncthreads();

    float acc[2][8];
    #pragma unroll
    for (int i = 0; i < 2; i++)
        #pragma unroll
        for (int j = 0; j < 8; j++) acc[i][j] = 0.f;

    int r0 = ty * 2, r1 = ty * 2 + 1;
    #pragma unroll
    for (int k = 0; k < K; k++) {
        float a0 = Hs[r0][k];
        float a1 = Hs[r1][k];
        float4 w0 = *(float4*)&Ws[k][tx * 4];
        float4 w1 = *(float4*)&Ws[k][64 + tx * 4];
        acc[0][0] += a0 * w0.x; acc[0][1] += a0 * w0.y; acc[0][2] += a0 * w0.z; acc[0][3] += a0 * w0.w;
        acc[0][4] += a0 * w1.x; acc[0][5] += a0 * w1.y; acc[0][6] += a0 * w1.z; acc[0][7] += a0 * w1.w;
        acc[1][0] += a1 * w0.x; acc[1][1] += a1 * w0.y; acc[1][2] += a1 * w0.z; acc[1][3] += a1 * w0.w;
        acc[1][4] += a1 * w1.x; acc[1][5] += a1 * w1.y; acc[1][6] += a1 * w1.z; acc[1][7] += a1 * w1.w;
    }

    float4 bb0 = *(const float4*)(bias + tx * 4);
    float4 bb1 = *(const float4*)(bias + 64 + tx * 4);
    #pragma unroll
    for (int i = 0; i < 2; i++) {
        int row = row0 + ty * 2 + i;
        if (row < N) {
            float4 v0 = make_float4(acc[i][0] + bb0.x, acc[i][1] + bb0.y, acc[i][2] + bb0.z, acc[i][3] + bb0.w);
            float4 v1 = make_float4(acc[i][4] + bb1.x, acc[i][5] + bb1.y, acc[i][6] + bb1.z, acc[i][7] + bb1.w);
            *(float4*)(outp + (size_t)row * HID + tx * 4) = v0;
            *(float4*)(outp + (size_t)row * HID + 64 + tx * 4) = v1;
        }
    }
}

// ---------------------------------------------------------------- layer-1 combine + bf16 split emit
__global__ __launch_bounds__(256) void combine16_kernel(
    const float* __restrict__ Hin,
    const float* __restrict__ W, const float* __restrict__ bias,
    float* __restrict__ Hio, unsigned short* __restrict__ Hhi, unsigned short* __restrict__ Hlo,
    int N) {
    constexpr int K = 16;
    __shared__ float Ws[K][HID];
    __shared__ float Hs[32][K + 4];

    int row0 = blockIdx.x * 32;
    int tid = threadIdx.x;
    int tx = tid & 15, ty = tid >> 4;

    for (int i = tid; i < 32 * (K / 4); i += 256) {
        int r = i / (K / 4), kq = i % (K / 4);
        int row = row0 + r;
        float4 v = make_float4(0.f, 0.f, 0.f, 0.f);
        if (row < N) v = *(const float4*)(Hin + (size_t)row * K + kq * 4);
        *(float4*)&Hs[r][kq * 4] = v;
    }
    for (int i = tid; i < K * 32; i += 256) {
        int k = i >> 5, cq = i & 31;
        *(float4*)&Ws[k][cq * 4] = *(const float4*)(W + (size_t)k * HID + cq * 4);
    }
    __syncthreads();

    float acc[2][8];
    #pragma unroll
    for (int i = 0; i < 2; i++)
        #pragma unroll
        for (int j = 0; j < 8; j++) acc[i][j] = 0.f;

    int r0 = ty * 2, r1 = ty * 2 + 1;
    #pragma unroll
    for (int k = 0; k < K; k++) {
        float a0 = Hs[r0][k];
        float a1 = Hs[r1][k];
        float4 w0 = *(float4*)&Ws[k][tx * 4];
        float4 w1 = *(float4*)&Ws[k][64 + tx * 4];
        acc[0][0] += a0 * w0.x; acc[0][1] += a0 * w0.y; acc[0][2] += a0 * w0.z; acc[0][3] += a0 * w0.w;
        acc[0][4] += a0 * w1.x; acc[0][5] += a0 * w1.y; acc[0][6] += a0 * w1.z; acc[0][7] += a0 * w1.w;
        acc[1][0] += a1 * w0.x; acc[1][1] += a1 * w0.y; acc[1][2] += a1 * w0.z; acc[1][3] += a1 * w0.w;
        acc[1][4] += a1 * w1.x; acc[1][5] += a1 * w1.y; acc[1][6] += a1 * w1.z; acc[1][7] += a1 * w1.w;
    }

    float4 bb0 = *(const float4*)(bias + tx * 4);
    float4 bb1 = *(const float4*)(bias + 64 + tx * 4);
    #pragma unroll
    for (int i = 0; i < 2; i++) {
        int row = row0 + ty * 2 + i;
        if (row < N) {
            float* p0 = Hio + (size_t)row * HID + tx * 4;
            float* p1 = p0 + 64;
            float4 g0 = *(float4*)p0;
            float4 g1 = *(float4*)p1;
            float v[8];
            v[0] = g0.x + acc[i][0] + bb0.x; v[1] = g0.y + acc[i][1] + bb0.y;
            v[2] = g0.z + acc[i][2] + bb0.z; v[3] = g0.w + acc[i][3] + bb0.w;
            v[4] = g1.x + acc[i][4] + bb1.x; v[5] = g1.y + acc[i][5] + bb1.y;
            v[6] = g1.z + acc[i][6] + bb1.z; v[7] = g1.w + acc[i][7] + bb1.w;
            #pragma unroll
            for (int j = 0; j < 8; j++) v[j] = (v[j] > 0.f) ? v[j] : (__expf(v[j]) - 1.f);
            *(float4*)p0 = make_float4(v[0], v[1], v[2], v[3]);
            *(float4*)p1 = make_float4(v[4], v[5], v[6], v[7]);
            ushort4 h0, h1, l0, l1;
            h0.x = f2bf(v[0]); h0.y = f2bf(v[1]); h0.z = f2bf(v[2]); h0.w = f2bf(v[3]);
            h1.x = f2bf(v[4]); h1.y = f2bf(v[5]); h1.z = f2bf(v[6]); h1.w = f2bf(v[7]);
            l0.x = f2bf(v[0] - bf2f(h0.x)); l0.y = f2bf(v[1] - bf2f(h0.y));
            l0.z = f2bf(v[2] - bf2f(h0.z)); l0.w = f2bf(v[3] - bf2f(h0.w));
            l1.x = f2bf(v[4] - bf2f(h1.x)); l1.y = f2bf(v[5] - bf2f(h1.y));
            l1.z = f2bf(v[6] - bf2f(h1.z)); l1.w = f2bf(v[7] - bf2f(h1.w));
            *(ushort4*)(Hhi + (size_t)row * HID + tx * 4) = h0;
            *(ushort4*)(Hhi + (size_t)row * HID + 64 + tx * 4) = h1;
            *(ushort4*)(Hlo + (size_t)row * HID + tx * 4) = l0;
            *(ushort4*)(Hlo + (size_t)row * HID + 64 + tx * 4) = l1;
        }
    }
}

// ---------------------------------------------------------------- edge/attention: 2 nodes per wave (32 lanes each),
// preloaded indices, packed bf16 edge attrs, 2 edges/iteration, 1-pair-ahead pipeline
template <int FUSE>
__global__ __launch_bounds__(256) void edge_kernel(
    const float* __restrict__ XL, const float* __restrict__ XR,
    const int* __restrict__ row_ptr, const int* __restrict__ csr_src,
    const unsigned int* __restrict__ csr_eap,
    const float* __restrict__ att,
    const float* __restrict__ We,
    const float* __restrict__ gbias,
    const float* __restrict__ lin,
    float* __restrict__ hf, unsigned short* __restrict__ hhi, unsigned short* __restrict__ hlo,
    int N) {
    int wv = (blockIdx.x * 256 + threadIdx.x) >> 6;
    int lane = threadIdx.x & 63;
    int half = lane >> 5;
    int l = lane & 31;
    int n = wv * 2 + half;
    bool active = (n < N);
    int nn = active ? n : 0;

    int c0 = l * 4;
    float4 av  = *(const float4*)(att + c0);
    float4 we0 = *(const float4*)(We + c0);
    float4 we1 = *(const float4*)(We + HID + c0);
    float4 xr  = *(const float4*)(XR + (size_t)nn * HID + c0);

    int eb = 0, eend = 0;
    if (active) { eb = row_ptr[n]; eend = row_ptr[n + 1]; }

    float m_run = -INFINITY, l_run = 0.f;
    float4 fa = make_float4(0.f, 0.f, 0.f, 0.f);

    for (int base = eb; base < eend; base += 32) {
        int cnt = min(32, eend - base);
        int myi = base + l;
        int msrc = 0; unsigned mea = 0;
        if (myi < eend) { msrc = csr_src[myi]; mea = csr_eap[myi]; }

        // pipeline prologue: pair 0
        int s0 = __shfl(msrc, 0, 32);
        int s1 = __shfl(msrc, 1, 32);
        unsigned e0 = __shfl(mea, 0, 32);
        unsigned e1 = __shfl(mea, 1, 32);
        float4 xl0 = *(const float4*)(XL + (size_t)s0 * HID + c0);
        float4 xl1 = *(const float4*)(XL + (size_t)s1 * HID + c0);

        for (int j = 0; ; j += 2) {
            bool more = (j + 2 < cnt);
            int ns0 = 0, ns1 = 0; unsigned ne0 = 0, ne1 = 0;
            float4 nxl0, nxl1;
            if (more) {
                ns0 = __shfl(msrc, j + 2, 32);
                ns1 = __shfl(msrc, j + 3, 32);
                ne0 = __shfl(mea, j + 2, 32);
                ne1 = __shfl(mea, j + 3, 32);
                nxl0 = *(const float4*)(XL + (size_t)ns0 * HID + c0);
                nxl1 = *(const float4*)(XL + (size_t)ns1 * HID + c0);
            }
            float ex0 = bflo(e0), ey0 = bfhi(e0);
            float ex1 = bflo(e1), ey1 = bfhi(e1);
            float t, part0, part1;
            float m0x = xl0.x + xr.x + ex0 * we0.x + ey0 * we1.x;
            float m0y = xl0.y + xr.y + ex0 * we0.y + ey0 * we1.y;
            float m0z = xl0.z + xr.z + ex0 * we0.z + ey0 * we1.z;
            float m0w = xl0.w + xr.w + ex0 * we0.w + ey0 * we1.w;
            m0x = fmaxf(m0x, 0.f) + 0.2f * fminf(m0x, 0.f);
            m0y = fmaxf(m0y, 0.f) + 0.2f * fminf(m0y, 0.f);
            m0z = fmaxf(m0z, 0.f) + 0.2f * fminf(m0z, 0.f);
            m0w = fmaxf(m0w, 0.f) + 0.2f * fminf(m0w, 0.f);
            part0 = m0x * av.x + m0y * av.y + m0z * av.z + m0w * av.w;
            float m1x = xl1.x + xr.x + ex1 * we0.x + ey1 * we1.x;
            float m1y = xl1.y + xr.y + ex1 * we0.y + ey1 * we1.y;
            float m1z = xl1.z + xr.z + ex1 * we0.z + ey1 * we1.z;
            float m1w = xl1.w + xr.w + ex1 * we0.w + ey1 * we1.w;
            m1x = fmaxf(m1x, 0.f) + 0.2f * fminf(m1x, 0.f);
            m1y = fmaxf(m1y, 0.f) + 0.2f * fminf(m1y, 0.f);
            m1z = fmaxf(m1z, 0.f) + 0.2f * fminf(m1z, 0.f);
            m1w = fmaxf(m1w, 0.f) + 0.2f * fminf(m1w, 0.f);
            part1 = m1x * av.x + m1y * av.y + m1z * av.z + m1w * av.w;
            // head reduce: head = 4 lanes (16 channels)
            t = __shfl_xor(part0, 1); part0 += t;
            t = __shfl_xor(part0, 2); part0 += t;
            t = __shfl_xor(part1, 1); part1 += t;
            t = __shfl_xor(part1, 2); part1 += t;

            bool two = (j + 1 < cnt);
            float pm = two ? fmaxf(part0, part1) : part0;
            float mx = fmaxf(m_run, pm);
            float sc = __expf(m_run - mx);   // first iter: exp(-inf)=0
            float p0 = __expf(part0 - mx);
            float p1 = two ? __expf(part1 - mx) : 0.f;
            l_run = l_run * sc + p0 + p1;
            fa.x = fa.x * sc + p0 * xl0.x + p1 * xl1.x;
            fa.y = fa.y * sc + p0 * xl0.y + p1 * xl1.y;
            fa.z = fa.z * sc + p0 * xl0.z + p1 * xl1.z;
            fa.w = fa.w * sc + p0 * xl0.w + p1 * xl1.w;
            m_run = mx;
            if (!more) break;
            s0 = ns0; s1 = ns1; e0 = ne0; e1 = ne1; xl0 = nxl0; xl1 = nxl1;
        }
    }

    if (!active) return;
    float inv = 1.f / fmaxf(l_run, 1e-16f);
    float4 bias4 = *(const float4*)(gbias + c0);
    float4 v;
    v.x = fa.x * inv + bias4.x;
    v.y = fa.y * inv + bias4.y;
    v.z = fa.z * inv + bias4.z;
    v.w = fa.w * inv + bias4.w;
    if constexpr (FUSE) {
        float4 lv = *(const float4*)(lin + (size_t)n * HID + c0);
        v.x += lv.x; v.y += lv.y; v.z += lv.z; v.w += lv.w;
        v.x = (v.x > 0.f) ? v.x : (__expf(v.x) - 1.f);
        v.y = (v.y > 0.f) ? v.y : (__expf(v.y) - 1.f);
        v.z = (v.z > 0.f) ? v.z : (__expf(v.z) - 1.f);
        v.w = (v.w > 0.f) ? v.w : (__expf(v.w) - 1.f);
        *(float4*)(hf + (size_t)n * HID + c0) = v;
        ushort4 hh, ll;
        hh.x = f2bf(v.x); hh.y = f2bf(v.y); hh.z = f2bf(v.z); hh.w = f2bf(v.w);
        ll.x = f2bf(v.x - bf2f(hh.x)); ll.y = f2bf(v.y - bf2f(hh.y));
        ll.z = f2bf(v.z - bf2f(hh.z)); ll.w = f2bf(v.w - bf2f(hh.w));
        *(ushort4*)(hhi + (size_t)n * HID + c0) = hh;
        *(ushort4*)(hlo + (size_t)n * HID + c0) = ll;
    } else {
        *(float4*)(hf + (size_t)n * HID + c0) = v;
    }
}

// ---------------------------------------------------------------- mean pool per graph
__global__ __launch_bounds__(128) void pool_kernel(const float* __restrict__ h,
                                                   const int* __restrict__ batch,
                                                   float* __restrict__ g, int N) {
    int gid = blockIdx.x;
    int lo = lower_bound_i(batch, N, gid);
    int hi = lower_bound_i(batch, N, gid + 1);
    int c = threadIdx.x;
    float s = 0.f;
    for (int i = lo; i < hi; i++) s += h[(size_t)i * HID + c];
    g[gid * HID + c] = s / fmaxf((float)(hi - lo), 1.0f);
}

// ---------------------------------------------------------------- readout GEMM
__global__ __launch_bounds__(256) void readout_kernel(const float* __restrict__ g,
                                                      const float* __restrict__ W,
                                                      const float* __restrict__ b,
                                                      float* __restrict__ out, int S) {
    __shared__ float gs[HID];
    int gid = blockIdx.y;
    if (threadIdx.x < HID) gs[threadIdx.x] = g[gid * HID + threadIdx.x];
    __syncthreads();
    int c = blockIdx.x * 256 + threadIdx.x;
    if (c < S) {
        float acc = b[c];
        #pragma unroll 8
        for (int k = 0; k < HID; k++) acc += gs[k] * W[(size_t)k * S + c];
        out[(size_t)gid * S + c] = acc;
    }
}

// ---------------------------------------------------------------- launcher
extern "C" void kernel_launch(void* const* d_in, const int* in_sizes, int n_in,
                              void* d_out, int out_size, void* d_ws, size_t ws_size,
                              hipStream_t stream) {
    const float* x      = (const float*)d_in[0];
    const int*   ei     = (const int*)d_in[1];
    const float* eattr  = (const float*)d_in[2];
    const int*   batch  = (const int*)d_in[3];
    const float* at1_Wl = (const float*)d_in[4];
    const float* at1_bl = (const float*)d_in[5];
    const float* at1_Wr = (const float*)d_in[6];
    const float* at1_br = (const float*)d_in[7];
    const float* at1_We = (const float*)d_in[8];
    const float* at1_att= (const float*)d_in[9];
    const float* at1_b  = (const float*)d_in[10];
    const float* l1_W   = (const float*)d_in[11];
    const float* l1_b   = (const float*)d_in[12];
    const float* atk_Wl = (const float*)d_in[13];
    const float* atk_bl = (const float*)d_in[14];
    const float* atk_Wr = (const float*)d_in[15];
    const float* atk_br = (const float*)d_in[16];
    const float* atk_We = (const float*)d_in[17];
    const float* atk_att= (const float*)d_in[18];
    const float* atk_b  = (const float*)d_in[19];
    const float* lk_W   = (const float*)d_in[20];
    const float* lk_b   = (const float*)d_in[21];
    const float* lin_W  = (const float*)d_in[22];
    const float* lin_b  = (const float*)d_in[23];
    float* out = (float*)d_out;

    const int N  = in_sizes[0] / 16;
    const int E  = in_sizes[1] / 2;
    const int ET = E + N;
    const int S  = 1000;
    const int G  = out_size / S;

    char* w = (char*)d_ws;
    auto alloc = [&](size_t bytes) -> char* {
        char* p = w; w += (bytes + 255) & ~(size_t)255; return p;
    };
    float*  XL      = (float*)alloc((size_t)N * HID * 4);
    float*  XR      = (float*)alloc((size_t)N * HID * 4);
    float*  Lin     = (float*)alloc((size_t)N * HID * 4);
    float*  Hf      = (float*)alloc((size_t)N * HID * 4);
    unsigned short* Hhi = (unsigned short*)alloc((size_t)N * HID * 2);
    unsigned short* Hlo = (unsigned short*)alloc((size_t)N * HID * 2);
    int*    deg     = (int*)alloc((size_t)N * 4);
    int*    row_ptr = (int*)alloc((size_t)(N + 1) * 4);
    int*    cursor  = (int*)alloc((size_t)N * 4);
    int*    csr_src = (int*)alloc((size_t)ET * 4);
    unsigned int* csr_eap = (unsigned int*)alloc((size_t)ET * 4);
    float*  meansum = (float*)alloc(8);
    int*    bsum    = (int*)alloc(256);
    int*    boff    = (int*)alloc(256);
    unsigned short* WlTh = (unsigned short*)alloc((size_t)9 * 16384 * 2);
    unsigned short* WlTl = (unsigned short*)alloc((size_t)9 * 16384 * 2);
    unsigned short* WrTh = (unsigned short*)alloc((size_t)9 * 16384 * 2);
    unsigned short* WrTl = (unsigned short*)alloc((size_t)9 * 16384 * 2);
    unsigned short* WkTh = (unsigned short*)alloc((size_t)9 * 16384 * 2);
    unsigned short* WkTl = (unsigned short*)alloc((size_t)9 * 16384 * 2);
    float*  gpool   = (float*)alloc((size_t)G * HID * 4);
    (void)ws_size; (void)n_in;

    hipMemsetAsync(deg, 0, (size_t)N * 4, stream);
    hipMemsetAsync(meansum, 0, 8, stream);

    const int wtot = 9 * 16384;
    wprep_kernel<<<(wtot + 255) / 256, 256, 0, stream>>>(atk_Wl, WlTh, WlTl, wtot);
    wprep_kernel<<<(wtot + 255) / 256, 256, 0, stream>>>(atk_Wr, WrTh, WrTl, wtot);
    wprep_kernel<<<(wtot + 255) / 256, 256, 0, stream>>>(lk_W,   WkTh, WkTl, wtot);

    mean_kernel<<<256, 256, 0, stream>>>(eattr, meansum, E);
    deg_kernel<<<(ET + 255) / 256, 256, 0, stream>>>(ei, deg, E, ET);
    const int NB = (N + 1023) / 1024;
    scanA_kernel<<<NB, 256, 0, stream>>>(deg, bsum, N);
    scanB_kernel<<<1, 64, 0, stream>>>(bsum, boff, row_ptr, NB, N);
    scanC_kernel<<<NB, 256, 0, stream>>>(deg, boff, row_ptr, cursor, N);
    fill_kernel<<<(ET + 255) / 256, 256, 0, stream>>>(ei, eattr, meansum, cursor, csr_src, csr_eap, E, ET);

    const int gx16 = (N + 31) / 32;
    const int ge   = (N + 7) / 8;        // 2 nodes per wave, 4 waves per block
    const int gx3  = (N + 127) / 128;

    transform16_kernel<<<dim3(gx16, 1, 2), 256, 0, stream>>>(x, at1_Wl, at1_bl, XL, at1_Wr, at1_br, XR, N);
    edge_kernel<0><<<ge, 256, 0, stream>>>(XL, XR, row_ptr, csr_src, csr_eap, at1_att, at1_We, at1_b,
                                           nullptr, Hf, nullptr, nullptr, N);
    combine16_kernel<<<gx16, 256, 0, stream>>>(x, l1_W, l1_b, Hf, Hhi, Hlo, N);

    for (int i = 0; i < 9; i++) {
        const unsigned short* wlh = WlTh + (size_t)i * 16384;
        const unsigned short* wll = WlTl + (size_t)i * 16384;
        const unsigned short* wrh = WrTh + (size_t)i * 16384;
        const unsigned short* wrl = WrTl + (size_t)i * 16384;
        const unsigned short* wkh = WkTh + (size_t)i * 16384;
        const unsigned short* wkl = WkTl + (size_t)i * 16384;
        const float* bl = atk_bl + (size_t)i * HID;
        const float* br = atk_br + (size_t)i * HID;
        const float* bk = lk_b   + (size_t)i * HID;
        const float* Wep = atk_We + (size_t)i * 2 * HID;
        const float* at = atk_att + (size_t)i * HID;
        const float* ab = atk_b  + (size_t)i * HID;

        gemm3_kernel<<<dim3(gx3, 3), 256, 0, stream>>>(Hhi, Hlo,
                                                       wlh, wll, bl, XL,
                                                       wrh, wrl, br, XR,
                                                       wkh, wkl, bk, Lin, N);
        edge_kernel<1><<<ge, 256, 0, stream>>>(XL, XR, row_ptr, csr_src, csr_eap, at, Wep, ab,
                                               Lin, Hf, Hhi, Hlo, N);
    }

    pool_kernel<<<G, 128, 0, stream>>>(Hf, batch, gpool, N);
    readout_kernel<<<dim3((S + 255) / 256, G), 256, 0, stream>>>(gpool, lin_W, lin_b, out, S);
}

// Round 6
// 1090.242 us; speedup vs baseline: 1.7361x; 1.0692x over previous
//
#include <hip/hip_runtime.h>
#include <hip/hip_bf16.h>
#include <cstdint>

#define HID 128

typedef __attribute__((ext_vector_type(8))) short bf16x8;
typedef __attribute__((ext_vector_type(4))) float f32x4;

__device__ __forceinline__ unsigned short f2bf(float x) {
    __hip_bfloat16 h = __float2bfloat16(x);
    return __builtin_bit_cast(unsigned short, h);
}
__device__ __forceinline__ float bf2f(unsigned short u) {
    return __bfloat162float(__builtin_bit_cast(__hip_bfloat16, u));
}
__device__ __forceinline__ float bflo(unsigned u) {
    return __builtin_bit_cast(float, u << 16);
}
__device__ __forceinline__ float bfhi(unsigned u) {
    return __builtin_bit_cast(float, u & 0xffff0000u);
}
__device__ __forceinline__ float4 ld4bf(const unsigned short* p) {
    ushort4 u = *(const ushort4*)p;
    return make_float4(bf2f(u.x), bf2f(u.y), bf2f(u.z), bf2f(u.w));
}
__device__ __forceinline__ int lower_bound_i(const int* a, int n, int v) {
    int lo = 0, hi = n;
    while (lo < hi) { int m = (lo + hi) >> 1; if (a[m] < v) lo = m + 1; else hi = m; }
    return lo;
}

// ---------------------------------------------------------------- mean of edge_attr
__global__ __launch_bounds__(256) void mean_kernel(const float* __restrict__ eattr,
                                                   float* __restrict__ meansum, int E) {
    float sx = 0.f, sy = 0.f;
    for (int i = blockIdx.x * 256 + threadIdx.x; i < E; i += gridDim.x * 256) {
        float2 v = *(const float2*)(eattr + 2 * (size_t)i);
        sx += v.x; sy += v.y;
    }
    for (int d = 1; d < 64; d <<= 1) { sx += __shfl_xor(sx, d); sy += __shfl_xor(sy, d); }
    if ((threadIdx.x & 63) == 0) { atomicAdd(&meansum[0], sx); atomicAdd(&meansum[1], sy); }
}

// ---------------------------------------------------------------- CSR build
__global__ __launch_bounds__(256) void deg_kernel(const int* __restrict__ ei,
                                                  int* __restrict__ deg, int E, int ET) {
    int e = blockIdx.x * 256 + threadIdx.x;
    if (e >= ET) return;
    int dst = (e < E) ? ei[E + e] : (e - E);
    atomicAdd(&deg[dst], 1);
}

__global__ __launch_bounds__(256) void scanA_kernel(const int* __restrict__ deg,
                                                    int* __restrict__ bsum, int N) {
    __shared__ int ws[4];
    int t = threadIdx.x;
    int base = blockIdx.x * 1024 + t * 4;
    int s = 0;
    #pragma unroll
    for (int j = 0; j < 4; j++) { int idx = base + j; if (idx < N) s += deg[idx]; }
    for (int d = 1; d < 64; d <<= 1) s += __shfl_xor(s, d);
    if ((t & 63) == 0) ws[t >> 6] = s;
    __syncthreads();
    if (t == 0) bsum[blockIdx.x] = ws[0] + ws[1] + ws[2] + ws[3];
}

__global__ __launch_bounds__(64) void scanB_kernel(const int* __restrict__ bsum,
                                                   int* __restrict__ boff,
                                                   int* __restrict__ row_ptr, int NB, int N) {
    int t = threadIdx.x;
    int v = (t < NB) ? bsum[t] : 0;
    int inc = v;
    #pragma unroll
    for (int d = 1; d < 64; d <<= 1) { int u = __shfl_up(inc, d); if (t >= d) inc += u; }
    if (t < NB) boff[t] = inc - v;
    if (t == 63) row_ptr[N] = inc;
}

__global__ __launch_bounds__(256) void scanC_kernel(const int* __restrict__ deg,
                                                    const int* __restrict__ boff,
                                                    int* __restrict__ row_ptr,
                                                    int* __restrict__ cursor, int N) {
    __shared__ int wsum[4];
    int t = threadIdx.x;
    int lane = t & 63, wid = t >> 6;
    int base = blockIdx.x * 1024 + t * 4;
    int v[4]; int s = 0;
    #pragma unroll
    for (int j = 0; j < 4; j++) { int idx = base + j; v[j] = (idx < N) ? deg[idx] : 0; s += v[j]; }
    int inc = s;
    #pragma unroll
    for (int d = 1; d < 64; d <<= 1) { int u = __shfl_up(inc, d); if (lane >= d) inc += u; }
    if (lane == 63) wsum[wid] = inc;
    __syncthreads();
    int woff = 0;
    for (int ww = 0; ww < wid; ww++) woff += wsum[ww];
    int excl = boff[blockIdx.x] + woff + inc - s;
    #pragma unroll
    for (int j = 0; j < 4; j++) {
        int idx = base + j;
        if (idx < N) { row_ptr[idx] = excl; cursor[idx] = excl; }
        excl += v[j];
    }
}

__global__ __launch_bounds__(256) void fill_kernel(const int* __restrict__ ei,
                                                   const float* __restrict__ eattr,
                                                   const float* __restrict__ meansum,
                                                   int* __restrict__ cursor,
                                                   int* __restrict__ csr_src,
                                                   unsigned int* __restrict__ csr_eap,
                                                   int E, int ET) {
    int e = blockIdx.x * 256 + threadIdx.x;
    if (e >= ET) return;
    int src, dst; float2 ea;
    if (e < E) {
        src = ei[e]; dst = ei[E + e];
        ea = *(const float2*)(eattr + 2 * (size_t)e);
    } else {
        src = dst = e - E;
        float inv = 1.0f / (float)E;
        ea.x = meansum[0] * inv; ea.y = meansum[1] * inv;
    }
    unsigned pea = (unsigned)f2bf(ea.x) | ((unsigned)f2bf(ea.y) << 16);
    int pos = atomicAdd(&cursor[dst], 1);
    csr_src[pos] = src;
    csr_eap[pos] = pea;
}

// ---------------------------------------------------------------- weight prep: transpose + bf16 hi/lo split
__global__ __launch_bounds__(256) void wprep_kernel(const float* __restrict__ src,
                                                    unsigned short* __restrict__ hi,
                                                    unsigned short* __restrict__ lo, int total) {
    int idx = blockIdx.x * 256 + threadIdx.x;
    if (idx >= total) return;
    int layer = idx >> 14;
    int rem = idx & 16383;
    int n = rem >> 7, k = rem & 127;
    float w = src[(layer << 14) | (k << 7) | n];
    unsigned short h = f2bf(w);
    hi[idx] = h;
    lo[idx] = f2bf(w - bf2f(h));
}

// ---------------------------------------------------------------- 3-GEMM, bf16x3-split MFMA, swapped operands:
// D = mfma(W_frag, H_frag) -> lane holds node=lane&15, 4 CONSECUTIVE channels -> packed 8B/16B stores.
// y=0,1 emit bf16 (XL/XR); y=2 emits f32 (Lin).
__global__ __launch_bounds__(256) void gemm3_kernel(
    const unsigned short* __restrict__ Ahi, const unsigned short* __restrict__ Alo,
    const unsigned short* __restrict__ W0h, const unsigned short* __restrict__ W0l,
    const float* __restrict__ b0, unsigned short* __restrict__ o0,
    const unsigned short* __restrict__ W1h, const unsigned short* __restrict__ W1l,
    const float* __restrict__ b1, unsigned short* __restrict__ o1,
    const unsigned short* __restrict__ W2h, const unsigned short* __restrict__ W2l,
    const float* __restrict__ b2, float* __restrict__ o2, int N) {
    int y = blockIdx.y;
    const unsigned short* wh  = (y == 0) ? W0h : (y == 1) ? W1h : W2h;
    const unsigned short* wlp = (y == 0) ? W0l : (y == 1) ? W1l : W2l;
    const float* bias = (y == 0) ? b0 : (y == 1) ? b1 : b2;
    unsigned short* outb = (y == 0) ? o0 : (y == 1) ? o1 : nullptr;

    int tid = threadIdx.x;
    int wid = tid >> 6, lane = tid & 63;
    int row0 = blockIdx.x * 128 + wid * 32;
    if (row0 >= N) return;
    int lr = lane & 15;           // node-in-frag (B/D) and out-ch-in-frag (A)
    int cgrp = lane >> 4;         // channel group in D
    int kb = cgrp * 8;            // k offset within 32-k frag

    // H fragments (B operand): node rows
    bf16x8 hh_[2][4], hl_[2][4];
    #pragma unroll
    for (int mf = 0; mf < 2; mf++) {
        int node = row0 + mf * 16 + lr;
        int nodec = (node < N) ? node : (N - 1);   // clamped: OOB nodes never stored
        const unsigned short* pa = Ahi + (size_t)nodec * HID + kb;
        const unsigned short* pl = Alo + (size_t)nodec * HID + kb;
        #pragma unroll
        for (int kf = 0; kf < 4; kf++) {
            hh_[mf][kf] = *(const bf16x8*)(pa + kf * 32);
            hl_[mf][kf] = *(const bf16x8*)(pl + kf * 32);
        }
    }

    #pragma unroll 2
    for (int nf = 0; nf < 8; nf++) {
        // W fragments (A operand): out-channel rows of Wt[n][k]
        const unsigned short* pw = wh + (size_t)(nf * 16 + lr) * HID + kb;
        const unsigned short* pwl = wlp + (size_t)(nf * 16 + lr) * HID + kb;
        bf16x8 wf[4], wfl[4];
        #pragma unroll
        for (int kf = 0; kf < 4; kf++) {
            wf[kf] = *(const bf16x8*)(pw + kf * 32);
            wfl[kf] = *(const bf16x8*)(pwl + kf * 32);
        }
        // 6 independent 4-deep MFMA chains: Wh*Hh + Wh*Hl + Wl*Hh
        f32x4 hh0 = {0.f,0.f,0.f,0.f}, hl0 = {0.f,0.f,0.f,0.f}, lh0 = {0.f,0.f,0.f,0.f};
        f32x4 hh1 = {0.f,0.f,0.f,0.f}, hl1 = {0.f,0.f,0.f,0.f}, lh1 = {0.f,0.f,0.f,0.f};
        #pragma unroll
        for (int kf = 0; kf < 4; kf++) {
            hh0 = __builtin_amdgcn_mfma_f32_16x16x32_bf16(wf[kf],  hh_[0][kf], hh0, 0, 0, 0);
            hl0 = __builtin_amdgcn_mfma_f32_16x16x32_bf16(wf[kf],  hl_[0][kf], hl0, 0, 0, 0);
            lh0 = __builtin_amdgcn_mfma_f32_16x16x32_bf16(wfl[kf], hh_[0][kf], lh0, 0, 0, 0);
            hh1 = __builtin_amdgcn_mfma_f32_16x16x32_bf16(wf[kf],  hh_[1][kf], hh1, 0, 0, 0);
            hl1 = __builtin_amdgcn_mfma_f32_16x16x32_bf16(wf[kf],  hl_[1][kf], hl1, 0, 0, 0);
            lh1 = __builtin_amdgcn_mfma_f32_16x16x32_bf16(wfl[kf], hh_[1][kf], lh1, 0, 0, 0);
        }
        f32x4 acc0 = hh0 + hl0 + lh0;
        f32x4 acc1 = hh1 + hl1 + lh1;
        int chb = nf * 16 + cgrp * 4;
        float4 bias4 = *(const float4*)(bias + chb);
        int node0 = row0 + lr;
        int node1 = row0 + 16 + lr;
        if (outb) {
            ushort4 u0, u1;
            u0.x = f2bf(acc0[0] + bias4.x); u0.y = f2bf(acc0[1] + bias4.y);
            u0.z = f2bf(acc0[2] + bias4.z); u0.w = f2bf(acc0[3] + bias4.w);
            u1.x = f2bf(acc1[0] + bias4.x); u1.y = f2bf(acc1[1] + bias4.y);
            u1.z = f2bf(acc1[2] + bias4.z); u1.w = f2bf(acc1[3] + bias4.w);
            if (node0 < N) *(ushort4*)(outb + (size_t)node0 * HID + chb) = u0;
            if (node1 < N) *(ushort4*)(outb + (size_t)node1 * HID + chb) = u1;
        } else {
            float4 f0 = make_float4(acc0[0] + bias4.x, acc0[1] + bias4.y, acc0[2] + bias4.z, acc0[3] + bias4.w);
            float4 f1 = make_float4(acc1[0] + bias4.x, acc1[1] + bias4.y, acc1[2] + bias4.z, acc1[3] + bias4.w);
            if (node0 < N) *(float4*)(o2 + (size_t)node0 * HID + chb) = f0;
            if (node1 < N) *(float4*)(o2 + (size_t)node1 * HID + chb) = f1;
        }
    }
}

// ---------------------------------------------------------------- layer-1 f32 transform (K=16)
__global__ __launch_bounds__(256) void transform16_kernel(
    const float* __restrict__ Hin,
    const float* __restrict__ W0, const float* __restrict__ b0, float* __restrict__ o0,
    const float* __restrict__ W1, const float* __restrict__ b1, float* __restrict__ o1,
    int N) {
    constexpr int K = 16;
    __shared__ float Ws[K][HID];
    __shared__ float Hs[32][K + 4];

    const float* W; const float* bias; float* outp;
    if (blockIdx.z == 0) { W = W0; bias = b0; outp = o0; }
    else                 { W = W1; bias = b1; outp = o1; }

    int row0 = blockIdx.x * 32;
    int tid = threadIdx.x;
    int tx = tid & 15, ty = tid >> 4;

    for (int i = tid; i < 32 * (K / 4); i += 256) {
        int r = i / (K / 4), kq = i % (K / 4);
        int row = row0 + r;
        float4 v = make_float4(0.f, 0.f, 0.f, 0.f);
        if (row < N) v = *(const float4*)(Hin + (size_t)row * K + kq * 4);
        *(float4*)&Hs[r][kq * 4] = v;
    }
    for (int i = tid; i < K * 32; i += 256) {
        int k = i >> 5, cq = i & 31;
        *(float4*)&Ws[k][cq * 4] = *(const float4*)(W + (size_t)k * HID + cq * 4);
    }
    __syncthreads();

    float acc[2][8];
    #pragma unroll
    for (int i = 0; i < 2; i++)
        #pragma unroll
        for (int j = 0; j < 8; j++) acc[i][j] = 0.f;

    int r0 = ty * 2, r1 = ty * 2 + 1;
    #pragma unroll
    for (int k = 0; k < K; k++) {
        float a0 = Hs[r0][k];
        float a1 = Hs[r1][k];
        float4 w0 = *(float4*)&Ws[k][tx * 4];
        float4 w1 = *(float4*)&Ws[k][64 + tx * 4];
        acc[0][0] += a0 * w0.x; acc[0][1] += a0 * w0.y; acc[0][2] += a0 * w0.z; acc[0][3] += a0 * w0.w;
        acc[0][4] += a0 * w1.x; acc[0][5] += a0 * w1.y; acc[0][6] += a0 * w1.z; acc[0][7] += a0 * w1.w;
        acc[1][0] += a1 * w0.x; acc[1][1] += a1 * w0.y; acc[1][2] += a1 * w0.z; acc[1][3] += a1 * w0.w;
        acc[1][4] += a1 * w1.x; acc[1][5] += a1 * w1.y; acc[1][6] += a1 * w1.z; acc[1][7] += a1 * w1.w;
    }

    float4 bb0 = *(const float4*)(bias + tx * 4);
    float4 bb1 = *(const float4*)(bias + 64 + tx * 4);
    #pragma unroll
    for (int i = 0; i < 2; i++) {
        int row = row0 + ty * 2 + i;
        if (row < N) {
            float4 v0 = make_float4(acc[i][0] + bb0.x, acc[i][1] + bb0.y, acc[i][2] + bb0.z, acc[i][3] + bb0.w);
            float4 v1 = make_float4(acc[i][4] + bb1.x, acc[i][5] + bb1.y, acc[i][6] + bb1.z, acc[i][7] + bb1.w);
            *(float4*)(outp + (size_t)row * HID + tx * 4) = v0;
            *(float4*)(outp + (size_t)row * HID + 64 + tx * 4) = v1;
        }
    }
}

// ---------------------------------------------------------------- layer-1 combine + bf16 split emit
__global__ __launch_bounds__(256) void combine16_kernel(
    const float* __restrict__ Hin,
    const float* __restrict__ W, const float* __restrict__ bias,
    float* __restrict__ Hio, unsigned short* __restrict__ Hhi, unsigned short* __restrict__ Hlo,
    int N) {
    constexpr int K = 16;
    __shared__ float Ws[K][HID];
    __shared__ float Hs[32][K + 4];

    int row0 = blockIdx.x * 32;
    int tid = threadIdx.x;
    int tx = tid & 15, ty = tid >> 4;

    for (int i = tid; i < 32 * (K / 4); i += 256) {
        int r = i / (K / 4), kq = i % (K / 4);
        int row = row0 + r;
        float4 v = make_float4(0.f, 0.f, 0.f, 0.f);
        if (row < N) v = *(const float4*)(Hin + (size_t)row * K + kq * 4);
        *(float4*)&Hs[r][kq * 4] = v;
    }
    for (int i = tid; i < K * 32; i += 256) {
        int k = i >> 5, cq = i & 31;
        *(float4*)&Ws[k][cq * 4] = *(const float4*)(W + (size_t)k * HID + cq * 4);
    }
    __syncthreads();

    float acc[2][8];
    #pragma unroll
    for (int i = 0; i < 2; i++)
        #pragma unroll
        for (int j = 0; j < 8; j++) acc[i][j] = 0.f;

    int r0 = ty * 2, r1 = ty * 2 + 1;
    #pragma unroll
    for (int k = 0; k < K; k++) {
        float a0 = Hs[r0][k];
        float a1 = Hs[r1][k];
        float4 w0 = *(float4*)&Ws[k][tx * 4];
        float4 w1 = *(float4*)&Ws[k][64 + tx * 4];
        acc[0][0] += a0 * w0.x; acc[0][1] += a0 * w0.y; acc[0][2] += a0 * w0.z; acc[0][3] += a0 * w0.w;
        acc[0][4] += a0 * w1.x; acc[0][5] += a0 * w1.y; acc[0][6] += a0 * w1.z; acc[0][7] += a0 * w1.w;
        acc[1][0] += a1 * w0.x; acc[1][1] += a1 * w0.y; acc[1][2] += a1 * w0.z; acc[1][3] += a1 * w0.w;
        acc[1][4] += a1 * w1.x; acc[1][5] += a1 * w1.y; acc[1][6] += a1 * w1.z; acc[1][7] += a1 * w1.w;
    }

    float4 bb0 = *(const float4*)(bias + tx * 4);
    float4 bb1 = *(const float4*)(bias + 64 + tx * 4);
    #pragma unroll
    for (int i = 0; i < 2; i++) {
        int row = row0 + ty * 2 + i;
        if (row < N) {
            float* p0 = Hio + (size_t)row * HID + tx * 4;
            float* p1 = p0 + 64;
            float4 g0 = *(float4*)p0;
            float4 g1 = *(float4*)p1;
            float v[8];
            v[0] = g0.x + acc[i][0] + bb0.x; v[1] = g0.y + acc[i][1] + bb0.y;
            v[2] = g0.z + acc[i][2] + bb0.z; v[3] = g0.w + acc[i][3] + bb0.w;
            v[4] = g1.x + acc[i][4] + bb1.x; v[5] = g1.y + acc[i][5] + bb1.y;
            v[6] = g1.z + acc[i][6] + bb1.z; v[7] = g1.w + acc[i][7] + bb1.w;
            #pragma unroll
            for (int j = 0; j < 8; j++) v[j] = (v[j] > 0.f) ? v[j] : (__expf(v[j]) - 1.f);
            *(float4*)p0 = make_float4(v[0], v[1], v[2], v[3]);
            *(float4*)p1 = make_float4(v[4], v[5], v[6], v[7]);
            ushort4 h0, h1, l0, l1;
            h0.x = f2bf(v[0]); h0.y = f2bf(v[1]); h0.z = f2bf(v[2]); h0.w = f2bf(v[3]);
            h1.x = f2bf(v[4]); h1.y = f2bf(v[5]); h1.z = f2bf(v[6]); h1.w = f2bf(v[7]);
            l0.x = f2bf(v[0] - bf2f(h0.x)); l0.y = f2bf(v[1] - bf2f(h0.y));
            l0.z = f2bf(v[2] - bf2f(h0.z)); l0.w = f2bf(v[3] - bf2f(h0.w));
            l1.x = f2bf(v[4] - bf2f(h1.x)); l1.y = f2bf(v[5] - bf2f(h1.y));
            l1.z = f2bf(v[6] - bf2f(h1.z)); l1.w = f2bf(v[7] - bf2f(h1.w));
            *(ushort4*)(Hhi + (size_t)row * HID + tx * 4) = h0;
            *(ushort4*)(Hhi + (size_t)row * HID + 64 + tx * 4) = h1;
            *(ushort4*)(Hlo + (size_t)row * HID + tx * 4) = l0;
            *(ushort4*)(Hlo + (size_t)row * HID + 64 + tx * 4) = l1;
        }
    }
}

// ---------------------------------------------------------------- edge/attention: 2 nodes per wave (32 lanes each).
// FUSE=0: f32 XL/XR (layer 1). FUSE=1: bf16 XL/XR; hf written only when non-null (last layer).
template <int FUSE>
__global__ __launch_bounds__(256) void edge_kernel(
    const void* __restrict__ XLv, const void* __restrict__ XRv,
    const int* __restrict__ row_ptr, const int* __restrict__ csr_src,
    const unsigned int* __restrict__ csr_eap,
    const float* __restrict__ att,
    const float* __restrict__ We,
    const float* __restrict__ gbias,
    const float* __restrict__ lin,
    float* __restrict__ hf, unsigned short* __restrict__ hhi, unsigned short* __restrict__ hlo,
    int N) {
    int wv = (blockIdx.x * 256 + threadIdx.x) >> 6;
    int lane = threadIdx.x & 63;
    int half = lane >> 5;
    int l = lane & 31;
    int n = wv * 2 + half;
    bool active = (n < N);
    int nn = active ? n : 0;

    int c0 = l * 4;
    float4 av  = *(const float4*)(att + c0);
    float4 we0 = *(const float4*)(We + c0);
    float4 we1 = *(const float4*)(We + HID + c0);

    auto ldx = [&](const void* p, int idx) -> float4 {
        if constexpr (FUSE) return ld4bf((const unsigned short*)p + (size_t)idx * HID + c0);
        else                return *(const float4*)((const float*)p + (size_t)idx * HID + c0);
    };
    float4 xr = ldx(XRv, nn);

    int eb = 0, eend = 0;
    if (active) { eb = row_ptr[n]; eend = row_ptr[n + 1]; }

    float m_run = -INFINITY, l_run = 0.f;
    float4 fa = make_float4(0.f, 0.f, 0.f, 0.f);

    for (int base = eb; base < eend; base += 32) {
        int cnt = min(32, eend - base);
        int myi = base + l;
        int msrc = 0; unsigned mea = 0;
        if (myi < eend) { msrc = csr_src[myi]; mea = csr_eap[myi]; }

        int s0 = __shfl(msrc, 0, 32);
        int s1 = __shfl(msrc, 1, 32);
        unsigned e0 = __shfl(mea, 0, 32);
        unsigned e1 = __shfl(mea, 1, 32);
        float4 xl0 = ldx(XLv, s0);
        float4 xl1 = ldx(XLv, s1);

        for (int j = 0; ; j += 2) {
            bool more = (j + 2 < cnt);
            int ns0 = 0, ns1 = 0; unsigned ne0 = 0, ne1 = 0;
            float4 nxl0, nxl1;
            if (more) {
                ns0 = __shfl(msrc, j + 2, 32);
                ns1 = __shfl(msrc, j + 3, 32);
                ne0 = __shfl(mea, j + 2, 32);
                ne1 = __shfl(mea, j + 3, 32);
                nxl0 = ldx(XLv, ns0);
                nxl1 = ldx(XLv, ns1);
            }
            float ex0 = bflo(e0), ey0 = bfhi(e0);
            float ex1 = bflo(e1), ey1 = bfhi(e1);
            float t, part0, part1;
            float m0x = xl0.x + xr.x + ex0 * we0.x + ey0 * we1.x;
            float m0y = xl0.y + xr.y + ex0 * we0.y + ey0 * we1.y;
            float m0z = xl0.z + xr.z + ex0 * we0.z + ey0 * we1.z;
            float m0w = xl0.w + xr.w + ex0 * we0.w + ey0 * we1.w;
            m0x = fmaxf(m0x, 0.f) + 0.2f * fminf(m0x, 0.f);
            m0y = fmaxf(m0y, 0.f) + 0.2f * fminf(m0y, 0.f);
            m0z = fmaxf(m0z, 0.f) + 0.2f * fminf(m0z, 0.f);
            m0w = fmaxf(m0w, 0.f) + 0.2f * fminf(m0w, 0.f);
            part0 = m0x * av.x + m0y * av.y + m0z * av.z + m0w * av.w;
            float m1x = xl1.x + xr.x + ex1 * we0.x + ey1 * we1.x;
            float m1y = xl1.y + xr.y + ex1 * we0.y + ey1 * we1.y;
            float m1z = xl1.z + xr.z + ex1 * we0.z + ey1 * we1.z;
            float m1w = xl1.w + xr.w + ex1 * we0.w + ey1 * we1.w;
            m1x = fmaxf(m1x, 0.f) + 0.2f * fminf(m1x, 0.f);
            m1y = fmaxf(m1y, 0.f) + 0.2f * fminf(m1y, 0.f);
            m1z = fmaxf(m1z, 0.f) + 0.2f * fminf(m1z, 0.f);
            m1w = fmaxf(m1w, 0.f) + 0.2f * fminf(m1w, 0.f);
            part1 = m1x * av.x + m1y * av.y + m1z * av.z + m1w * av.w;
            t = __shfl_xor(part0, 1); part0 += t;
            t = __shfl_xor(part0, 2); part0 += t;
            t = __shfl_xor(part1, 1); part1 += t;
            t = __shfl_xor(part1, 2); part1 += t;

            bool two = (j + 1 < cnt);
            float pm = two ? fmaxf(part0, part1) : part0;
            float mx = fmaxf(m_run, pm);
            float sc = __expf(m_run - mx);
            float p0 = __expf(part0 - mx);
            float p1 = two ? __expf(part1 - mx) : 0.f;
            l_run = l_run * sc + p0 + p1;
            fa.x = fa.x * sc + p0 * xl0.x + p1 * xl1.x;
            fa.y = fa.y * sc + p0 * xl0.y + p1 * xl1.y;
            fa.z = fa.z * sc + p0 * xl0.z + p1 * xl1.z;
            fa.w = fa.w * sc + p0 * xl0.w + p1 * xl1.w;
            m_run = mx;
            if (!more) break;
            s0 = ns0; s1 = ns1; e0 = ne0; e1 = ne1; xl0 = nxl0; xl1 = nxl1;
        }
    }

    if (!active) return;
    float inv = 1.f / fmaxf(l_run, 1e-16f);
    float4 bias4 = *(const float4*)(gbias + c0);
    float4 v;
    v.x = fa.x * inv + bias4.x;
    v.y = fa.y * inv + bias4.y;
    v.z = fa.z * inv + bias4.z;
    v.w = fa.w * inv + bias4.w;
    if constexpr (FUSE) {
        float4 lv = *(const float4*)(lin + (size_t)n * HID + c0);
        v.x += lv.x; v.y += lv.y; v.z += lv.z; v.w += lv.w;
        v.x = (v.x > 0.f) ? v.x : (__expf(v.x) - 1.f);
        v.y = (v.y > 0.f) ? v.y : (__expf(v.y) - 1.f);
        v.z = (v.z > 0.f) ? v.z : (__expf(v.z) - 1.f);
        v.w = (v.w > 0.f) ? v.w : (__expf(v.w) - 1.f);
        if (hf) *(float4*)(hf + (size_t)n * HID + c0) = v;
        ushort4 hh, ll;
        hh.x = f2bf(v.x); hh.y = f2bf(v.y); hh.z = f2bf(v.z); hh.w = f2bf(v.w);
        ll.x = f2bf(v.x - bf2f(hh.x)); ll.y = f2bf(v.y - bf2f(hh.y));
        ll.z = f2bf(v.z - bf2f(hh.z)); ll.w = f2bf(v.w - bf2f(hh.w));
        *(ushort4*)(hhi + (size_t)n * HID + c0) = hh;
        *(ushort4*)(hlo + (size_t)n * HID + c0) = ll;
    } else {
        *(float4*)(hf + (size_t)n * HID + c0) = v;
    }
}

// ---------------------------------------------------------------- mean pool per graph
__global__ __launch_bounds__(128) void pool_kernel(const float* __restrict__ h,
                                                   const int* __restrict__ batch,
                                                   float* __restrict__ g, int N) {
    int gid = blockIdx.x;
    int lo = lower_bound_i(batch, N, gid);
    int hi = lower_bound_i(batch, N, gid + 1);
    int c = threadIdx.x;
    float s = 0.f;
    for (int i = lo; i < hi; i++) s += h[(size_t)i * HID + c];
    g[gid * HID + c] = s / fmaxf((float)(hi - lo), 1.0f);
}

// ---------------------------------------------------------------- readout GEMM
__global__ __launch_bounds__(256) void readout_kernel(const float* __restrict__ g,
                                                      const float* __restrict__ W,
                                                      const float* __restrict__ b,
                                                      float* __restrict__ out, int S) {
    __shared__ float gs[HID];
    int gid = blockIdx.y;
    if (threadIdx.x < HID) gs[threadIdx.x] = g[gid * HID + threadIdx.x];
    __syncthreads();
    int c = blockIdx.x * 256 + threadIdx.x;
    if (c < S) {
        float acc = b[c];
        #pragma unroll 8
        for (int k = 0; k < HID; k++) acc += gs[k] * W[(size_t)k * S + c];
        out[(size_t)gid * S + c] = acc;
    }
}

// ---------------------------------------------------------------- launcher
extern "C" void kernel_launch(void* const* d_in, const int* in_sizes, int n_in,
                              void* d_out, int out_size, void* d_ws, size_t ws_size,
                              hipStream_t stream) {
    const float* x      = (const float*)d_in[0];
    const int*   ei     = (const int*)d_in[1];
    const float* eattr  = (const float*)d_in[2];
    const int*   batch  = (const int*)d_in[3];
    const float* at1_Wl = (const float*)d_in[4];
    const float* at1_bl = (const float*)d_in[5];
    const float* at1_Wr = (const float*)d_in[6];
    const float* at1_br = (const float*)d_in[7];
    const float* at1_We = (const float*)d_in[8];
    const float* at1_att= (const float*)d_in[9];
    const float* at1_b  = (const float*)d_in[10];
    const float* l1_W   = (const float*)d_in[11];
    const float* l1_b   = (const float*)d_in[12];
    const float* atk_Wl = (const float*)d_in[13];
    const float* atk_bl = (const float*)d_in[14];
    const float* atk_Wr = (const float*)d_in[15];
    const float* atk_br = (const float*)d_in[16];
    const float* atk_We = (const float*)d_in[17];
    const float* atk_att= (const float*)d_in[18];
    const float* atk_b  = (const float*)d_in[19];
    const float* lk_W   = (const float*)d_in[20];
    const float* lk_b   = (const float*)d_in[21];
    const float* lin_W  = (const float*)d_in[22];
    const float* lin_b  = (const float*)d_in[23];
    float* out = (float*)d_out;

    const int N  = in_sizes[0] / 16;
    const int E  = in_sizes[1] / 2;
    const int ET = E + N;
    const int S  = 1000;
    const int G  = out_size / S;

    char* w = (char*)d_ws;
    auto alloc = [&](size_t bytes) -> char* {
        char* p = w; w += (bytes + 255) & ~(size_t)255; return p;
    };
    float*  XLf     = (float*)alloc((size_t)N * HID * 4);   // layer-1 only
    float*  XRf     = (float*)alloc((size_t)N * HID * 4);   // layer-1 only
    unsigned short* XLb = (unsigned short*)alloc((size_t)N * HID * 2);
    unsigned short* XRb = (unsigned short*)alloc((size_t)N * HID * 2);
    float*  Lin     = (float*)alloc((size_t)N * HID * 4);
    float*  Hf      = (float*)alloc((size_t)N * HID * 4);
    unsigned short* Hhi = (unsigned short*)alloc((size_t)N * HID * 2);
    unsigned short* Hlo = (unsigned short*)alloc((size_t)N * HID * 2);
    int*    deg     = (int*)alloc((size_t)N * 4);
    int*    row_ptr = (int*)alloc((size_t)(N + 1) * 4);
    int*    cursor  = (int*)alloc((size_t)N * 4);
    int*    csr_src = (int*)alloc((size_t)ET * 4);
    unsigned int* csr_eap = (unsigned int*)alloc((size_t)ET * 4);
    float*  meansum = (float*)alloc(8);
    int*    bsum    = (int*)alloc(256);
    int*    boff    = (int*)alloc(256);
    unsigned short* WlTh = (unsigned short*)alloc((size_t)9 * 16384 * 2);
    unsigned short* WlTl = (unsigned short*)alloc((size_t)9 * 16384 * 2);
    unsigned short* WrTh = (unsigned short*)alloc((size_t)9 * 16384 * 2);
    unsigned short* WrTl = (unsigned short*)alloc((size_t)9 * 16384 * 2);
    unsigned short* WkTh = (unsigned short*)alloc((size_t)9 * 16384 * 2);
    unsigned short* WkTl = (unsigned short*)alloc((size_t)9 * 16384 * 2);
    float*  gpool   = (float*)alloc((size_t)G * HID * 4);
    (void)ws_size; (void)n_in;

    hipMemsetAsync(deg, 0, (size_t)N * 4, stream);
    hipMemsetAsync(meansum, 0, 8, stream);

    const int wtot = 9 * 16384;
    wprep_kernel<<<(wtot + 255) / 256, 256, 0, stream>>>(atk_Wl, WlTh, WlTl, wtot);
    wprep_kernel<<<(wtot + 255) / 256, 256, 0, stream>>>(atk_Wr, WrTh, WrTl, wtot);
    wprep_kernel<<<(wtot + 255) / 256, 256, 0, stream>>>(lk_W,   WkTh, WkTl, wtot);

    mean_kernel<<<256, 256, 0, stream>>>(eattr, meansum, E);
    deg_kernel<<<(ET + 255) / 256, 256, 0, stream>>>(ei, deg, E, ET);
    const int NB = (N + 1023) / 1024;
    scanA_kernel<<<NB, 256, 0, stream>>>(deg, bsum, N);
    scanB_kernel<<<1, 64, 0, stream>>>(bsum, boff, row_ptr, NB, N);
    scanC_kernel<<<NB, 256, 0, stream>>>(deg, boff, row_ptr, cursor, N);
    fill_kernel<<<(ET + 255) / 256, 256, 0, stream>>>(ei, eattr, meansum, cursor, csr_src, csr_eap, E, ET);

    const int gx16 = (N + 31) / 32;
    const int ge   = (N + 7) / 8;
    const int gx3  = (N + 127) / 128;

    transform16_kernel<<<dim3(gx16, 1, 2), 256, 0, stream>>>(x, at1_Wl, at1_bl, XLf, at1_Wr, at1_br, XRf, N);
    edge_kernel<0><<<ge, 256, 0, stream>>>(XLf, XRf, row_ptr, csr_src, csr_eap, at1_att, at1_We, at1_b,
                                           nullptr, Hf, nullptr, nullptr, N);
    combine16_kernel<<<gx16, 256, 0, stream>>>(x, l1_W, l1_b, Hf, Hhi, Hlo, N);

    for (int i = 0; i < 9; i++) {
        const unsigned short* wlh = WlTh + (size_t)i * 16384;
        const unsigned short* wll = WlTl + (size_t)i * 16384;
        const unsigned short* wrh = WrTh + (size_t)i * 16384;
        const unsigned short* wrl = WrTl + (size_t)i * 16384;
        const unsigned short* wkh = WkTh + (size_t)i * 16384;
        const unsigned short* wkl = WkTl + (size_t)i * 16384;
        const float* bl = atk_bl + (size_t)i * HID;
        const float* br = atk_br + (size_t)i * HID;
        const float* bk = lk_b   + (size_t)i * HID;
        const float* Wep = atk_We + (size_t)i * 2 * HID;
        const float* at = atk_att + (size_t)i * HID;
        const float* ab = atk_b  + (size_t)i * HID;

        gemm3_kernel<<<dim3(gx3, 3), 256, 0, stream>>>(Hhi, Hlo,
                                                       wlh, wll, bl, XLb,
                                                       wrh, wrl, br, XRb,
                                                       wkh, wkl, bk, Lin, N);
        edge_kernel<1><<<ge, 256, 0, stream>>>(XLb, XRb, row_ptr, csr_src, csr_eap, at, Wep, ab,
                                               Lin, (i == 8) ? Hf : nullptr, Hhi, Hlo, N);
    }

    pool_kernel<<<G, 128, 0, stream>>>(Hf, batch, gpool, N);
    readout_kernel<<<dim3((S + 255) / 256, G), 256, 0, stream>>>(gpool, lin_W, lin_b, out, S);
}

// Round 7
// 847.155 us; speedup vs baseline: 2.2343x; 1.2869x over previous
//
#include <hip/hip_runtime.h>
#include <hip/hip_bf16.h>
#include <cstdint>

#define HID 128

typedef __attribute__((ext_vector_type(8))) short bf16x8;
typedef __attribute__((ext_vector_type(4))) float f32x4;

__device__ __forceinline__ unsigned short f2bf(float x) {
    __hip_bfloat16 h = __float2bfloat16(x);
    return __builtin_bit_cast(unsigned short, h);
}
__device__ __forceinline__ float bf2f(unsigned short u) {
    return __bfloat162float(__builtin_bit_cast(__hip_bfloat16, u));
}
__device__ __forceinline__ float bflo(unsigned u) {
    return __builtin_bit_cast(float, u << 16);
}
__device__ __forceinline__ float bfhi(unsigned u) {
    return __builtin_bit_cast(float, u & 0xffff0000u);
}
__device__ __forceinline__ float4 ld4bf(const unsigned short* p) {
    ushort4 u = *(const ushort4*)p;
    return make_float4(bf2f(u.x), bf2f(u.y), bf2f(u.z), bf2f(u.w));
}
__device__ __forceinline__ int lower_bound_i(const int* a, int n, int v) {
    int lo = 0, hi = n;
    while (lo < hi) { int m = (lo + hi) >> 1; if (a[m] < v) lo = m + 1; else hi = m; }
    return lo;
}

// ---------------------------------------------------------------- mean of edge_attr
__global__ __launch_bounds__(256) void mean_kernel(const float* __restrict__ eattr,
                                                   float* __restrict__ meansum, int E) {
    float sx = 0.f, sy = 0.f;
    for (int i = blockIdx.x * 256 + threadIdx.x; i < E; i += gridDim.x * 256) {
        float2 v = *(const float2*)(eattr + 2 * (size_t)i);
        sx += v.x; sy += v.y;
    }
    for (int d = 1; d < 64; d <<= 1) { sx += __shfl_xor(sx, d); sy += __shfl_xor(sy, d); }
    if ((threadIdx.x & 63) == 0) { atomicAdd(&meansum[0], sx); atomicAdd(&meansum[1], sy); }
}

// ---------------------------------------------------------------- CSR build
__global__ __launch_bounds__(256) void deg_kernel(const int* __restrict__ ei,
                                                  int* __restrict__ deg, int E, int ET) {
    int e = blockIdx.x * 256 + threadIdx.x;
    if (e >= ET) return;
    int dst = (e < E) ? ei[E + e] : (e - E);
    atomicAdd(&deg[dst], 1);
}

__global__ __launch_bounds__(256) void scanA_kernel(const int* __restrict__ deg,
                                                    int* __restrict__ bsum, int N) {
    __shared__ int ws[4];
    int t = threadIdx.x;
    int base = blockIdx.x * 1024 + t * 4;
    int s = 0;
    #pragma unroll
    for (int j = 0; j < 4; j++) { int idx = base + j; if (idx < N) s += deg[idx]; }
    for (int d = 1; d < 64; d <<= 1) s += __shfl_xor(s, d);
    if ((t & 63) == 0) ws[t >> 6] = s;
    __syncthreads();
    if (t == 0) bsum[blockIdx.x] = ws[0] + ws[1] + ws[2] + ws[3];
}

__global__ __launch_bounds__(64) void scanB_kernel(const int* __restrict__ bsum,
                                                   int* __restrict__ boff,
                                                   int* __restrict__ row_ptr, int NB, int N) {
    int t = threadIdx.x;
    int v = (t < NB) ? bsum[t] : 0;
    int inc = v;
    #pragma unroll
    for (int d = 1; d < 64; d <<= 1) { int u = __shfl_up(inc, d); if (t >= d) inc += u; }
    if (t < NB) boff[t] = inc - v;
    if (t == 63) row_ptr[N] = inc;
}

__global__ __launch_bounds__(256) void scanC_kernel(const int* __restrict__ deg,
                                                    const int* __restrict__ boff,
                                                    int* __restrict__ row_ptr,
                                                    int* __restrict__ cursor, int N) {
    __shared__ int wsum[4];
    int t = threadIdx.x;
    int lane = t & 63, wid = t >> 6;
    int base = blockIdx.x * 1024 + t * 4;
    int v[4]; int s = 0;
    #pragma unroll
    for (int j = 0; j < 4; j++) { int idx = base + j; v[j] = (idx < N) ? deg[idx] : 0; s += v[j]; }
    int inc = s;
    #pragma unroll
    for (int d = 1; d < 64; d <<= 1) { int u = __shfl_up(inc, d); if (lane >= d) inc += u; }
    if (lane == 63) wsum[wid] = inc;
    __syncthreads();
    int woff = 0;
    for (int ww = 0; ww < wid; ww++) woff += wsum[ww];
    int excl = boff[blockIdx.x] + woff + inc - s;
    #pragma unroll
    for (int j = 0; j < 4; j++) {
        int idx = base + j;
        if (idx < N) { row_ptr[idx] = excl; cursor[idx] = excl; }
        excl += v[j];
    }
}

__global__ __launch_bounds__(256) void fill_kernel(const int* __restrict__ ei,
                                                   const float* __restrict__ eattr,
                                                   const float* __restrict__ meansum,
                                                   int* __restrict__ cursor,
                                                   int* __restrict__ csr_src,
                                                   unsigned int* __restrict__ csr_eap,
                                                   int E, int ET) {
    int e = blockIdx.x * 256 + threadIdx.x;
    if (e >= ET) return;
    int src, dst; float2 ea;
    if (e < E) {
        src = ei[e]; dst = ei[E + e];
        ea = *(const float2*)(eattr + 2 * (size_t)e);
    } else {
        src = dst = e - E;
        float inv = 1.0f / (float)E;
        ea.x = meansum[0] * inv; ea.y = meansum[1] * inv;
    }
    unsigned pea = (unsigned)f2bf(ea.x) | ((unsigned)f2bf(ea.y) << 16);
    int pos = atomicAdd(&cursor[dst], 1);
    csr_src[pos] = src;
    csr_eap[pos] = pea;
}

// ---------------------------------------------------------------- weight prep: transpose + bf16 hi/lo split
__global__ __launch_bounds__(256) void wprep_kernel(const float* __restrict__ src,
                                                    unsigned short* __restrict__ hi,
                                                    unsigned short* __restrict__ lo, int total) {
    int idx = blockIdx.x * 256 + threadIdx.x;
    if (idx >= total) return;
    int layer = idx >> 14;
    int rem = idx & 16383;
    int n = rem >> 7, k = rem & 127;
    float w = src[(layer << 14) | (k << 7) | n];
    unsigned short h = f2bf(w);
    hi[idx] = h;
    lo[idx] = f2bf(w - bf2f(h));
}

// ---------------------------------------------------------------- fused 3-GEMM: A bf16 (single), W hi/lo in LDS,
// swapped operands -> packed ushort4 stores. All 3 outputs bf16.
#define LROW 136   // LDS row stride in shorts (128 + 8 pad = 272B -> spreads banks)
__global__ __launch_bounds__(256) void gemm3_kernel(
    const unsigned short* __restrict__ Hb,
    const unsigned short* __restrict__ W0h, const unsigned short* __restrict__ W0l,
    const float* __restrict__ b0, unsigned short* __restrict__ o0,
    const unsigned short* __restrict__ W1h, const unsigned short* __restrict__ W1l,
    const float* __restrict__ b1, unsigned short* __restrict__ o1,
    const unsigned short* __restrict__ W2h, const unsigned short* __restrict__ W2l,
    const float* __restrict__ b2, unsigned short* __restrict__ o2, int N) {
    __shared__ unsigned short lds_h[128 * LROW];
    __shared__ unsigned short lds_l[128 * LROW];

    int tid = threadIdx.x;
    int wid = tid >> 6, lane = tid & 63;
    int row0 = blockIdx.x * 128 + wid * 32;
    int lr = lane & 15;           // node-in-frag (B/D) and W-row-in-frag (A)
    int cgrp = lane >> 4;         // channel group in D
    int kb = cgrp * 8;            // k offset within 32-k frag

    // A (H) fragments: 2 m-frags x 4 k-frags, bf16 single
    bf16x8 ha[2][4];
    bool rowsok = (row0 < N);
    #pragma unroll
    for (int mf = 0; mf < 2; mf++) {
        int node = row0 + mf * 16 + lr;
        int nodec = (node < N) ? node : (N - 1);
        if (!rowsok) nodec = 0;
        const unsigned short* pa = Hb + (size_t)nodec * HID + kb;
        #pragma unroll
        for (int kf = 0; kf < 4; kf++) ha[mf][kf] = *(const bf16x8*)(pa + kf * 32);
    }

    const unsigned short* Whs[3] = {W0h, W1h, W2h};
    const unsigned short* Wls[3] = {W0l, W1l, W2l};
    const float* Bs[3] = {b0, b1, b2};
    unsigned short* Os[3] = {o0, o1, o2};

    for (int w = 0; w < 3; w++) {
        __syncthreads();   // previous compute done before restage
        // stage 32KB hi + 32KB lo: 2048 x 16B chunks each, 8 per thread
        const unsigned short* sh = Whs[w];
        const unsigned short* sl = Wls[w];
        #pragma unroll
        for (int j = 0; j < 8; j++) {
            int c = tid + 256 * j;
            int r = c >> 4, col = (c & 15) * 8;
            *(bf16x8*)&lds_h[r * LROW + col] = *(const bf16x8*)(sh + r * HID + col);
            *(bf16x8*)&lds_l[r * LROW + col] = *(const bf16x8*)(sl + r * HID + col);
        }
        __syncthreads();
        if (!rowsok) continue;

        const float* bias = Bs[w];
        unsigned short* outp = Os[w];
        #pragma unroll 2
        for (int nf = 0; nf < 8; nf++) {
            int wrow = nf * 16 + lr;
            const unsigned short* ph = &lds_h[wrow * LROW + kb];
            const unsigned short* pl = &lds_l[wrow * LROW + kb];
            bf16x8 wf[4], wfl[4];
            #pragma unroll
            for (int kf = 0; kf < 4; kf++) {
                wf[kf]  = *(const bf16x8*)(ph + kf * 32);
                wfl[kf] = *(const bf16x8*)(pl + kf * 32);
            }
            // 4 independent chains: Wh*A (x2 mfrag) + Wl*A (x2 mfrag)
            f32x4 hh0 = {0.f,0.f,0.f,0.f}, lh0 = {0.f,0.f,0.f,0.f};
            f32x4 hh1 = {0.f,0.f,0.f,0.f}, lh1 = {0.f,0.f,0.f,0.f};
            #pragma unroll
            for (int kf = 0; kf < 4; kf++) {
                hh0 = __builtin_amdgcn_mfma_f32_16x16x32_bf16(wf[kf],  ha[0][kf], hh0, 0, 0, 0);
                lh0 = __builtin_amdgcn_mfma_f32_16x16x32_bf16(wfl[kf], ha[0][kf], lh0, 0, 0, 0);
                hh1 = __builtin_amdgcn_mfma_f32_16x16x32_bf16(wf[kf],  ha[1][kf], hh1, 0, 0, 0);
                lh1 = __builtin_amdgcn_mfma_f32_16x16x32_bf16(wfl[kf], ha[1][kf], lh1, 0, 0, 0);
            }
            f32x4 acc0 = hh0 + lh0;
            f32x4 acc1 = hh1 + lh1;
            int chb = nf * 16 + cgrp * 4;
            float4 bias4 = *(const float4*)(bias + chb);
            int node0 = row0 + lr;
            int node1 = row0 + 16 + lr;
            ushort4 u0, u1;
            u0.x = f2bf(acc0[0] + bias4.x); u0.y = f2bf(acc0[1] + bias4.y);
            u0.z = f2bf(acc0[2] + bias4.z); u0.w = f2bf(acc0[3] + bias4.w);
            u1.x = f2bf(acc1[0] + bias4.x); u1.y = f2bf(acc1[1] + bias4.y);
            u1.z = f2bf(acc1[2] + bias4.z); u1.w = f2bf(acc1[3] + bias4.w);
            if (node0 < N) *(ushort4*)(outp + (size_t)node0 * HID + chb) = u0;
            if (node1 < N) *(ushort4*)(outp + (size_t)node1 * HID + chb) = u1;
        }
    }
}

// ---------------------------------------------------------------- layer-1 f32 transform (K=16)
__global__ __launch_bounds__(256) void transform16_kernel(
    const float* __restrict__ Hin,
    const float* __restrict__ W0, const float* __restrict__ b0, float* __restrict__ o0,
    const float* __restrict__ W1, const float* __restrict__ b1, float* __restrict__ o1,
    int N) {
    constexpr int K = 16;
    __shared__ float Ws[K][HID];
    __shared__ float Hs[32][K + 4];

    const float* W; const float* bias; float* outp;
    if (blockIdx.z == 0) { W = W0; bias = b0; outp = o0; }
    else                 { W = W1; bias = b1; outp = o1; }

    int row0 = blockIdx.x * 32;
    int tid = threadIdx.x;
    int tx = tid & 15, ty = tid >> 4;

    for (int i = tid; i < 32 * (K / 4); i += 256) {
        int r = i / (K / 4), kq = i % (K / 4);
        int row = row0 + r;
        float4 v = make_float4(0.f, 0.f, 0.f, 0.f);
        if (row < N) v = *(const float4*)(Hin + (size_t)row * K + kq * 4);
        *(float4*)&Hs[r][kq * 4] = v;
    }
    for (int i = tid; i < K * 32; i += 256) {
        int k = i >> 5, cq = i & 31;
        *(float4*)&Ws[k][cq * 4] = *(const float4*)(W + (size_t)k * HID + cq * 4);
    }
    __syncthreads();

    float acc[2][8];
    #pragma unroll
    for (int i = 0; i < 2; i++)
        #pragma unroll
        for (int j = 0; j < 8; j++) acc[i][j] = 0.f;

    int r0 = ty * 2, r1 = ty * 2 + 1;
    #pragma unroll
    for (int k = 0; k < K; k++) {
        float a0 = Hs[r0][k];
        float a1 = Hs[r1][k];
        float4 w0 = *(float4*)&Ws[k][tx * 4];
        float4 w1 = *(float4*)&Ws[k][64 + tx * 4];
        acc[0][0] += a0 * w0.x; acc[0][1] += a0 * w0.y; acc[0][2] += a0 * w0.z; acc[0][3] += a0 * w0.w;
        acc[0][4] += a0 * w1.x; acc[0][5] += a0 * w1.y; acc[0][6] += a0 * w1.z; acc[0][7] += a0 * w1.w;
        acc[1][0] += a1 * w0.x; acc[1][1] += a1 * w0.y; acc[1][2] += a1 * w0.z; acc[1][3] += a1 * w0.w;
        acc[1][4] += a1 * w1.x; acc[1][5] += a1 * w1.y; acc[1][6] += a1 * w1.z; acc[1][7] += a1 * w1.w;
    }

    float4 bb0 = *(const float4*)(bias + tx * 4);
    float4 bb1 = *(const float4*)(bias + 64 + tx * 4);
    #pragma unroll
    for (int i = 0; i < 2; i++) {
        int row = row0 + ty * 2 + i;
        if (row < N) {
            float4 v0 = make_float4(acc[i][0] + bb0.x, acc[i][1] + bb0.y, acc[i][2] + bb0.z, acc[i][3] + bb0.w);
            float4 v1 = make_float4(acc[i][4] + bb1.x, acc[i][5] + bb1.y, acc[i][6] + bb1.z, acc[i][7] + bb1.w);
            *(float4*)(outp + (size_t)row * HID + tx * 4) = v0;
            *(float4*)(outp + (size_t)row * HID + 64 + tx * 4) = v1;
        }
    }
}

// ---------------------------------------------------------------- layer-1 combine: Hb = bf16(elu(att + x@W + b))
__global__ __launch_bounds__(256) void combine16_kernel(
    const float* __restrict__ Hin,
    const float* __restrict__ W, const float* __restrict__ bias,
    const float* __restrict__ Att, unsigned short* __restrict__ Hb,
    int N) {
    constexpr int K = 16;
    __shared__ float Ws[K][HID];
    __shared__ float Hs[32][K + 4];

    int row0 = blockIdx.x * 32;
    int tid = threadIdx.x;
    int tx = tid & 15, ty = tid >> 4;

    for (int i = tid; i < 32 * (K / 4); i += 256) {
        int r = i / (K / 4), kq = i % (K / 4);
        int row = row0 + r;
        float4 v = make_float4(0.f, 0.f, 0.f, 0.f);
        if (row < N) v = *(const float4*)(Hin + (size_t)row * K + kq * 4);
        *(float4*)&Hs[r][kq * 4] = v;
    }
    for (int i = tid; i < K * 32; i += 256) {
        int k = i >> 5, cq = i & 31;
        *(float4*)&Ws[k][cq * 4] = *(const float4*)(W + (size_t)k * HID + cq * 4);
    }
    __syncthreads();

    float acc[2][8];
    #pragma unroll
    for (int i = 0; i < 2; i++)
        #pragma unroll
        for (int j = 0; j < 8; j++) acc[i][j] = 0.f;

    int r0 = ty * 2, r1 = ty * 2 + 1;
    #pragma unroll
    for (int k = 0; k < K; k++) {
        float a0 = Hs[r0][k];
        float a1 = Hs[r1][k];
        float4 w0 = *(float4*)&Ws[k][tx * 4];
        float4 w1 = *(float4*)&Ws[k][64 + tx * 4];
        acc[0][0] += a0 * w0.x; acc[0][1] += a0 * w0.y; acc[0][2] += a0 * w0.z; acc[0][3] += a0 * w0.w;
        acc[0][4] += a0 * w1.x; acc[0][5] += a0 * w1.y; acc[0][6] += a0 * w1.z; acc[0][7] += a0 * w1.w;
        acc[1][0] += a1 * w0.x; acc[1][1] += a1 * w0.y; acc[1][2] += a1 * w0.z; acc[1][3] += a1 * w0.w;
        acc[1][4] += a1 * w1.x; acc[1][5] += a1 * w1.y; acc[1][6] += a1 * w1.z; acc[1][7] += a1 * w1.w;
    }

    float4 bb0 = *(const float4*)(bias + tx * 4);
    float4 bb1 = *(const float4*)(bias + 64 + tx * 4);
    #pragma unroll
    for (int i = 0; i < 2; i++) {
        int row = row0 + ty * 2 + i;
        if (row < N) {
            const float* p0 = Att + (size_t)row * HID + tx * 4;
            float4 g0 = *(const float4*)p0;
            float4 g1 = *(const float4*)(p0 + 64);
            float v[8];
            v[0] = g0.x + acc[i][0] + bb0.x; v[1] = g0.y + acc[i][1] + bb0.y;
            v[2] = g0.z + acc[i][2] + bb0.z; v[3] = g0.w + acc[i][3] + bb0.w;
            v[4] = g1.x + acc[i][4] + bb1.x; v[5] = g1.y + acc[i][5] + bb1.y;
            v[6] = g1.z + acc[i][6] + bb1.z; v[7] = g1.w + acc[i][7] + bb1.w;
            #pragma unroll
            for (int j = 0; j < 8; j++) v[j] = (v[j] > 0.f) ? v[j] : (__expf(v[j]) - 1.f);
            ushort4 h0, h1;
            h0.x = f2bf(v[0]); h0.y = f2bf(v[1]); h0.z = f2bf(v[2]); h0.w = f2bf(v[3]);
            h1.x = f2bf(v[4]); h1.y = f2bf(v[5]); h1.z = f2bf(v[6]); h1.w = f2bf(v[7]);
            *(ushort4*)(Hb + (size_t)row * HID + tx * 4) = h0;
            *(ushort4*)(Hb + (size_t)row * HID + 64 + tx * 4) = h1;
        }
    }
}

// ---------------------------------------------------------------- edge/attention: 2 nodes per wave (32 lanes each).
// FUSE=0: f32 XL/XR (layer 1), writes f32 att -> hf. FUSE=1: bf16 XL/XR + bf16 lin; writes bf16 hb (+f32 hf if non-null).
template <int FUSE>
__global__ __launch_bounds__(256) void edge_kernel(
    const void* __restrict__ XLv, const void* __restrict__ XRv,
    const int* __restrict__ row_ptr, const int* __restrict__ csr_src,
    const unsigned int* __restrict__ csr_eap,
    const float* __restrict__ att,
    const float* __restrict__ We,
    const float* __restrict__ gbias,
    const unsigned short* __restrict__ lin,
    float* __restrict__ hf, unsigned short* __restrict__ hb,
    int N) {
    int wv = (blockIdx.x * 256 + threadIdx.x) >> 6;
    int lane = threadIdx.x & 63;
    int half = lane >> 5;
    int l = lane & 31;
    int n = wv * 2 + half;
    bool active = (n < N);
    int nn = active ? n : 0;

    int c0 = l * 4;
    float4 av  = *(const float4*)(att + c0);
    float4 we0 = *(const float4*)(We + c0);
    float4 we1 = *(const float4*)(We + HID + c0);

    auto ldx = [&](const void* p, int idx) -> float4 {
        if constexpr (FUSE) return ld4bf((const unsigned short*)p + (size_t)idx * HID + c0);
        else                return *(const float4*)((const float*)p + (size_t)idx * HID + c0);
    };
    float4 xr = ldx(XRv, nn);

    int eb = 0, eend = 0;
    if (active) { eb = row_ptr[n]; eend = row_ptr[n + 1]; }

    float m_run = -INFINITY, l_run = 0.f;
    float4 fa = make_float4(0.f, 0.f, 0.f, 0.f);

    for (int base = eb; base < eend; base += 32) {
        int cnt = min(32, eend - base);
        int myi = base + l;
        int msrc = 0; unsigned mea = 0;
        if (myi < eend) { msrc = csr_src[myi]; mea = csr_eap[myi]; }

        int s0 = __shfl(msrc, 0, 32);
        int s1 = __shfl(msrc, 1, 32);
        unsigned e0 = __shfl(mea, 0, 32);
        unsigned e1 = __shfl(mea, 1, 32);
        float4 xl0 = ldx(XLv, s0);
        float4 xl1 = ldx(XLv, s1);

        for (int j = 0; ; j += 2) {
            bool more = (j + 2 < cnt);
            int ns0 = 0, ns1 = 0; unsigned ne0 = 0, ne1 = 0;
            float4 nxl0, nxl1;
            if (more) {
                ns0 = __shfl(msrc, j + 2, 32);
                ns1 = __shfl(msrc, j + 3, 32);
                ne0 = __shfl(mea, j + 2, 32);
                ne1 = __shfl(mea, j + 3, 32);
                nxl0 = ldx(XLv, ns0);
                nxl1 = ldx(XLv, ns1);
            }
            float ex0 = bflo(e0), ey0 = bfhi(e0);
            float ex1 = bflo(e1), ey1 = bfhi(e1);
            float t, part0, part1;
            float m0x = xl0.x + xr.x + ex0 * we0.x + ey0 * we1.x;
            float m0y = xl0.y + xr.y + ex0 * we0.y + ey0 * we1.y;
            float m0z = xl0.z + xr.z + ex0 * we0.z + ey0 * we1.z;
            float m0w = xl0.w + xr.w + ex0 * we0.w + ey0 * we1.w;
            m0x = fmaxf(m0x, 0.f) + 0.2f * fminf(m0x, 0.f);
            m0y = fmaxf(m0y, 0.f) + 0.2f * fminf(m0y, 0.f);
            m0z = fmaxf(m0z, 0.f) + 0.2f * fminf(m0z, 0.f);
            m0w = fmaxf(m0w, 0.f) + 0.2f * fminf(m0w, 0.f);
            part0 = m0x * av.x + m0y * av.y + m0z * av.z + m0w * av.w;
            float m1x = xl1.x + xr.x + ex1 * we0.x + ey1 * we1.x;
            float m1y = xl1.y + xr.y + ex1 * we0.y + ey1 * we1.y;
            float m1z = xl1.z + xr.z + ex1 * we0.z + ey1 * we1.z;
            float m1w = xl1.w + xr.w + ex1 * we0.w + ey1 * we1.w;
            m1x = fmaxf(m1x, 0.f) + 0.2f * fminf(m1x, 0.f);
            m1y = fmaxf(m1y, 0.f) + 0.2f * fminf(m1y, 0.f);
            m1z = fmaxf(m1z, 0.f) + 0.2f * fminf(m1z, 0.f);
            m1w = fmaxf(m1w, 0.f) + 0.2f * fminf(m1w, 0.f);
            part1 = m1x * av.x + m1y * av.y + m1z * av.z + m1w * av.w;
            t = __shfl_xor(part0, 1); part0 += t;
            t = __shfl_xor(part0, 2); part0 += t;
            t = __shfl_xor(part1, 1); part1 += t;
            t = __shfl_xor(part1, 2); part1 += t;

            bool two = (j + 1 < cnt);
            float pm = two ? fmaxf(part0, part1) : part0;
            float mx = fmaxf(m_run, pm);
            float sc = __expf(m_run - mx);
            float p0 = __expf(part0 - mx);
            float p1 = two ? __expf(part1 - mx) : 0.f;
            l_run = l_run * sc + p0 + p1;
            fa.x = fa.x * sc + p0 * xl0.x + p1 * xl1.x;
            fa.y = fa.y * sc + p0 * xl0.y + p1 * xl1.y;
            fa.z = fa.z * sc + p0 * xl0.z + p1 * xl1.z;
            fa.w = fa.w * sc + p0 * xl0.w + p1 * xl1.w;
            m_run = mx;
            if (!more) break;
            s0 = ns0; s1 = ns1; e0 = ne0; e1 = ne1; xl0 = nxl0; xl1 = nxl1;
        }
    }

    if (!active) return;
    float inv = 1.f / fmaxf(l_run, 1e-16f);
    float4 bias4 = *(const float4*)(gbias + c0);
    float4 v;
    v.x = fa.x * inv + bias4.x;
    v.y = fa.y * inv + bias4.y;
    v.z = fa.z * inv + bias4.z;
    v.w = fa.w * inv + bias4.w;
    if constexpr (FUSE) {
        float4 lv = ld4bf(lin + (size_t)n * HID + c0);
        v.x += lv.x; v.y += lv.y; v.z += lv.z; v.w += lv.w;
        v.x = (v.x > 0.f) ? v.x : (__expf(v.x) - 1.f);
        v.y = (v.y > 0.f) ? v.y : (__expf(v.y) - 1.f);
        v.z = (v.z > 0.f) ? v.z : (__expf(v.z) - 1.f);
        v.w = (v.w > 0.f) ? v.w : (__expf(v.w) - 1.f);
        if (hf) *(float4*)(hf + (size_t)n * HID + c0) = v;
        ushort4 hh;
        hh.x = f2bf(v.x); hh.y = f2bf(v.y); hh.z = f2bf(v.z); hh.w = f2bf(v.w);
        *(ushort4*)(hb + (size_t)n * HID + c0) = hh;
    } else {
        *(float4*)(hf + (size_t)n * HID + c0) = v;
    }
}

// ---------------------------------------------------------------- mean pool per graph
__global__ __launch_bounds__(128) void pool_kernel(const float* __restrict__ h,
                                                   const int* __restrict__ batch,
                                                   float* __restrict__ g, int N) {
    int gid = blockIdx.x;
    int lo = lower_bound_i(batch, N, gid);
    int hi = lower_bound_i(batch, N, gid + 1);
    int c = threadIdx.x;
    float s = 0.f;
    for (int i = lo; i < hi; i++) s += h[(size_t)i * HID + c];
    g[gid * HID + c] = s / fmaxf((float)(hi - lo), 1.0f);
}

// ---------------------------------------------------------------- readout GEMM
__global__ __launch_bounds__(256) void readout_kernel(const float* __restrict__ g,
                                                      const float* __restrict__ W,
                                                      const float* __restrict__ b,
                                                      float* __restrict__ out, int S) {
    __shared__ float gs[HID];
    int gid = blockIdx.y;
    if (threadIdx.x < HID) gs[threadIdx.x] = g[gid * HID + threadIdx.x];
    __syncthreads();
    int c = blockIdx.x * 256 + threadIdx.x;
    if (c < S) {
        float acc = b[c];
        #pragma unroll 8
        for (int k = 0; k < HID; k++) acc += gs[k] * W[(size_t)k * S + c];
        out[(size_t)gid * S + c] = acc;
    }
}

// ---------------------------------------------------------------- launcher
extern "C" void kernel_launch(void* const* d_in, const int* in_sizes, int n_in,
                              void* d_out, int out_size, void* d_ws, size_t ws_size,
                              hipStream_t stream) {
    const float* x      = (const float*)d_in[0];
    const int*   ei     = (const int*)d_in[1];
    const float* eattr  = (const float*)d_in[2];
    const int*   batch  = (const int*)d_in[3];
    const float* at1_Wl = (const float*)d_in[4];
    const float* at1_bl = (const float*)d_in[5];
    const float* at1_Wr = (const float*)d_in[6];
    const float* at1_br = (const float*)d_in[7];
    const float* at1_We = (const float*)d_in[8];
    const float* at1_att= (const float*)d_in[9];
    const float* at1_b  = (const float*)d_in[10];
    const float* l1_W   = (const float*)d_in[11];
    const float* l1_b   = (const float*)d_in[12];
    const float* atk_Wl = (const float*)d_in[13];
    const float* atk_bl = (const float*)d_in[14];
    const float* atk_Wr = (const float*)d_in[15];
    const float* atk_br = (const float*)d_in[16];
    const float* atk_We = (const float*)d_in[17];
    const float* atk_att= (const float*)d_in[18];
    const float* atk_b  = (const float*)d_in[19];
    const float* lk_W   = (const float*)d_in[20];
    const float* lk_b   = (const float*)d_in[21];
    const float* lin_W  = (const float*)d_in[22];
    const float* lin_b  = (const float*)d_in[23];
    float* out = (float*)d_out;

    const int N  = in_sizes[0] / 16;
    const int E  = in_sizes[1] / 2;
    const int ET = E + N;
    const int S  = 1000;
    const int G  = out_size / S;

    char* w = (char*)d_ws;
    auto alloc = [&](size_t bytes) -> char* {
        char* p = w; w += (bytes + 255) & ~(size_t)255; return p;
    };
    float*  XLf     = (float*)alloc((size_t)N * HID * 4);   // layer-1 only
    float*  XRf     = (float*)alloc((size_t)N * HID * 4);   // layer-1 only
    unsigned short* XLb = (unsigned short*)alloc((size_t)N * HID * 2);
    unsigned short* XRb = (unsigned short*)alloc((size_t)N * HID * 2);
    unsigned short* Linb = (unsigned short*)alloc((size_t)N * HID * 2);
    float*  Hf      = (float*)alloc((size_t)N * HID * 4);
    unsigned short* Hb = (unsigned short*)alloc((size_t)N * HID * 2);
    int*    deg     = (int*)alloc((size_t)N * 4);
    int*    row_ptr = (int*)alloc((size_t)(N + 1) * 4);
    int*    cursor  = (int*)alloc((size_t)N * 4);
    int*    csr_src = (int*)alloc((size_t)ET * 4);
    unsigned int* csr_eap = (unsigned int*)alloc((size_t)ET * 4);
    float*  meansum = (float*)alloc(8);
    int*    bsum    = (int*)alloc(256);
    int*    boff    = (int*)alloc(256);
    unsigned short* WlTh = (unsigned short*)alloc((size_t)9 * 16384 * 2);
    unsigned short* WlTl = (unsigned short*)alloc((size_t)9 * 16384 * 2);
    unsigned short* WrTh = (unsigned short*)alloc((size_t)9 * 16384 * 2);
    unsigned short* WrTl = (unsigned short*)alloc((size_t)9 * 16384 * 2);
    unsigned short* WkTh = (unsigned short*)alloc((size_t)9 * 16384 * 2);
    unsigned short* WkTl = (unsigned short*)alloc((size_t)9 * 16384 * 2);
    float*  gpool   = (float*)alloc((size_t)G * HID * 4);
    (void)ws_size; (void)n_in;

    hipMemsetAsync(deg, 0, (size_t)N * 4, stream);
    hipMemsetAsync(meansum, 0, 8, stream);

    const int wtot = 9 * 16384;
    wprep_kernel<<<(wtot + 255) / 256, 256, 0, stream>>>(atk_Wl, WlTh, WlTl, wtot);
    wprep_kernel<<<(wtot + 255) / 256, 256, 0, stream>>>(atk_Wr, WrTh, WrTl, wtot);
    wprep_kernel<<<(wtot + 255) / 256, 256, 0, stream>>>(lk_W,   WkTh, WkTl, wtot);

    mean_kernel<<<256, 256, 0, stream>>>(eattr, meansum, E);
    deg_kernel<<<(ET + 255) / 256, 256, 0, stream>>>(ei, deg, E, ET);
    const int NB = (N + 1023) / 1024;
    scanA_kernel<<<NB, 256, 0, stream>>>(deg, bsum, N);
    scanB_kernel<<<1, 64, 0, stream>>>(bsum, boff, row_ptr, NB, N);
    scanC_kernel<<<NB, 256, 0, stream>>>(deg, boff, row_ptr, cursor, N);
    fill_kernel<<<(ET + 255) / 256, 256, 0, stream>>>(ei, eattr, meansum, cursor, csr_src, csr_eap, E, ET);

    const int gx16 = (N + 31) / 32;
    const int ge   = (N + 7) / 8;
    const int gx3  = (N + 127) / 128;

    transform16_kernel<<<dim3(gx16, 1, 2), 256, 0, stream>>>(x, at1_Wl, at1_bl, XLf, at1_Wr, at1_br, XRf, N);
    edge_kernel<0><<<ge, 256, 0, stream>>>(XLf, XRf, row_ptr, csr_src, csr_eap, at1_att, at1_We, at1_b,
                                           nullptr, Hf, nullptr, N);
    combine16_kernel<<<gx16, 256, 0, stream>>>(x, l1_W, l1_b, Hf, Hb, N);

    for (int i = 0; i < 9; i++) {
        const unsigned short* wlh = WlTh + (size_t)i * 16384;
        const unsigned short* wll = WlTl + (size_t)i * 16384;
        const unsigned short* wrh = WrTh + (size_t)i * 16384;
        const unsigned short* wrl = WrTl + (size_t)i * 16384;
        const unsigned short* wkh = WkTh + (size_t)i * 16384;
        const unsigned short* wkl = WkTl + (size_t)i * 16384;
        const float* bl = atk_bl + (size_t)i * HID;
        const float* br = atk_br + (size_t)i * HID;
        const float* bk = lk_b   + (size_t)i * HID;
        const float* Wep = atk_We + (size_t)i * 2 * HID;
        const float* at = atk_att + (size_t)i * HID;
        const float* ab = atk_b  + (size_t)i * HID;

        gemm3_kernel<<<gx3, 256, 0, stream>>>(Hb,
                                              wlh, wll, bl, XLb,
                                              wrh, wrl, br, XRb,
                                              wkh, wkl, bk, Linb, N);
        edge_kernel<1><<<ge, 256, 0, stream>>>(XLb, XRb, row_ptr, csr_src, csr_eap, at, Wep, ab,
                                               Linb, (i == 8) ? Hf : nullptr, Hb, N);
    }

    pool_kernel<<<G, 128, 0, stream>>>(Hf, batch, gpool, N);
    readout_kernel<<<dim3((S + 255) / 256, G), 256, 0, stream>>>(gpool, lin_W, lin_b, out, S);
}

// Round 8
// 791.697 us; speedup vs baseline: 2.3908x; 1.0700x over previous
//
#include <hip/hip_runtime.h>
#include <hip/hip_bf16.h>
#include <cstdint>

#define HID 128

typedef __attribute__((ext_vector_type(8))) short bf16x8;
typedef __attribute__((ext_vector_type(4))) float f32x4;

__device__ __forceinline__ unsigned short f2bf(float x) {
    __hip_bfloat16 h = __float2bfloat16(x);
    return __builtin_bit_cast(unsigned short, h);
}
__device__ __forceinline__ float bf2f(unsigned short u) {
    return __bfloat162float(__builtin_bit_cast(__hip_bfloat16, u));
}
__device__ __forceinline__ float bflo(unsigned u) {
    return __builtin_bit_cast(float, u << 16);
}
__device__ __forceinline__ float bfhi(unsigned u) {
    return __builtin_bit_cast(float, u & 0xffff0000u);
}
__device__ __forceinline__ float4 ld4bf(const unsigned short* p) {
    ushort4 u = *(const ushort4*)p;
    return make_float4(bf2f(u.x), bf2f(u.y), bf2f(u.z), bf2f(u.w));
}
__device__ __forceinline__ int lower_bound_i(const int* a, int n, int v) {
    int lo = 0, hi = n;
    while (lo < hi) { int m = (lo + hi) >> 1; if (a[m] < v) lo = m + 1; else hi = m; }
    return lo;
}

// ---------------------------------------------------------------- mean of edge_attr
__global__ __launch_bounds__(256) void mean_kernel(const float* __restrict__ eattr,
                                                   float* __restrict__ meansum, int E) {
    float sx = 0.f, sy = 0.f;
    for (int i = blockIdx.x * 256 + threadIdx.x; i < E; i += gridDim.x * 256) {
        float2 v = *(const float2*)(eattr + 2 * (size_t)i);
        sx += v.x; sy += v.y;
    }
    for (int d = 1; d < 64; d <<= 1) { sx += __shfl_xor(sx, d); sy += __shfl_xor(sy, d); }
    if ((threadIdx.x & 63) == 0) { atomicAdd(&meansum[0], sx); atomicAdd(&meansum[1], sy); }
}

// ---------------------------------------------------------------- CSR build
__global__ __launch_bounds__(256) void deg_kernel(const int* __restrict__ ei,
                                                  int* __restrict__ deg, int E, int ET) {
    int e = blockIdx.x * 256 + threadIdx.x;
    if (e >= ET) return;
    int dst = (e < E) ? ei[E + e] : (e - E);
    atomicAdd(&deg[dst], 1);
}

__global__ __launch_bounds__(256) void scanA_kernel(const int* __restrict__ deg,
                                                    int* __restrict__ bsum, int N) {
    __shared__ int ws[4];
    int t = threadIdx.x;
    int base = blockIdx.x * 1024 + t * 4;
    int s = 0;
    #pragma unroll
    for (int j = 0; j < 4; j++) { int idx = base + j; if (idx < N) s += deg[idx]; }
    for (int d = 1; d < 64; d <<= 1) s += __shfl_xor(s, d);
    if ((t & 63) == 0) ws[t >> 6] = s;
    __syncthreads();
    if (t == 0) bsum[blockIdx.x] = ws[0] + ws[1] + ws[2] + ws[3];
}

__global__ __launch_bounds__(64) void scanB_kernel(const int* __restrict__ bsum,
                                                   int* __restrict__ boff,
                                                   int* __restrict__ row_ptr, int NB, int N) {
    int t = threadIdx.x;
    int v = (t < NB) ? bsum[t] : 0;
    int inc = v;
    #pragma unroll
    for (int d = 1; d < 64; d <<= 1) { int u = __shfl_up(inc, d); if (t >= d) inc += u; }
    if (t < NB) boff[t] = inc - v;
    if (t == 63) row_ptr[N] = inc;
}

__global__ __launch_bounds__(256) void scanC_kernel(const int* __restrict__ deg,
                                                    const int* __restrict__ boff,
                                                    int* __restrict__ row_ptr,
                                                    int* __restrict__ cursor, int N) {
    __shared__ int wsum[4];
    int t = threadIdx.x;
    int lane = t & 63, wid = t >> 6;
    int base = blockIdx.x * 1024 + t * 4;
    int v[4]; int s = 0;
    #pragma unroll
    for (int j = 0; j < 4; j++) { int idx = base + j; v[j] = (idx < N) ? deg[idx] : 0; s += v[j]; }
    int inc = s;
    #pragma unroll
    for (int d = 1; d < 64; d <<= 1) { int u = __shfl_up(inc, d); if (lane >= d) inc += u; }
    if (lane == 63) wsum[wid] = inc;
    __syncthreads();
    int woff = 0;
    for (int ww = 0; ww < wid; ww++) woff += wsum[ww];
    int excl = boff[blockIdx.x] + woff + inc - s;
    #pragma unroll
    for (int j = 0; j < 4; j++) {
        int idx = base + j;
        if (idx < N) { row_ptr[idx] = excl; cursor[idx] = excl; }
        excl += v[j];
    }
}

__global__ __launch_bounds__(256) void fill_kernel(const int* __restrict__ ei,
                                                   const float* __restrict__ eattr,
                                                   const float* __restrict__ meansum,
                                                   int* __restrict__ cursor,
                                                   int* __restrict__ csr_src,
                                                   unsigned int* __restrict__ csr_eap,
                                                   int E, int ET) {
    int e = blockIdx.x * 256 + threadIdx.x;
    if (e >= ET) return;
    int src, dst; float2 ea;
    if (e < E) {
        src = ei[e]; dst = ei[E + e];
        ea = *(const float2*)(eattr + 2 * (size_t)e);
    } else {
        src = dst = e - E;
        float inv = 1.0f / (float)E;
        ea.x = meansum[0] * inv; ea.y = meansum[1] * inv;
    }
    unsigned pea = (unsigned)f2bf(ea.x) | ((unsigned)f2bf(ea.y) << 16);
    int pos = atomicAdd(&cursor[dst], 1);
    csr_src[pos] = src;
    csr_eap[pos] = pea;
}

// ---------------------------------------------------------------- weight prep: transpose to [n][k] bf16 (hi only)
__global__ __launch_bounds__(256) void wprep_kernel(const float* __restrict__ src,
                                                    unsigned short* __restrict__ hi, int total) {
    int idx = blockIdx.x * 256 + threadIdx.x;
    if (idx >= total) return;
    int layer = idx >> 14;
    int rem = idx & 16383;
    int n = rem >> 7, k = rem & 127;
    hi[idx] = f2bf(src[(layer << 14) | (k << 7) | n]);
}

// ---------------------------------------------------------------- 3-GEMM: A bf16, W bf16 staged in LDS,
// blockIdx.y selects matrix; swapped operands -> packed ushort4 stores.
#define LROW 136   // LDS row stride in shorts (272B: rows shift 4 banks -> 2-way aliasing only)
__global__ __launch_bounds__(256) void gemm3_kernel(
    const unsigned short* __restrict__ Hb,
    const unsigned short* __restrict__ W0h, const float* __restrict__ b0, unsigned short* __restrict__ o0,
    const unsigned short* __restrict__ W1h, const float* __restrict__ b1, unsigned short* __restrict__ o1,
    const unsigned short* __restrict__ W2h, const float* __restrict__ b2, unsigned short* __restrict__ o2,
    int N) {
    __shared__ unsigned short lds_h[128 * LROW];
    int y = blockIdx.y;
    const unsigned short* wsrc = (y == 0) ? W0h : (y == 1) ? W1h : W2h;
    const float* bias = (y == 0) ? b0 : (y == 1) ? b1 : b2;
    unsigned short* outp = (y == 0) ? o0 : (y == 1) ? o1 : o2;

    int tid = threadIdx.x;
    int wid = tid >> 6, lane = tid & 63;
    int row0 = blockIdx.x * 128 + wid * 32;
    int lr = lane & 15;
    int cgrp = lane >> 4;
    int kb = cgrp * 8;

    // stage W: 32KB = 2048 x 16B chunks, 8 per thread
    #pragma unroll
    for (int j = 0; j < 8; j++) {
        int c = tid + 256 * j;
        int r = c >> 4, col = (c & 15) * 8;
        *(bf16x8*)&lds_h[r * LROW + col] = *(const bf16x8*)(wsrc + r * HID + col);
    }

    // A fragments (issued alongside staging; independent)
    bf16x8 ha[2][4];
    bool rowsok = (row0 < N);
    #pragma unroll
    for (int mf = 0; mf < 2; mf++) {
        int node = row0 + mf * 16 + lr;
        int nodec = (node < N) ? node : (N - 1);
        if (!rowsok) nodec = 0;
        const unsigned short* pa = Hb + (size_t)nodec * HID + kb;
        #pragma unroll
        for (int kf = 0; kf < 4; kf++) ha[mf][kf] = *(const bf16x8*)(pa + kf * 32);
    }

    __syncthreads();
    if (!rowsok) return;

    #pragma unroll 2
    for (int nf = 0; nf < 8; nf++) {
        int wrow = nf * 16 + lr;
        const unsigned short* ph = &lds_h[wrow * LROW + kb];
        bf16x8 wf[4];
        #pragma unroll
        for (int kf = 0; kf < 4; kf++) wf[kf] = *(const bf16x8*)(ph + kf * 32);
        f32x4 acc0 = {0.f, 0.f, 0.f, 0.f};
        f32x4 acc1 = {0.f, 0.f, 0.f, 0.f};
        #pragma unroll
        for (int kf = 0; kf < 4; kf++) {
            acc0 = __builtin_amdgcn_mfma_f32_16x16x32_bf16(wf[kf], ha[0][kf], acc0, 0, 0, 0);
            acc1 = __builtin_amdgcn_mfma_f32_16x16x32_bf16(wf[kf], ha[1][kf], acc1, 0, 0, 0);
        }
        int chb = nf * 16 + cgrp * 4;
        float4 bias4 = *(const float4*)(bias + chb);
        int node0 = row0 + lr;
        int node1 = row0 + 16 + lr;
        ushort4 u0, u1;
        u0.x = f2bf(acc0[0] + bias4.x); u0.y = f2bf(acc0[1] + bias4.y);
        u0.z = f2bf(acc0[2] + bias4.z); u0.w = f2bf(acc0[3] + bias4.w);
        u1.x = f2bf(acc1[0] + bias4.x); u1.y = f2bf(acc1[1] + bias4.y);
        u1.z = f2bf(acc1[2] + bias4.z); u1.w = f2bf(acc1[3] + bias4.w);
        if (node0 < N) *(ushort4*)(outp + (size_t)node0 * HID + chb) = u0;
        if (node1 < N) *(ushort4*)(outp + (size_t)node1 * HID + chb) = u1;
    }
}

// ---------------------------------------------------------------- layer-1 f32 transform (K=16)
__global__ __launch_bounds__(256) void transform16_kernel(
    const float* __restrict__ Hin,
    const float* __restrict__ W0, const float* __restrict__ b0, float* __restrict__ o0,
    const float* __restrict__ W1, const float* __restrict__ b1, float* __restrict__ o1,
    int N) {
    constexpr int K = 16;
    __shared__ float Ws[K][HID];
    __shared__ float Hs[32][K + 4];

    const float* W; const float* bias; float* outp;
    if (blockIdx.z == 0) { W = W0; bias = b0; outp = o0; }
    else                 { W = W1; bias = b1; outp = o1; }

    int row0 = blockIdx.x * 32;
    int tid = threadIdx.x;
    int tx = tid & 15, ty = tid >> 4;

    for (int i = tid; i < 32 * (K / 4); i += 256) {
        int r = i / (K / 4), kq = i % (K / 4);
        int row = row0 + r;
        float4 v = make_float4(0.f, 0.f, 0.f, 0.f);
        if (row < N) v = *(const float4*)(Hin + (size_t)row * K + kq * 4);
        *(float4*)&Hs[r][kq * 4] = v;
    }
    for (int i = tid; i < K * 32; i += 256) {
        int k = i >> 5, cq = i & 31;
        *(float4*)&Ws[k][cq * 4] = *(const float4*)(W + (size_t)k * HID + cq * 4);
    }
    __syncthreads();

    float acc[2][8];
    #pragma unroll
    for (int i = 0; i < 2; i++)
        #pragma unroll
        for (int j = 0; j < 8; j++) acc[i][j] = 0.f;

    int r0 = ty * 2, r1 = ty * 2 + 1;
    #pragma unroll
    for (int k = 0; k < K; k++) {
        float a0 = Hs[r0][k];
        float a1 = Hs[r1][k];
        float4 w0 = *(float4*)&Ws[k][tx * 4];
        float4 w1 = *(float4*)&Ws[k][64 + tx * 4];
        acc[0][0] += a0 * w0.x; acc[0][1] += a0 * w0.y; acc[0][2] += a0 * w0.z; acc[0][3] += a0 * w0.w;
        acc[0][4] += a0 * w1.x; acc[0][5] += a0 * w1.y; acc[0][6] += a0 * w1.z; acc[0][7] += a0 * w1.w;
        acc[1][0] += a1 * w0.x; acc[1][1] += a1 * w0.y; acc[1][2] += a1 * w0.z; acc[1][3] += a1 * w0.w;
        acc[1][4] += a1 * w1.x; acc[1][5] += a1 * w1.y; acc[1][6] += a1 * w1.z; acc[1][7] += a1 * w1.w;
    }

    float4 bb0 = *(const float4*)(bias + tx * 4);
    float4 bb1 = *(const float4*)(bias + 64 + tx * 4);
    #pragma unroll
    for (int i = 0; i < 2; i++) {
        int row = row0 + ty * 2 + i;
        if (row < N) {
            float4 v0 = make_float4(acc[i][0] + bb0.x, acc[i][1] + bb0.y, acc[i][2] + bb0.z, acc[i][3] + bb0.w);
            float4 v1 = make_float4(acc[i][4] + bb1.x, acc[i][5] + bb1.y, acc[i][6] + bb1.z, acc[i][7] + bb1.w);
            *(float4*)(outp + (size_t)row * HID + tx * 4) = v0;
            *(float4*)(outp + (size_t)row * HID + 64 + tx * 4) = v1;
        }
    }
}

// ---------------------------------------------------------------- layer-1 combine: Hb = bf16(elu(att + x@W + b))
__global__ __launch_bounds__(256) void combine16_kernel(
    const float* __restrict__ Hin,
    const float* __restrict__ W, const float* __restrict__ bias,
    const float* __restrict__ Att, unsigned short* __restrict__ Hb,
    int N) {
    constexpr int K = 16;
    __shared__ float Ws[K][HID];
    __shared__ float Hs[32][K + 4];

    int row0 = blockIdx.x * 32;
    int tid = threadIdx.x;
    int tx = tid & 15, ty = tid >> 4;

    for (int i = tid; i < 32 * (K / 4); i += 256) {
        int r = i / (K / 4), kq = i % (K / 4);
        int row = row0 + r;
        float4 v = make_float4(0.f, 0.f, 0.f, 0.f);
        if (row < N) v = *(const float4*)(Hin + (size_t)row * K + kq * 4);
        *(float4*)&Hs[r][kq * 4] = v;
    }
    for (int i = tid; i < K * 32; i += 256) {
        int k = i >> 5, cq = i & 31;
        *(float4*)&Ws[k][cq * 4] = *(const float4*)(W + (size_t)k * HID + cq * 4);
    }
    __syncthreads();

    float acc[2][8];
    #pragma unroll
    for (int i = 0; i < 2; i++)
        #pragma unroll
        for (int j = 0; j < 8; j++) acc[i][j] = 0.f;

    int r0 = ty * 2, r1 = ty * 2 + 1;
    #pragma unroll
    for (int k = 0; k < K; k++) {
        float a0 = Hs[r0][k];
        float a1 = Hs[r1][k];
        float4 w0 = *(float4*)&Ws[k][tx * 4];
        float4 w1 = *(float4*)&Ws[k][64 + tx * 4];
        acc[0][0] += a0 * w0.x; acc[0][1] += a0 * w0.y; acc[0][2] += a0 * w0.z; acc[0][3] += a0 * w0.w;
        acc[0][4] += a0 * w1.x; acc[0][5] += a0 * w1.y; acc[0][6] += a0 * w1.z; acc[0][7] += a0 * w1.w;
        acc[1][0] += a1 * w0.x; acc[1][1] += a1 * w0.y; acc[1][2] += a1 * w0.z; acc[1][3] += a1 * w0.w;
        acc[1][4] += a1 * w1.x; acc[1][5] += a1 * w1.y; acc[1][6] += a1 * w1.z; acc[1][7] += a1 * w1.w;
    }

    float4 bb0 = *(const float4*)(bias + tx * 4);
    float4 bb1 = *(const float4*)(bias + 64 + tx * 4);
    #pragma unroll
    for (int i = 0; i < 2; i++) {
        int row = row0 + ty * 2 + i;
        if (row < N) {
            const float* p0 = Att + (size_t)row * HID + tx * 4;
            float4 g0 = *(const float4*)p0;
            float4 g1 = *(const float4*)(p0 + 64);
            float v[8];
            v[0] = g0.x + acc[i][0] + bb0.x; v[1] = g0.y + acc[i][1] + bb0.y;
            v[2] = g0.z + acc[i][2] + bb0.z; v[3] = g0.w + acc[i][3] + bb0.w;
            v[4] = g1.x + acc[i][4] + bb1.x; v[5] = g1.y + acc[i][5] + bb1.y;
            v[6] = g1.z + acc[i][6] + bb1.z; v[7] = g1.w + acc[i][7] + bb1.w;
            #pragma unroll
            for (int j = 0; j < 8; j++) v[j] = (v[j] > 0.f) ? v[j] : (__expf(v[j]) - 1.f);
            ushort4 h0, h1;
            h0.x = f2bf(v[0]); h0.y = f2bf(v[1]); h0.z = f2bf(v[2]); h0.w = f2bf(v[3]);
            h1.x = f2bf(v[4]); h1.y = f2bf(v[5]); h1.z = f2bf(v[6]); h1.w = f2bf(v[7]);
            *(ushort4*)(Hb + (size_t)row * HID + tx * 4) = h0;
            *(ushort4*)(Hb + (size_t)row * HID + 64 + tx * 4) = h1;
        }
    }
}

// ---------------------------------------------------------------- edge/attention: ONE node per wave; the two
// 32-lane halves process disjoint halves of the edge list (serial chain = deg/4), then flash-merge states.
template <int FUSE>
__global__ __launch_bounds__(256) void edge_kernel(
    const void* __restrict__ XLv, const void* __restrict__ XRv,
    const int* __restrict__ row_ptr, const int* __restrict__ csr_src,
    const unsigned int* __restrict__ csr_eap,
    const float* __restrict__ att,
    const float* __restrict__ We,
    const float* __restrict__ gbias,
    const unsigned short* __restrict__ lin,
    float* __restrict__ hf, unsigned short* __restrict__ hb,
    int N) {
    int n = (blockIdx.x * 256 + threadIdx.x) >> 6;   // one node per wave
    int lane = threadIdx.x & 63;
    int half = lane >> 5;
    int l = lane & 31;
    bool active = (n < N);
    int nn = active ? n : 0;

    int c0 = l * 4;
    float4 av  = *(const float4*)(att + c0);
    float4 we0 = *(const float4*)(We + c0);
    float4 we1 = *(const float4*)(We + HID + c0);

    auto ldx = [&](const void* p, int idx) -> float4 {
        if constexpr (FUSE) return ld4bf((const unsigned short*)p + (size_t)idx * HID + c0);
        else                return *(const float4*)((const float*)p + (size_t)idx * HID + c0);
    };
    float4 xr = ldx(XRv, nn);

    int eb = 0, eend = 0;
    if (active) { eb = row_ptr[n]; eend = row_ptr[n + 1]; }
    int mid = (eb + eend + 1) >> 1;      // half A: [eb,mid)  (non-empty when deg>=1)
    int sb = half ? mid : eb;
    int se = half ? eend : mid;

    float m_run = -INFINITY, l_run = 0.f;
    float4 fa = make_float4(0.f, 0.f, 0.f, 0.f);

    for (int base = sb; base < se; base += 32) {
        int cnt = min(32, se - base);
        int myi = base + l;
        int msrc = 0; unsigned mea = 0;
        if (myi < se) { msrc = csr_src[myi]; mea = csr_eap[myi]; }

        int s0 = __shfl(msrc, 0, 32);
        int s1 = __shfl(msrc, 1, 32);
        unsigned e0 = __shfl(mea, 0, 32);
        unsigned e1 = __shfl(mea, 1, 32);
        float4 xl0 = ldx(XLv, s0);
        float4 xl1 = ldx(XLv, s1);

        for (int j = 0; ; j += 2) {
            bool more = (j + 2 < cnt);
            int ns0 = 0, ns1 = 0; unsigned ne0 = 0, ne1 = 0;
            float4 nxl0, nxl1;
            if (more) {
                ns0 = __shfl(msrc, j + 2, 32);
                ns1 = __shfl(msrc, j + 3, 32);
                ne0 = __shfl(mea, j + 2, 32);
                ne1 = __shfl(mea, j + 3, 32);
                nxl0 = ldx(XLv, ns0);
                nxl1 = ldx(XLv, ns1);
            }
            float ex0 = bflo(e0), ey0 = bfhi(e0);
            float ex1 = bflo(e1), ey1 = bfhi(e1);
            float t, part0, part1;
            float m0x = xl0.x + xr.x + ex0 * we0.x + ey0 * we1.x;
            float m0y = xl0.y + xr.y + ex0 * we0.y + ey0 * we1.y;
            float m0z = xl0.z + xr.z + ex0 * we0.z + ey0 * we1.z;
            float m0w = xl0.w + xr.w + ex0 * we0.w + ey0 * we1.w;
            m0x = fmaxf(m0x, 0.f) + 0.2f * fminf(m0x, 0.f);
            m0y = fmaxf(m0y, 0.f) + 0.2f * fminf(m0y, 0.f);
            m0z = fmaxf(m0z, 0.f) + 0.2f * fminf(m0z, 0.f);
            m0w = fmaxf(m0w, 0.f) + 0.2f * fminf(m0w, 0.f);
            part0 = m0x * av.x + m0y * av.y + m0z * av.z + m0w * av.w;
            float m1x = xl1.x + xr.x + ex1 * we0.x + ey1 * we1.x;
            float m1y = xl1.y + xr.y + ex1 * we0.y + ey1 * we1.y;
            float m1z = xl1.z + xr.z + ex1 * we0.z + ey1 * we1.z;
            float m1w = xl1.w + xr.w + ex1 * we0.w + ey1 * we1.w;
            m1x = fmaxf(m1x, 0.f) + 0.2f * fminf(m1x, 0.f);
            m1y = fmaxf(m1y, 0.f) + 0.2f * fminf(m1y, 0.f);
            m1z = fmaxf(m1z, 0.f) + 0.2f * fminf(m1z, 0.f);
            m1w = fmaxf(m1w, 0.f) + 0.2f * fminf(m1w, 0.f);
            part1 = m1x * av.x + m1y * av.y + m1z * av.z + m1w * av.w;
            t = __shfl_xor(part0, 1); part0 += t;
            t = __shfl_xor(part0, 2); part0 += t;
            t = __shfl_xor(part1, 1); part1 += t;
            t = __shfl_xor(part1, 2); part1 += t;

            bool two = (j + 1 < cnt);
            float pm = two ? fmaxf(part0, part1) : part0;
            float mx = fmaxf(m_run, pm);
            float sc = __expf(m_run - mx);   // first iter: exp(-inf)=0
            float p0 = __expf(part0 - mx);
            float p1 = two ? __expf(part1 - mx) : 0.f;
            l_run = l_run * sc + p0 + p1;
            fa.x = fa.x * sc + p0 * xl0.x + p1 * xl1.x;
            fa.y = fa.y * sc + p0 * xl0.y + p1 * xl1.y;
            fa.z = fa.z * sc + p0 * xl0.z + p1 * xl1.z;
            fa.w = fa.w * sc + p0 * xl0.w + p1 * xl1.w;
            m_run = mx;
            if (!more) break;
            s0 = ns0; s1 = ns1; e0 = ne0; e1 = ne1; xl0 = nxl0; xl1 = nxl1;
        }
    }

    // flash-merge the two halves (all lanes participate in the shuffles)
    float m_o = __shfl_xor(m_run, 32);
    float l_o = __shfl_xor(l_run, 32);
    float4 fo;
    fo.x = __shfl_xor(fa.x, 32);
    fo.y = __shfl_xor(fa.y, 32);
    fo.z = __shfl_xor(fa.z, 32);
    fo.w = __shfl_xor(fa.w, 32);
    float m_c = fmaxf(m_run, m_o);
    float wa = __expf(m_run - m_c);   // empty half: exp(-inf - finite) = 0
    float wb = __expf(m_o - m_c);
    float l_c = l_run * wa + l_o * wb;
    fa.x = fa.x * wa + fo.x * wb;
    fa.y = fa.y * wa + fo.y * wb;
    fa.z = fa.z * wa + fo.z * wb;
    fa.w = fa.w * wa + fo.w * wb;

    if (!active || half) return;      // lanes 0-31 write
    float inv = 1.f / fmaxf(l_c, 1e-16f);
    float4 bias4 = *(const float4*)(gbias + c0);
    float4 v;
    v.x = fa.x * inv + bias4.x;
    v.y = fa.y * inv + bias4.y;
    v.z = fa.z * inv + bias4.z;
    v.w = fa.w * inv + bias4.w;
    if constexpr (FUSE) {
        float4 lv = ld4bf(lin + (size_t)n * HID + c0);
        v.x += lv.x; v.y += lv.y; v.z += lv.z; v.w += lv.w;
        v.x = (v.x > 0.f) ? v.x : (__expf(v.x) - 1.f);
        v.y = (v.y > 0.f) ? v.y : (__expf(v.y) - 1.f);
        v.z = (v.z > 0.f) ? v.z : (__expf(v.z) - 1.f);
        v.w = (v.w > 0.f) ? v.w : (__expf(v.w) - 1.f);
        if (hf) *(float4*)(hf + (size_t)n * HID + c0) = v;
        ushort4 hh;
        hh.x = f2bf(v.x); hh.y = f2bf(v.y); hh.z = f2bf(v.z); hh.w = f2bf(v.w);
        *(ushort4*)(hb + (size_t)n * HID + c0) = hh;
    } else {
        *(float4*)(hf + (size_t)n * HID + c0) = v;
    }
}

// ---------------------------------------------------------------- mean pool per graph
__global__ __launch_bounds__(128) void pool_kernel(const float* __restrict__ h,
                                                   const int* __restrict__ batch,
                                                   float* __restrict__ g, int N) {
    int gid = blockIdx.x;
    int lo = lower_bound_i(batch, N, gid);
    int hi = lower_bound_i(batch, N, gid + 1);
    int c = threadIdx.x;
    float s = 0.f;
    for (int i = lo; i < hi; i++) s += h[(size_t)i * HID + c];
    g[gid * HID + c] = s / fmaxf((float)(hi - lo), 1.0f);
}

// ---------------------------------------------------------------- readout GEMM
__global__ __launch_bounds__(256) void readout_kernel(const float* __restrict__ g,
                                                      const float* __restrict__ W,
                                                      const float* __restrict__ b,
                                                      float* __restrict__ out, int S) {
    __shared__ float gs[HID];
    int gid = blockIdx.y;
    if (threadIdx.x < HID) gs[threadIdx.x] = g[gid * HID + threadIdx.x];
    __syncthreads();
    int c = blockIdx.x * 256 + threadIdx.x;
    if (c < S) {
        float acc = b[c];
        #pragma unroll 8
        for (int k = 0; k < HID; k++) acc += gs[k] * W[(size_t)k * S + c];
        out[(size_t)gid * S + c] = acc;
    }
}

// ---------------------------------------------------------------- launcher
extern "C" void kernel_launch(void* const* d_in, const int* in_sizes, int n_in,
                              void* d_out, int out_size, void* d_ws, size_t ws_size,
                              hipStream_t stream) {
    const float* x      = (const float*)d_in[0];
    const int*   ei     = (const int*)d_in[1];
    const float* eattr  = (const float*)d_in[2];
    const int*   batch  = (const int*)d_in[3];
    const float* at1_Wl = (const float*)d_in[4];
    const float* at1_bl = (const float*)d_in[5];
    const float* at1_Wr = (const float*)d_in[6];
    const float* at1_br = (const float*)d_in[7];
    const float* at1_We = (const float*)d_in[8];
    const float* at1_att= (const float*)d_in[9];
    const float* at1_b  = (const float*)d_in[10];
    const float* l1_W   = (const float*)d_in[11];
    const float* l1_b   = (const float*)d_in[12];
    const float* atk_Wl = (const float*)d_in[13];
    const float* atk_bl = (const float*)d_in[14];
    const float* atk_Wr = (const float*)d_in[15];
    const float* atk_br = (const float*)d_in[16];
    const float* atk_We = (const float*)d_in[17];
    const float* atk_att= (const float*)d_in[18];
    const float* atk_b  = (const float*)d_in[19];
    const float* lk_W   = (const float*)d_in[20];
    const float* lk_b   = (const float*)d_in[21];
    const float* lin_W  = (const float*)d_in[22];
    const float* lin_b  = (const float*)d_in[23];
    float* out = (float*)d_out;

    const int N  = in_sizes[0] / 16;
    const int E  = in_sizes[1] / 2;
    const int ET = E + N;
    const int S  = 1000;
    const int G  = out_size / S;

    char* w = (char*)d_ws;
    auto alloc = [&](size_t bytes) -> char* {
        char* p = w; w += (bytes + 255) & ~(size_t)255; return p;
    };
    float*  XLf     = (float*)alloc((size_t)N * HID * 4);   // layer-1 only
    float*  XRf     = (float*)alloc((size_t)N * HID * 4);   // layer-1 only
    unsigned short* XLb = (unsigned short*)alloc((size_t)N * HID * 2);
    unsigned short* XRb = (unsigned short*)alloc((size_t)N * HID * 2);
    unsigned short* Linb = (unsigned short*)alloc((size_t)N * HID * 2);
    float*  Hf      = (float*)alloc((size_t)N * HID * 4);
    unsigned short* Hb = (unsigned short*)alloc((size_t)N * HID * 2);
    int*    deg     = (int*)alloc((size_t)N * 4);
    int*    row_ptr = (int*)alloc((size_t)(N + 1) * 4);
    int*    cursor  = (int*)alloc((size_t)N * 4);
    int*    csr_src = (int*)alloc((size_t)ET * 4);
    unsigned int* csr_eap = (unsigned int*)alloc((size_t)ET * 4);
    float*  meansum = (float*)alloc(8);
    int*    bsum    = (int*)alloc(256);
    int*    boff    = (int*)alloc(256);
    unsigned short* WlTh = (unsigned short*)alloc((size_t)9 * 16384 * 2);
    unsigned short* WrTh = (unsigned short*)alloc((size_t)9 * 16384 * 2);
    unsigned short* WkTh = (unsigned short*)alloc((size_t)9 * 16384 * 2);
    float*  gpool   = (float*)alloc((size_t)G * HID * 4);
    (void)ws_size; (void)n_in;

    hipMemsetAsync(deg, 0, (size_t)N * 4, stream);
    hipMemsetAsync(meansum, 0, 8, stream);

    const int wtot = 9 * 16384;
    wprep_kernel<<<(wtot + 255) / 256, 256, 0, stream>>>(atk_Wl, WlTh, wtot);
    wprep_kernel<<<(wtot + 255) / 256, 256, 0, stream>>>(atk_Wr, WrTh, wtot);
    wprep_kernel<<<(wtot + 255) / 256, 256, 0, stream>>>(lk_W,   WkTh, wtot);

    mean_kernel<<<256, 256, 0, stream>>>(eattr, meansum, E);
    deg_kernel<<<(ET + 255) / 256, 256, 0, stream>>>(ei, deg, E, ET);
    const int NB = (N + 1023) / 1024;
    scanA_kernel<<<NB, 256, 0, stream>>>(deg, bsum, N);
    scanB_kernel<<<1, 64, 0, stream>>>(bsum, boff, row_ptr, NB, N);
    scanC_kernel<<<NB, 256, 0, stream>>>(deg, boff, row_ptr, cursor, N);
    fill_kernel<<<(ET + 255) / 256, 256, 0, stream>>>(ei, eattr, meansum, cursor, csr_src, csr_eap, E, ET);

    const int gx16 = (N + 31) / 32;
    const int ge   = (N + 3) / 4;        // 1 node per wave, 4 waves per block
    const int gx3  = (N + 127) / 128;

    transform16_kernel<<<dim3(gx16, 1, 2), 256, 0, stream>>>(x, at1_Wl, at1_bl, XLf, at1_Wr, at1_br, XRf, N);
    edge_kernel<0><<<ge, 256, 0, stream>>>(XLf, XRf, row_ptr, csr_src, csr_eap, at1_att, at1_We, at1_b,
                                           nullptr, Hf, nullptr, N);
    combine16_kernel<<<gx16, 256, 0, stream>>>(x, l1_W, l1_b, Hf, Hb, N);

    for (int i = 0; i < 9; i++) {
        const unsigned short* wlh = WlTh + (size_t)i * 16384;
        const unsigned short* wrh = WrTh + (size_t)i * 16384;
        const unsigned short* wkh = WkTh + (size_t)i * 16384;
        const float* bl = atk_bl + (size_t)i * HID;
        const float* br = atk_br + (size_t)i * HID;
        const float* bk = lk_b   + (size_t)i * HID;
        const float* Wep = atk_We + (size_t)i * 2 * HID;
        const float* at = atk_att + (size_t)i * HID;
        const float* ab = atk_b  + (size_t)i * HID;

        gemm3_kernel<<<dim3(gx3, 3), 256, 0, stream>>>(Hb,
                                                       wlh, bl, XLb,
                                                       wrh, br, XRb,
                                                       wkh, bk, Linb, N);
        edge_kernel<1><<<ge, 256, 0, stream>>>(XLb, XRb, row_ptr, csr_src, csr_eap, at, Wep, ab,
                                               Linb, (i == 8) ? Hf : nullptr, Hb, N);
    }

    pool_kernel<<<G, 128, 0, stream>>>(Hf, batch, gpool, N);
    readout_kernel<<<dim3((S + 255) / 256, G), 256, 0, stream>>>(gpool, lin_W, lin_b, out, S);
}

// Round 9
// 771.306 us; speedup vs baseline: 2.4540x; 1.0264x over previous
//
#include <hip/hip_runtime.h>
#include <hip/hip_bf16.h>
#include <cstdint>

#define HID 128

typedef __attribute__((ext_vector_type(8))) short bf16x8;
typedef __attribute__((ext_vector_type(4))) float f32x4;

__device__ __forceinline__ unsigned short f2bf(float x) {
    __hip_bfloat16 h = __float2bfloat16(x);
    return __builtin_bit_cast(unsigned short, h);
}
__device__ __forceinline__ float bf2f(unsigned short u) {
    return __bfloat162float(__builtin_bit_cast(__hip_bfloat16, u));
}
__device__ __forceinline__ float bflo(unsigned u) {
    return __builtin_bit_cast(float, u << 16);
}
__device__ __forceinline__ float bfhi(unsigned u) {
    return __builtin_bit_cast(float, u & 0xffff0000u);
}
__device__ __forceinline__ float4 ld4bf(const unsigned short* p) {
    ushort4 u = *(const ushort4*)p;
    return make_float4(bf2f(u.x), bf2f(u.y), bf2f(u.z), bf2f(u.w));
}
__device__ __forceinline__ int lower_bound_i(const int* a, int n, int v) {
    int lo = 0, hi = n;
    while (lo < hi) { int m = (lo + hi) >> 1; if (a[m] < v) lo = m + 1; else hi = m; }
    return lo;
}

// ---------------------------------------------------------------- mean of edge_attr
__global__ __launch_bounds__(256) void mean_kernel(const float* __restrict__ eattr,
                                                   float* __restrict__ meansum, int E) {
    float sx = 0.f, sy = 0.f;
    for (int i = blockIdx.x * 256 + threadIdx.x; i < E; i += gridDim.x * 256) {
        float2 v = *(const float2*)(eattr + 2 * (size_t)i);
        sx += v.x; sy += v.y;
    }
    for (int d = 1; d < 64; d <<= 1) { sx += __shfl_xor(sx, d); sy += __shfl_xor(sy, d); }
    if ((threadIdx.x & 63) == 0) { atomicAdd(&meansum[0], sx); atomicAdd(&meansum[1], sy); }
}

// ---------------------------------------------------------------- CSR build
__global__ __launch_bounds__(256) void deg_kernel(const int* __restrict__ ei,
                                                  int* __restrict__ deg, int E, int ET) {
    int e = blockIdx.x * 256 + threadIdx.x;
    if (e >= ET) return;
    int dst = (e < E) ? ei[E + e] : (e - E);
    atomicAdd(&deg[dst], 1);
}

__global__ __launch_bounds__(256) void scanA_kernel(const int* __restrict__ deg,
                                                    int* __restrict__ bsum, int N) {
    __shared__ int ws[4];
    int t = threadIdx.x;
    int base = blockIdx.x * 1024 + t * 4;
    int s = 0;
    #pragma unroll
    for (int j = 0; j < 4; j++) { int idx = base + j; if (idx < N) s += deg[idx]; }
    for (int d = 1; d < 64; d <<= 1) s += __shfl_xor(s, d);
    if ((t & 63) == 0) ws[t >> 6] = s;
    __syncthreads();
    if (t == 0) bsum[blockIdx.x] = ws[0] + ws[1] + ws[2] + ws[3];
}

__global__ __launch_bounds__(64) void scanB_kernel(const int* __restrict__ bsum,
                                                   int* __restrict__ boff,
                                                   int* __restrict__ row_ptr, int NB, int N) {
    int t = threadIdx.x;
    int v = (t < NB) ? bsum[t] : 0;
    int inc = v;
    #pragma unroll
    for (int d = 1; d < 64; d <<= 1) { int u = __shfl_up(inc, d); if (t >= d) inc += u; }
    if (t < NB) boff[t] = inc - v;
    if (t == 63) row_ptr[N] = inc;
}

__global__ __launch_bounds__(256) void scanC_kernel(const int* __restrict__ deg,
                                                    const int* __restrict__ boff,
                                                    int* __restrict__ row_ptr,
                                                    int* __restrict__ cursor, int N) {
    __shared__ int wsum[4];
    int t = threadIdx.x;
    int lane = t & 63, wid = t >> 6;
    int base = blockIdx.x * 1024 + t * 4;
    int v[4]; int s = 0;
    #pragma unroll
    for (int j = 0; j < 4; j++) { int idx = base + j; v[j] = (idx < N) ? deg[idx] : 0; s += v[j]; }
    int inc = s;
    #pragma unroll
    for (int d = 1; d < 64; d <<= 1) { int u = __shfl_up(inc, d); if (lane >= d) inc += u; }
    if (lane == 63) wsum[wid] = inc;
    __syncthreads();
    int woff = 0;
    for (int ww = 0; ww < wid; ww++) woff += wsum[ww];
    int excl = boff[blockIdx.x] + woff + inc - s;
    #pragma unroll
    for (int j = 0; j < 4; j++) {
        int idx = base + j;
        if (idx < N) { row_ptr[idx] = excl; cursor[idx] = excl; }
        excl += v[j];
    }
}

__global__ __launch_bounds__(256) void fill_kernel(const int* __restrict__ ei,
                                                   const float* __restrict__ eattr,
                                                   const float* __restrict__ meansum,
                                                   int* __restrict__ cursor,
                                                   int* __restrict__ csr_src,
                                                   unsigned int* __restrict__ csr_eap,
                                                   int E, int ET) {
    int e = blockIdx.x * 256 + threadIdx.x;
    if (e >= ET) return;
    int src, dst; float2 ea;
    if (e < E) {
        src = ei[e]; dst = ei[E + e];
        ea = *(const float2*)(eattr + 2 * (size_t)e);
    } else {
        src = dst = e - E;
        float inv = 1.0f / (float)E;
        ea.x = meansum[0] * inv; ea.y = meansum[1] * inv;
    }
    unsigned pea = (unsigned)f2bf(ea.x) | ((unsigned)f2bf(ea.y) << 16);
    int pos = atomicAdd(&cursor[dst], 1);
    csr_src[pos] = src;
    csr_eap[pos] = pea;
}

// ---------------------------------------------------------------- weight prep: transpose to [n][k] bf16 (hi only)
__global__ __launch_bounds__(256) void wprep_kernel(const float* __restrict__ src,
                                                    unsigned short* __restrict__ hi, int total) {
    int idx = blockIdx.x * 256 + threadIdx.x;
    if (idx >= total) return;
    int layer = idx >> 14;
    int rem = idx & 16383;
    int n = rem >> 7, k = rem & 127;
    hi[idx] = f2bf(src[(layer << 14) | (k << 7) | n]);
}

// ---------------------------------------------------------------- 3-GEMM: A bf16, W bf16 staged in LDS,
// blockIdx.y selects matrix; swapped operands -> packed ushort4 stores.
#define LROW 136   // LDS row stride in shorts (272B: rows shift 4 banks -> 2-way aliasing only)
__global__ __launch_bounds__(256) void gemm3_kernel(
    const unsigned short* __restrict__ Hb,
    const unsigned short* __restrict__ W0h, const float* __restrict__ b0, unsigned short* __restrict__ o0,
    const unsigned short* __restrict__ W1h, const float* __restrict__ b1, unsigned short* __restrict__ o1,
    const unsigned short* __restrict__ W2h, const float* __restrict__ b2, unsigned short* __restrict__ o2,
    int N) {
    __shared__ unsigned short lds_h[128 * LROW];
    int y = blockIdx.y;
    const unsigned short* wsrc = (y == 0) ? W0h : (y == 1) ? W1h : W2h;
    const float* bias = (y == 0) ? b0 : (y == 1) ? b1 : b2;
    unsigned short* outp = (y == 0) ? o0 : (y == 1) ? o1 : o2;

    int tid = threadIdx.x;
    int wid = tid >> 6, lane = tid & 63;
    int row0 = blockIdx.x * 128 + wid * 32;
    int lr = lane & 15;
    int cgrp = lane >> 4;
    int kb = cgrp * 8;

    // stage W: 32KB = 2048 x 16B chunks, 8 per thread
    #pragma unroll
    for (int j = 0; j < 8; j++) {
        int c = tid + 256 * j;
        int r = c >> 4, col = (c & 15) * 8;
        *(bf16x8*)&lds_h[r * LROW + col] = *(const bf16x8*)(wsrc + r * HID + col);
    }

    // A fragments (issued alongside staging; independent)
    bf16x8 ha[2][4];
    bool rowsok = (row0 < N);
    #pragma unroll
    for (int mf = 0; mf < 2; mf++) {
        int node = row0 + mf * 16 + lr;
        int nodec = (node < N) ? node : (N - 1);
        if (!rowsok) nodec = 0;
        const unsigned short* pa = Hb + (size_t)nodec * HID + kb;
        #pragma unroll
        for (int kf = 0; kf < 4; kf++) ha[mf][kf] = *(const bf16x8*)(pa + kf * 32);
    }

    __syncthreads();
    if (!rowsok) return;

    #pragma unroll 2
    for (int nf = 0; nf < 8; nf++) {
        int wrow = nf * 16 + lr;
        const unsigned short* ph = &lds_h[wrow * LROW + kb];
        bf16x8 wf[4];
        #pragma unroll
        for (int kf = 0; kf < 4; kf++) wf[kf] = *(const bf16x8*)(ph + kf * 32);
        f32x4 acc0 = {0.f, 0.f, 0.f, 0.f};
        f32x4 acc1 = {0.f, 0.f, 0.f, 0.f};
        #pragma unroll
        for (int kf = 0; kf < 4; kf++) {
            acc0 = __builtin_amdgcn_mfma_f32_16x16x32_bf16(wf[kf], ha[0][kf], acc0, 0, 0, 0);
            acc1 = __builtin_amdgcn_mfma_f32_16x16x32_bf16(wf[kf], ha[1][kf], acc1, 0, 0, 0);
        }
        int chb = nf * 16 + cgrp * 4;
        float4 bias4 = *(const float4*)(bias + chb);
        int node0 = row0 + lr;
        int node1 = row0 + 16 + lr;
        ushort4 u0, u1;
        u0.x = f2bf(acc0[0] + bias4.x); u0.y = f2bf(acc0[1] + bias4.y);
        u0.z = f2bf(acc0[2] + bias4.z); u0.w = f2bf(acc0[3] + bias4.w);
        u1.x = f2bf(acc1[0] + bias4.x); u1.y = f2bf(acc1[1] + bias4.y);
        u1.z = f2bf(acc1[2] + bias4.z); u1.w = f2bf(acc1[3] + bias4.w);
        if (node0 < N) *(ushort4*)(outp + (size_t)node0 * HID + chb) = u0;
        if (node1 < N) *(ushort4*)(outp + (size_t)node1 * HID + chb) = u1;
    }
}

// ---------------------------------------------------------------- layer-1 f32 transform (K=16)
__global__ __launch_bounds__(256) void transform16_kernel(
    const float* __restrict__ Hin,
    const float* __restrict__ W0, const float* __restrict__ b0, float* __restrict__ o0,
    const float* __restrict__ W1, const float* __restrict__ b1, float* __restrict__ o1,
    int N) {
    constexpr int K = 16;
    __shared__ float Ws[K][HID];
    __shared__ float Hs[32][K + 4];

    const float* W; const float* bias; float* outp;
    if (blockIdx.z == 0) { W = W0; bias = b0; outp = o0; }
    else                 { W = W1; bias = b1; outp = o1; }

    int row0 = blockIdx.x * 32;
    int tid = threadIdx.x;
    int tx = tid & 15, ty = tid >> 4;

    for (int i = tid; i < 32 * (K / 4); i += 256) {
        int r = i / (K / 4), kq = i % (K / 4);
        int row = row0 + r;
        float4 v = make_float4(0.f, 0.f, 0.f, 0.f);
        if (row < N) v = *(const float4*)(Hin + (size_t)row * K + kq * 4);
        *(float4*)&Hs[r][kq * 4] = v;
    }
    for (int i = tid; i < K * 32; i += 256) {
        int k = i >> 5, cq = i & 31;
        *(float4*)&Ws[k][cq * 4] = *(const float4*)(W + (size_t)k * HID + cq * 4);
    }
    __syncthreads();

    float acc[2][8];
    #pragma unroll
    for (int i = 0; i < 2; i++)
        #pragma unroll
        for (int j = 0; j < 8; j++) acc[i][j] = 0.f;

    int r0 = ty * 2, r1 = ty * 2 + 1;
    #pragma unroll
    for (int k = 0; k < K; k++) {
        float a0 = Hs[r0][k];
        float a1 = Hs[r1][k];
        float4 w0 = *(float4*)&Ws[k][tx * 4];
        float4 w1 = *(float4*)&Ws[k][64 + tx * 4];
        acc[0][0] += a0 * w0.x; acc[0][1] += a0 * w0.y; acc[0][2] += a0 * w0.z; acc[0][3] += a0 * w0.w;
        acc[0][4] += a0 * w1.x; acc[0][5] += a0 * w1.y; acc[0][6] += a0 * w1.z; acc[0][7] += a0 * w1.w;
        acc[1][0] += a1 * w0.x; acc[1][1] += a1 * w0.y; acc[1][2] += a1 * w0.z; acc[1][3] += a1 * w0.w;
        acc[1][4] += a1 * w1.x; acc[1][5] += a1 * w1.y; acc[1][6] += a1 * w1.z; acc[1][7] += a1 * w1.w;
    }

    float4 bb0 = *(const float4*)(bias + tx * 4);
    float4 bb1 = *(const float4*)(bias + 64 + tx * 4);
    #pragma unroll
    for (int i = 0; i < 2; i++) {
        int row = row0 + ty * 2 + i;
        if (row < N) {
            float4 v0 = make_float4(acc[i][0] + bb0.x, acc[i][1] + bb0.y, acc[i][2] + bb0.z, acc[i][3] + bb0.w);
            float4 v1 = make_float4(acc[i][4] + bb1.x, acc[i][5] + bb1.y, acc[i][6] + bb1.z, acc[i][7] + bb1.w);
            *(float4*)(outp + (size_t)row * HID + tx * 4) = v0;
            *(float4*)(outp + (size_t)row * HID + 64 + tx * 4) = v1;
        }
    }
}

// ---------------------------------------------------------------- layer-1 combine: Hb = bf16(elu(att + x@W + b))
__global__ __launch_bounds__(256) void combine16_kernel(
    const float* __restrict__ Hin,
    const float* __restrict__ W, const float* __restrict__ bias,
    const float* __restrict__ Att, unsigned short* __restrict__ Hb,
    int N) {
    constexpr int K = 16;
    __shared__ float Ws[K][HID];
    __shared__ float Hs[32][K + 4];

    int row0 = blockIdx.x * 32;
    int tid = threadIdx.x;
    int tx = tid & 15, ty = tid >> 4;

    for (int i = tid; i < 32 * (K / 4); i += 256) {
        int r = i / (K / 4), kq = i % (K / 4);
        int row = row0 + r;
        float4 v = make_float4(0.f, 0.f, 0.f, 0.f);
        if (row < N) v = *(const float4*)(Hin + (size_t)row * K + kq * 4);
        *(float4*)&Hs[r][kq * 4] = v;
    }
    for (int i = tid; i < K * 32; i += 256) {
        int k = i >> 5, cq = i & 31;
        *(float4*)&Ws[k][cq * 4] = *(const float4*)(W + (size_t)k * HID + cq * 4);
    }
    __syncthreads();

    float acc[2][8];
    #pragma unroll
    for (int i = 0; i < 2; i++)
        #pragma unroll
        for (int j = 0; j < 8; j++) acc[i][j] = 0.f;

    int r0 = ty * 2, r1 = ty * 2 + 1;
    #pragma unroll
    for (int k = 0; k < K; k++) {
        float a0 = Hs[r0][k];
        float a1 = Hs[r1][k];
        float4 w0 = *(float4*)&Ws[k][tx * 4];
        float4 w1 = *(float4*)&Ws[k][64 + tx * 4];
        acc[0][0] += a0 * w0.x; acc[0][1] += a0 * w0.y; acc[0][2] += a0 * w0.z; acc[0][3] += a0 * w0.w;
        acc[0][4] += a0 * w1.x; acc[0][5] += a0 * w1.y; acc[0][6] += a0 * w1.z; acc[0][7] += a0 * w1.w;
        acc[1][0] += a1 * w0.x; acc[1][1] += a1 * w0.y; acc[1][2] += a1 * w0.z; acc[1][3] += a1 * w0.w;
        acc[1][4] += a1 * w1.x; acc[1][5] += a1 * w1.y; acc[1][6] += a1 * w1.z; acc[1][7] += a1 * w1.w;
    }

    float4 bb0 = *(const float4*)(bias + tx * 4);
    float4 bb1 = *(const float4*)(bias + 64 + tx * 4);
    #pragma unroll
    for (int i = 0; i < 2; i++) {
        int row = row0 + ty * 2 + i;
        if (row < N) {
            const float* p0 = Att + (size_t)row * HID + tx * 4;
            float4 g0 = *(const float4*)p0;
            float4 g1 = *(const float4*)(p0 + 64);
            float v[8];
            v[0] = g0.x + acc[i][0] + bb0.x; v[1] = g0.y + acc[i][1] + bb0.y;
            v[2] = g0.z + acc[i][2] + bb0.z; v[3] = g0.w + acc[i][3] + bb0.w;
            v[4] = g1.x + acc[i][4] + bb1.x; v[5] = g1.y + acc[i][5] + bb1.y;
            v[6] = g1.z + acc[i][6] + bb1.z; v[7] = g1.w + acc[i][7] + bb1.w;
            #pragma unroll
            for (int j = 0; j < 8; j++) v[j] = (v[j] > 0.f) ? v[j] : (__expf(v[j]) - 1.f);
            ushort4 h0, h1;
            h0.x = f2bf(v[0]); h0.y = f2bf(v[1]); h0.z = f2bf(v[2]); h0.w = f2bf(v[3]);
            h1.x = f2bf(v[4]); h1.y = f2bf(v[5]); h1.z = f2bf(v[6]); h1.w = f2bf(v[7]);
            *(ushort4*)(Hb + (size_t)row * HID + tx * 4) = h0;
            *(ushort4*)(Hb + (size_t)row * HID + 64 + tx * 4) = h1;
        }
    }
}

// ---------------------------------------------------------------- edge/attention: ONE node per wave; halves split
// the edge list. NO running max: logits are O(1) (0.05-scale weights); p = exp(min(logit,60)) cannot overflow f32.
// Accumulators are plain sums -> no serial rescale chain.
template <int FUSE>
__global__ __launch_bounds__(256) void edge_kernel(
    const void* __restrict__ XLv, const void* __restrict__ XRv,
    const int* __restrict__ row_ptr, const int* __restrict__ csr_src,
    const unsigned int* __restrict__ csr_eap,
    const float* __restrict__ att,
    const float* __restrict__ We,
    const float* __restrict__ gbias,
    const unsigned short* __restrict__ lin,
    float* __restrict__ hf, unsigned short* __restrict__ hb,
    int N) {
    int n = (blockIdx.x * 256 + threadIdx.x) >> 6;   // one node per wave
    int lane = threadIdx.x & 63;
    int half = lane >> 5;
    int l = lane & 31;
    bool active = (n < N);
    int nn = active ? n : 0;

    int c0 = l * 4;
    float4 av  = *(const float4*)(att + c0);
    float4 we0 = *(const float4*)(We + c0);
    float4 we1 = *(const float4*)(We + HID + c0);

    auto ldx = [&](const void* p, int idx) -> float4 {
        if constexpr (FUSE) return ld4bf((const unsigned short*)p + (size_t)idx * HID + c0);
        else                return *(const float4*)((const float*)p + (size_t)idx * HID + c0);
    };
    float4 xr = ldx(XRv, nn);

    int eb = 0, eend = 0;
    if (active) { eb = row_ptr[n]; eend = row_ptr[n + 1]; }
    int mid = (eb + eend + 1) >> 1;
    int sb = half ? mid : eb;
    int se = half ? eend : mid;

    float l_run = 0.f;
    float4 fa = make_float4(0.f, 0.f, 0.f, 0.f);

    for (int base = sb; base < se; base += 32) {
        int cnt = min(32, se - base);
        int myi = base + l;
        int msrc = 0; unsigned mea = 0;
        if (myi < se) { msrc = csr_src[myi]; mea = csr_eap[myi]; }

        int s0 = __shfl(msrc, 0, 32);
        int s1 = __shfl(msrc, 1, 32);
        unsigned e0 = __shfl(mea, 0, 32);
        unsigned e1 = __shfl(mea, 1, 32);
        float4 xl0 = ldx(XLv, s0);
        float4 xl1 = ldx(XLv, s1);

        for (int j = 0; ; j += 2) {
            bool more = (j + 2 < cnt);
            int ns0 = 0, ns1 = 0; unsigned ne0 = 0, ne1 = 0;
            float4 nxl0, nxl1;
            if (more) {
                ns0 = __shfl(msrc, j + 2, 32);
                ns1 = __shfl(msrc, j + 3, 32);
                ne0 = __shfl(mea, j + 2, 32);
                ne1 = __shfl(mea, j + 3, 32);
                nxl0 = ldx(XLv, ns0);
                nxl1 = ldx(XLv, ns1);
            }
            float ex0 = bflo(e0), ey0 = bfhi(e0);
            float ex1 = bflo(e1), ey1 = bfhi(e1);
            float t, part0, part1;
            float m0x = xl0.x + xr.x + ex0 * we0.x + ey0 * we1.x;
            float m0y = xl0.y + xr.y + ex0 * we0.y + ey0 * we1.y;
            float m0z = xl0.z + xr.z + ex0 * we0.z + ey0 * we1.z;
            float m0w = xl0.w + xr.w + ex0 * we0.w + ey0 * we1.w;
            m0x = fmaxf(m0x, 0.2f * m0x);
            m0y = fmaxf(m0y, 0.2f * m0y);
            m0z = fmaxf(m0z, 0.2f * m0z);
            m0w = fmaxf(m0w, 0.2f * m0w);
            part0 = m0x * av.x + m0y * av.y + m0z * av.z + m0w * av.w;
            float m1x = xl1.x + xr.x + ex1 * we0.x + ey1 * we1.x;
            float m1y = xl1.y + xr.y + ex1 * we0.y + ey1 * we1.y;
            float m1z = xl1.z + xr.z + ex1 * we0.z + ey1 * we1.z;
            float m1w = xl1.w + xr.w + ex1 * we0.w + ey1 * we1.w;
            m1x = fmaxf(m1x, 0.2f * m1x);
            m1y = fmaxf(m1y, 0.2f * m1y);
            m1z = fmaxf(m1z, 0.2f * m1z);
            m1w = fmaxf(m1w, 0.2f * m1w);
            part1 = m1x * av.x + m1y * av.y + m1z * av.z + m1w * av.w;
            t = __shfl_xor(part0, 1); part0 += t;
            t = __shfl_xor(part0, 2); part0 += t;
            t = __shfl_xor(part1, 1); part1 += t;
            t = __shfl_xor(part1, 2); part1 += t;

            bool two = (j + 1 < cnt);
            float p0 = __expf(fminf(part0, 60.f));
            float p1 = two ? __expf(fminf(part1, 60.f)) : 0.f;
            l_run += p0 + p1;
            fa.x += p0 * xl0.x + p1 * xl1.x;
            fa.y += p0 * xl0.y + p1 * xl1.y;
            fa.z += p0 * xl0.z + p1 * xl1.z;
            fa.w += p0 * xl0.w + p1 * xl1.w;
            if (!more) break;
            s0 = ns0; s1 = ns1; e0 = ne0; e1 = ne1; xl0 = nxl0; xl1 = nxl1;
        }
    }

    // merge halves: plain sums
    l_run += __shfl_xor(l_run, 32);
    fa.x += __shfl_xor(fa.x, 32);
    fa.y += __shfl_xor(fa.y, 32);
    fa.z += __shfl_xor(fa.z, 32);
    fa.w += __shfl_xor(fa.w, 32);

    if (!active || half) return;      // lanes 0-31 write
    float inv = 1.f / fmaxf(l_run, 1e-16f);
    float4 bias4 = *(const float4*)(gbias + c0);
    float4 v;
    v.x = fa.x * inv + bias4.x;
    v.y = fa.y * inv + bias4.y;
    v.z = fa.z * inv + bias4.z;
    v.w = fa.w * inv + bias4.w;
    if constexpr (FUSE) {
        float4 lv = ld4bf(lin + (size_t)n * HID + c0);
        v.x += lv.x; v.y += lv.y; v.z += lv.z; v.w += lv.w;
        v.x = (v.x > 0.f) ? v.x : (__expf(v.x) - 1.f);
        v.y = (v.y > 0.f) ? v.y : (__expf(v.y) - 1.f);
        v.z = (v.z > 0.f) ? v.z : (__expf(v.z) - 1.f);
        v.w = (v.w > 0.f) ? v.w : (__expf(v.w) - 1.f);
        if (hf) *(float4*)(hf + (size_t)n * HID + c0) = v;
        ushort4 hh;
        hh.x = f2bf(v.x); hh.y = f2bf(v.y); hh.z = f2bf(v.z); hh.w = f2bf(v.w);
        *(ushort4*)(hb + (size_t)n * HID + c0) = hh;
    } else {
        *(float4*)(hf + (size_t)n * HID + c0) = v;
    }
}

// ---------------------------------------------------------------- mean pool per graph
__global__ __launch_bounds__(128) void pool_kernel(const float* __restrict__ h,
                                                   const int* __restrict__ batch,
                                                   float* __restrict__ g, int N) {
    int gid = blockIdx.x;
    int lo = lower_bound_i(batch, N, gid);
    int hi = lower_bound_i(batch, N, gid + 1);
    int c = threadIdx.x;
    float s = 0.f;
    for (int i = lo; i < hi; i++) s += h[(size_t)i * HID + c];
    g[gid * HID + c] = s / fmaxf((float)(hi - lo), 1.0f);
}

// ---------------------------------------------------------------- readout GEMM
__global__ __launch_bounds__(256) void readout_kernel(const float* __restrict__ g,
                                                      const float* __restrict__ W,
                                                      const float* __restrict__ b,
                                                      float* __restrict__ out, int S) {
    __shared__ float gs[HID];
    int gid = blockIdx.y;
    if (threadIdx.x < HID) gs[threadIdx.x] = g[gid * HID + threadIdx.x];
    __syncthreads();
    int c = blockIdx.x * 256 + threadIdx.x;
    if (c < S) {
        float acc = b[c];
        #pragma unroll 8
        for (int k = 0; k < HID; k++) acc += gs[k] * W[(size_t)k * S + c];
        out[(size_t)gid * S + c] = acc;
    }
}

// ---------------------------------------------------------------- launcher
extern "C" void kernel_launch(void* const* d_in, const int* in_sizes, int n_in,
                              void* d_out, int out_size, void* d_ws, size_t ws_size,
                              hipStream_t stream) {
    const float* x      = (const float*)d_in[0];
    const int*   ei     = (const int*)d_in[1];
    const float* eattr  = (const float*)d_in[2];
    const int*   batch  = (const int*)d_in[3];
    const float* at1_Wl = (const float*)d_in[4];
    const float* at1_bl = (const float*)d_in[5];
    const float* at1_Wr = (const float*)d_in[6];
    const float* at1_br = (const float*)d_in[7];
    const float* at1_We = (const float*)d_in[8];
    const float* at1_att= (const float*)d_in[9];
    const float* at1_b  = (const float*)d_in[10];
    const float* l1_W   = (const float*)d_in[11];
    const float* l1_b   = (const float*)d_in[12];
    const float* atk_Wl = (const float*)d_in[13];
    const float* atk_bl = (const float*)d_in[14];
    const float* atk_Wr = (const float*)d_in[15];
    const float* atk_br = (const float*)d_in[16];
    const float* atk_We = (const float*)d_in[17];
    const float* atk_att= (const float*)d_in[18];
    const float* atk_b  = (const float*)d_in[19];
    const float* lk_W   = (const float*)d_in[20];
    const float* lk_b   = (const float*)d_in[21];
    const float* lin_W  = (const float*)d_in[22];
    const float* lin_b  = (const float*)d_in[23];
    float* out = (float*)d_out;

    const int N  = in_sizes[0] / 16;
    const int E  = in_sizes[1] / 2;
    const int ET = E + N;
    const int S  = 1000;
    const int G  = out_size / S;

    char* w = (char*)d_ws;
    auto alloc = [&](size_t bytes) -> char* {
        char* p = w; w += (bytes + 255) & ~(size_t)255; return p;
    };
    float*  XLf     = (float*)alloc((size_t)N * HID * 4);   // layer-1 only
    float*  XRf     = (float*)alloc((size_t)N * HID * 4);   // layer-1 only
    unsigned short* XLb = (unsigned short*)alloc((size_t)N * HID * 2);
    unsigned short* XRb = (unsigned short*)alloc((size_t)N * HID * 2);
    unsigned short* Linb = (unsigned short*)alloc((size_t)N * HID * 2);
    float*  Hf      = (float*)alloc((size_t)N * HID * 4);
    unsigned short* Hb = (unsigned short*)alloc((size_t)N * HID * 2);
    int*    deg     = (int*)alloc((size_t)N * 4);
    int*    row_ptr = (int*)alloc((size_t)(N + 1) * 4);
    int*    cursor  = (int*)alloc((size_t)N * 4);
    int*    csr_src = (int*)alloc((size_t)ET * 4);
    unsigned int* csr_eap = (unsigned int*)alloc((size_t)ET * 4);
    float*  meansum = (float*)alloc(8);
    int*    bsum    = (int*)alloc(256);
    int*    boff    = (int*)alloc(256);
    unsigned short* WlTh = (unsigned short*)alloc((size_t)9 * 16384 * 2);
    unsigned short* WrTh = (unsigned short*)alloc((size_t)9 * 16384 * 2);
    unsigned short* WkTh = (unsigned short*)alloc((size_t)9 * 16384 * 2);
    float*  gpool   = (float*)alloc((size_t)G * HID * 4);
    (void)ws_size; (void)n_in;

    hipMemsetAsync(deg, 0, (size_t)N * 4, stream);
    hipMemsetAsync(meansum, 0, 8, stream);

    const int wtot = 9 * 16384;
    wprep_kernel<<<(wtot + 255) / 256, 256, 0, stream>>>(atk_Wl, WlTh, wtot);
    wprep_kernel<<<(wtot + 255) / 256, 256, 0, stream>>>(atk_Wr, WrTh, wtot);
    wprep_kernel<<<(wtot + 255) / 256, 256, 0, stream>>>(lk_W,   WkTh, wtot);

    mean_kernel<<<256, 256, 0, stream>>>(eattr, meansum, E);
    deg_kernel<<<(ET + 255) / 256, 256, 0, stream>>>(ei, deg, E, ET);
    const int NB = (N + 1023) / 1024;
    scanA_kernel<<<NB, 256, 0, stream>>>(deg, bsum, N);
    scanB_kernel<<<1, 64, 0, stream>>>(bsum, boff, row_ptr, NB, N);
    scanC_kernel<<<NB, 256, 0, stream>>>(deg, boff, row_ptr, cursor, N);
    fill_kernel<<<(ET + 255) / 256, 256, 0, stream>>>(ei, eattr, meansum, cursor, csr_src, csr_eap, E, ET);

    const int gx16 = (N + 31) / 32;
    const int ge   = (N + 3) / 4;        // 1 node per wave, 4 waves per block
    const int gx3  = (N + 127) / 128;

    transform16_kernel<<<dim3(gx16, 1, 2), 256, 0, stream>>>(x, at1_Wl, at1_bl, XLf, at1_Wr, at1_br, XRf, N);
    edge_kernel<0><<<ge, 256, 0, stream>>>(XLf, XRf, row_ptr, csr_src, csr_eap, at1_att, at1_We, at1_b,
                                           nullptr, Hf, nullptr, N);
    combine16_kernel<<<gx16, 256, 0, stream>>>(x, l1_W, l1_b, Hf, Hb, N);

    for (int i = 0; i < 9; i++) {
        const unsigned short* wlh = WlTh + (size_t)i * 16384;
        const unsigned short* wrh = WrTh + (size_t)i * 16384;
        const unsigned short* wkh = WkTh + (size_t)i * 16384;
        const float* bl = atk_bl + (size_t)i * HID;
        const float* br = atk_br + (size_t)i * HID;
        const float* bk = lk_b   + (size_t)i * HID;
        const float* Wep = atk_We + (size_t)i * 2 * HID;
        const float* at = atk_att + (size_t)i * HID;
        const float* ab = atk_b  + (size_t)i * HID;

        gemm3_kernel<<<dim3(gx3, 3), 256, 0, stream>>>(Hb,
                                                       wlh, bl, XLb,
                                                       wrh, br, XRb,
                                                       wkh, bk, Linb, N);
        edge_kernel<1><<<ge, 256, 0, stream>>>(XLb, XRb, row_ptr, csr_src, csr_eap, at, Wep, ab,
                                               Linb, (i == 8) ? Hf : nullptr, Hb, N);
    }

    pool_kernel<<<G, 128, 0, stream>>>(Hf, batch, gpool, N);
    readout_kernel<<<dim3((S + 255) / 256, G), 256, 0, stream>>>(gpool, lin_W, lin_b, out, S);
}